// Round 25
// baseline (794.363 us; speedup 1.0000x reference)
//
#include <hip/hip_runtime.h>
#include <cstdint>
#include <math.h>

typedef unsigned short u16;
typedef unsigned int u32;
typedef __bf16 bf16x8 __attribute__((ext_vector_type(8)));
typedef float f32x4 __attribute__((ext_vector_type(4)));

#define TBATCH 2
#define TSEQ   2048
#define TDIM   1024
#define THEADS 16
#define THDIM  64
#define TEXP   8
#define TFF    1024
#define TTOK   (TBATCH*TSEQ)
#define TPAIRS (TTOK*2)

__device__ __forceinline__ u16 f2bf(float f) {
  u32 u = __float_as_uint(f);
  u += 0x7FFFu + ((u >> 16) & 1u);
  return (u16)(u >> 16);
}
__device__ __forceinline__ u16 f2bft(float f) {        // truncating split (1 op)
  return (u16)(__float_as_uint(f) >> 16);
}
__device__ __forceinline__ float bf2f(u16 h) { return __uint_as_float(((u32)h) << 16); }
__device__ __forceinline__ float fexp2(float x) {      // raw v_exp_f32 (exp2)
  float r;
  asm("v_exp_f32 %0, %1" : "=v"(r) : "v"(x));
  return r;
}

__device__ __forceinline__ void gll16(const void* g, void* l) {
  __builtin_amdgcn_global_load_lds((const __attribute__((address_space(1))) void*)g,
                                   (__attribute__((address_space(3))) void*)l, 16, 0, 0);
}
__device__ __forceinline__ bf16x8 ldsread(const void* p) { return *(const bf16x8*)p; }
__device__ __forceinline__ f32x4 mm16(bf16x8 a, bf16x8 b, f32x4 c) {
  return __builtin_amdgcn_mfma_f32_16x16x32_bf16(a, b, c, 0, 0, 0);
}
__device__ __forceinline__ f32x4 fzero() { f32x4 z = {0.f, 0.f, 0.f, 0.f}; return z; }

// ---------- ALL weight transposes in ONE launch: f32 [z][1024][1024] -> bf16 [z][1024][1024]^T ----------
__global__ void transpose_all_k(const float* __restrict__ wq, const float* __restrict__ wk,
                                const float* __restrict__ wv, const float* __restrict__ wo,
                                const float* __restrict__ w1, const float* __restrict__ w3,
                                const float* __restrict__ w2,
                                u16* __restrict__ qth, u16* __restrict__ qtl,
                                u16* __restrict__ kth, u16* __restrict__ ktl,
                                u16* __restrict__ vth_, u16* __restrict__ vtl_,
                                u16* __restrict__ oth, u16* __restrict__ otl,
                                u16* __restrict__ w1t, u16* __restrict__ w3t, u16* __restrict__ w2t) {
  __shared__ float t[32][33];
  int id = (int)blockIdx.x;
  const float* in; u16* outh; u16* outl = nullptr;
  size_t bo = 0;
  int tile;
  if (id < 4096) {
    const int wi = id >> 10;
    in   = (wi == 0) ? wq  : (wi == 1) ? wk  : (wi == 2) ? wv   : wo;
    outh = (wi == 0) ? qth : (wi == 1) ? kth : (wi == 2) ? vth_ : oth;
    outl = (wi == 0) ? qtl : (wi == 1) ? ktl : (wi == 2) ? vtl_ : otl;
    tile = id & 1023;
  } else {
    const int id2 = id - 4096;
    const int wi = id2 >> 13;                 // 0=w1 1=w3 2=w2
    const int rem = id2 & 8191;
    bo = (size_t)(rem >> 10) << 20;           // z * 1024*1024
    in   = (wi == 0) ? w1  : (wi == 1) ? w3  : w2;
    outh = (wi == 0) ? w1t : (wi == 1) ? w3t : w2t;
    tile = rem & 1023;
  }
  const int c0 = (tile & 31) * 32, r0 = (tile >> 5) * 32;
  const int tx = threadIdx.x, ty = threadIdx.y;
#pragma unroll
  for (int j = 0; j < 32; j += 8)
    t[ty + j][tx] = in[bo + (size_t)(r0 + ty + j) * 1024 + (c0 + tx)];
  __syncthreads();
#pragma unroll
  for (int j = 0; j < 32; j += 8) {
    float v = t[tx][ty + j];
    u16 hv = f2bf(v);
    size_t o = bo + (size_t)(c0 + ty + j) * 1024 + (r0 + tx);
    outh[o] = hv;
    if (outl != nullptr) outl[o] = f2bf(v - bf2f(hv));
  }
}

// ---------- RMSNorm: f32 [T][D] -> bf16 split (attn input) ----------
__launch_bounds__(256)
__global__ void rmsnorm_k(const float* __restrict__ x, const float* __restrict__ w,
                          u16* __restrict__ oh, u16* __restrict__ ol) {
  const int t = blockIdx.x, tid = threadIdx.x;
  const float4 xv = ((const float4*)(x + (size_t)t * TDIM))[tid];
  float ss = xv.x*xv.x + xv.y*xv.y + xv.z*xv.z + xv.w*xv.w;
#pragma unroll
  for (int d = 1; d < 64; d <<= 1) ss += __shfl_xor(ss, d, 64);
  __shared__ float sp[4];
  if ((tid & 63) == 0) sp[tid >> 6] = ss;
  __syncthreads();
  const float rsc = rsqrtf((sp[0] + sp[1] + sp[2] + sp[3]) * (1.0f / TDIM) + 1e-6f);
  const float4 wv = ((const float4*)w)[tid];
  float v0 = xv.x*rsc*wv.x, v1 = xv.y*rsc*wv.y, v2 = xv.z*rsc*wv.z, v3 = xv.w*rsc*wv.w;
  u16 h0 = f2bf(v0), h1 = f2bf(v1), h2 = f2bf(v2), h3 = f2bf(v3);
  uint2 ph; ph.x = (u32)h0 | ((u32)h1 << 16); ph.y = (u32)h2 | ((u32)h3 << 16);
  *(uint2*)(oh + (size_t)t * TDIM + tid * 4) = ph;
  u16 l0 = f2bf(v0 - bf2f(h0)), l1 = f2bf(v1 - bf2f(h1));
  u16 l2 = f2bf(v2 - bf2f(h2)), l3 = f2bf(v3 - bf2f(h3));
  uint2 pl; pl.x = (u32)l0 | ((u32)l1 << 16); pl.y = (u32)l2 | ((u32)l3 << 16);
  *(uint2*)(ol + (size_t)t * TDIM + tid * 4) = pl;
}

// ---------- fused QKV bf16x3 GEMM: one launch, blockIdx.y selects Q/K/V (grid 32 x 48) ----------
// Q output is pre-scaled by 1/sqrt(HD)*log2(e) so flash_k's softmax works directly in exp2 domain.
__launch_bounds__(256)
__global__ void gemm_qkv_k(const u16* __restrict__ Ah, const u16* __restrict__ Al,
                           const u16* __restrict__ Bqh, const u16* __restrict__ Bql,
                           const u16* __restrict__ Bkh, const u16* __restrict__ Bkl,
                           const u16* __restrict__ Bvh, const u16* __restrict__ Bvl,
                           u16* __restrict__ qh, u16* __restrict__ ql,
                           u16* __restrict__ kh, u16* __restrict__ kl,
                           u16* __restrict__ vth, u16* __restrict__ vtl) {
  __shared__ u16 sAh[2][128 * 32], sAl[2][128 * 32], sBh[2][64 * 32], sBl[2][64 * 32];
  const int tid = threadIdx.x, wid = tid >> 6, lane = tid & 63;
  const int which = blockIdx.y >> 4;                 // 0=Q 1=K 2=V (block-uniform)
  const int m0 = blockIdx.x * 128, n0 = (blockIdx.y & 15) * 64;
  const int wr = wid >> 1, wc = wid & 1;
  const u16* Bth = (which == 0) ? Bqh : (which == 1) ? Bkh : Bvh;
  const u16* Btl = (which == 0) ? Bql : (which == 1) ? Bkl : Bvl;
  u16* outh = (which == 0) ? qh : kh;
  u16* outl = (which == 0) ? ql : kl;

  f32x4 acc[4][2];
#pragma unroll
  for (int i = 0; i < 4; i++)
#pragma unroll
    for (int j = 0; j < 2; j++) acc[i][j] = fzero();

  const int srow = tid >> 2;
  const int scol = (((tid & 3) ^ ((tid >> 3) & 3)) * 8);
  const size_t a0 = (size_t)(m0 + srow) * TDIM + scol;
  const size_t a1 = (size_t)(m0 + srow + 64) * TDIM + scol;
  const size_t b0 = (size_t)(n0 + srow) * TDIM + scol;
  const int ldsw = wid * 1024;

  const int g = (lane >> 1) & 3;
  int aoffs[4], boffs[2];
#pragma unroll
  for (int mf = 0; mf < 4; mf++)
    aoffs[mf] = (wr*64 + mf*16 + (lane & 15)) * 64 + ((((lane >> 4)) ^ g) << 4);
#pragma unroll
  for (int nf = 0; nf < 2; nf++)
    boffs[nf] = (wc*32 + nf*16 + (lane & 15)) * 64 + ((((lane >> 4)) ^ g) << 4);

  auto stage = [&](int kk, int bi) {
    const int ke = kk * 32;
    gll16(Ah + a0 + ke, (char*)sAh[bi] + ldsw);
    gll16(Ah + a1 + ke, (char*)sAh[bi] + 4096 + ldsw);
    gll16(Al + a0 + ke, (char*)sAl[bi] + ldsw);
    gll16(Al + a1 + ke, (char*)sAl[bi] + 4096 + ldsw);
    gll16(Bth + b0 + ke, (char*)sBh[bi] + ldsw);
    gll16(Btl + b0 + ke, (char*)sBl[bi] + ldsw);
  };

  stage(0, 0);
  asm volatile("s_waitcnt vmcnt(0)" ::: "memory");
  __builtin_amdgcn_s_barrier();

  for (int kk = 0; kk < 32; ++kk) {
    const int cur = kk & 1;
    if (kk + 1 < 32) stage(kk + 1, cur ^ 1);
    bf16x8 fah[4], fal[4], fbh[2], fbl[2];
#pragma unroll
    for (int mf = 0; mf < 4; mf++) { fah[mf] = ldsread((char*)sAh[cur] + aoffs[mf]); fal[mf] = ldsread((char*)sAl[cur] + aoffs[mf]); }
#pragma unroll
    for (int nf = 0; nf < 2; nf++) { fbh[nf] = ldsread((char*)sBh[cur] + boffs[nf]); fbl[nf] = ldsread((char*)sBl[cur] + boffs[nf]); }
#pragma unroll
    for (int mf = 0; mf < 4; mf++)
#pragma unroll
      for (int nf = 0; nf < 2; nf++) {
        acc[mf][nf] = mm16(fah[mf], fbh[nf], acc[mf][nf]);
        acc[mf][nf] = mm16(fah[mf], fbl[nf], acc[mf][nf]);
        acc[mf][nf] = mm16(fal[mf], fbh[nf], acc[mf][nf]);
      }
    asm volatile("s_waitcnt vmcnt(0)" ::: "memory");
    __builtin_amdgcn_s_barrier();
  }

  const float qscale = (which == 0) ? 0.18033688011112042f : 1.0f;  // 0.125 * log2(e)
#pragma unroll
  for (int mf = 0; mf < 4; mf++)
#pragma unroll
    for (int nf = 0; nf < 2; nf++)
#pragma unroll
      for (int r = 0; r < 4; r++) {
        const int grow = m0 + wr*64 + mf*16 + ((lane >> 4) * 4) + r;
        const int gcol = n0 + wc*32 + nf*16 + (lane & 15);
        const float v = acc[mf][nf][r] * qscale;
        u16 hv = f2bf(v);
        u16 lv = f2bf(v - bf2f(hv));
        if (which < 2) {
          const size_t o = (size_t)grow * TDIM + gcol;
          outh[o] = hv; outl[o] = lv;
        } else {
          const int b = grow >> 11, s = grow & (TSEQ - 1);
          const int hh = gcol >> 6, hd = gcol & 63;
          const size_t o = ((size_t)((b * THEADS + hh) * THDIM + hd)) * TSEQ + s;
          vth[o] = hv; vtl[o] = lv;
        }
      }
}

// ---------- bf16x3 GEMM (WO): 2-buffer + prefetch; EPI2 = f32 out + resid ----------
template<int EPI>
__launch_bounds__(256)
__global__ void gemm_x3_k(const u16* __restrict__ Ah, const u16* __restrict__ Al,
                          const u16* __restrict__ Bth, const u16* __restrict__ Btl,
                          u16* __restrict__ outh, u16* __restrict__ outl,
                          float* __restrict__ outf, const float* __restrict__ resid,
                          int M, int N, int K) {
  __shared__ u16 sAh[2][128 * 32], sAl[2][128 * 32], sBh[2][64 * 32], sBl[2][64 * 32];
  const int tid = threadIdx.x, wid = tid >> 6, lane = tid & 63;
  const int m0 = blockIdx.x * 128, n0 = blockIdx.y * 64;
  const int wr = wid >> 1, wc = wid & 1;

  f32x4 acc[4][2];
#pragma unroll
  for (int i = 0; i < 4; i++)
#pragma unroll
    for (int j = 0; j < 2; j++) acc[i][j] = fzero();

  const int srow = tid >> 2;
  const int scol = (((tid & 3) ^ ((tid >> 3) & 3)) * 8);
  const size_t a0 = (size_t)(m0 + srow) * K + scol;
  const size_t a1 = (size_t)(m0 + srow + 64) * K + scol;
  const size_t b0 = (size_t)(n0 + srow) * K + scol;
  const int ldsw = wid * 1024;

  const int g = (lane >> 1) & 3;
  int aoffs[4], boffs[2];
#pragma unroll
  for (int mf = 0; mf < 4; mf++)
    aoffs[mf] = (wr*64 + mf*16 + (lane & 15)) * 64 + ((((lane >> 4)) ^ g) << 4);
#pragma unroll
  for (int nf = 0; nf < 2; nf++)
    boffs[nf] = (wc*32 + nf*16 + (lane & 15)) * 64 + ((((lane >> 4)) ^ g) << 4);

  auto stage = [&](int kk, int bi) {
    const int ke = kk * 32;
    gll16(Ah + a0 + ke, (char*)sAh[bi] + ldsw);
    gll16(Ah + a1 + ke, (char*)sAh[bi] + 4096 + ldsw);
    gll16(Al + a0 + ke, (char*)sAl[bi] + ldsw);
    gll16(Al + a1 + ke, (char*)sAl[bi] + 4096 + ldsw);
    gll16(Bth + b0 + ke, (char*)sBh[bi] + ldsw);
    gll16(Btl + b0 + ke, (char*)sBl[bi] + ldsw);
  };

  const int nk = K >> 5;
  stage(0, 0);
  asm volatile("s_waitcnt vmcnt(0)" ::: "memory");
  __builtin_amdgcn_s_barrier();

  for (int kk = 0; kk < nk; ++kk) {
    const int cur = kk & 1;
    if (kk + 1 < nk) stage(kk + 1, cur ^ 1);
    bf16x8 fah[4], fal[4], fbh[2], fbl[2];
#pragma unroll
    for (int mf = 0; mf < 4; mf++) { fah[mf] = ldsread((char*)sAh[cur] + aoffs[mf]); fal[mf] = ldsread((char*)sAl[cur] + aoffs[mf]); }
#pragma unroll
    for (int nf = 0; nf < 2; nf++) { fbh[nf] = ldsread((char*)sBh[cur] + boffs[nf]); fbl[nf] = ldsread((char*)sBl[cur] + boffs[nf]); }
#pragma unroll
    for (int mf = 0; mf < 4; mf++)
#pragma unroll
      for (int nf = 0; nf < 2; nf++) {
        acc[mf][nf] = mm16(fah[mf], fbh[nf], acc[mf][nf]);
        acc[mf][nf] = mm16(fah[mf], fbl[nf], acc[mf][nf]);
        acc[mf][nf] = mm16(fal[mf], fbh[nf], acc[mf][nf]);
      }
    asm volatile("s_waitcnt vmcnt(0)" ::: "memory");
    __builtin_amdgcn_s_barrier();
  }

#pragma unroll
  for (int mf = 0; mf < 4; mf++)
#pragma unroll
    for (int nf = 0; nf < 2; nf++)
#pragma unroll
      for (int r = 0; r < 4; r++) {
        const int grow = m0 + wr*64 + mf*16 + ((lane >> 4) * 4) + r;
        const int gcol = n0 + wc*32 + nf*16 + (lane & 15);
        const float v = acc[mf][nf][r];
        if (EPI == 0) {
          const size_t o = (size_t)grow * N + gcol;
          u16 hv = f2bf(v);
          outh[o] = hv; outl[o] = f2bf(v - bf2f(hv));
        } else if (EPI == 1) {
          const int b = grow >> 11, s = grow & (TSEQ - 1);
          const int hh = gcol >> 6, hd = gcol & 63;
          const size_t o = ((size_t)((b * THEADS + hh) * THDIM + hd)) * TSEQ + s;
          u16 hv = f2bf(v);
          outh[o] = hv; outl[o] = f2bf(v - bf2f(hv));
        } else {
          const size_t o = (size_t)grow * N + gcol;
          outf[o] = v + resid[o];
        }
      }
}

// ---------- causal flash attention, split-KV(2), KVBLK=32, 40KB LDS (4 blocks/CU), partial outputs ----------
__global__ void flash_k(const u16* __restrict__ Qh, const u16* __restrict__ Ql,
                        const u16* __restrict__ Kh, const u16* __restrict__ Kl,
                        const u16* __restrict__ Vth, const u16* __restrict__ Vtl,
                        float* __restrict__ Op, float* __restrict__ ml) {
  __shared__ u16 sK[2][2][2048];   // [buf][hi/lo][32x64] rows 128B, 16KB
  __shared__ u16 sV[2][2][2048];   // [buf][hi/lo][64x32] rows 64B, 16KB
  __shared__ u16 sP[2][4][512];    // [hi/lo][warp][16x32] rows 64B, 8KB
  const int tid = threadIdx.x, wid = tid >> 6, lane = tid & 63;
  const int qb = (int)(gridDim.x - 1 - blockIdx.x);   // longest-first
  const int bh = blockIdx.y;
  const int b = bh >> 4, h = bh & 15;
  const int sp = blockIdx.z;                          // KV split index (0/1)

  // Q fragments for both 64-row halves (Q pre-scaled by 0.125*log2(e) in gemm_qkv_k)
  bf16x8 fqh[2][2], fql[2][2];
#pragma unroll
  for (int hh = 0; hh < 2; hh++) {
    const size_t qbase = ((size_t)(b * TSEQ + qb * 128 + hh * 64 + wid * 16 + (lane & 15))) * TDIM + h * 64;
#pragma unroll
    for (int kq = 0; kq < 2; kq++) {
      fqh[hh][kq] = *(const bf16x8*)(Qh + qbase + (kq * 4 + (lane >> 4)) * 8);
      fql[hh][kq] = *(const bf16x8*)(Ql + qbase + (kq * 4 + (lane >> 4)) * 8);
    }
  }

  f32x4 oacc[2][4];
  float m_run[2][4], l_lane[2][4];
#pragma unroll
  for (int hh = 0; hh < 2; hh++)
#pragma unroll
    for (int i = 0; i < 4; i++) { oacc[hh][i] = fzero(); m_run[hh][i] = -INFINITY; l_lane[hh][i] = 0.f; }

  // K staging: 32 tokens x 64 d (128B rows), pre-swizzled global col (8 chunks, key=row&7)
  const int ksrow = tid >> 3;
  const int ksxcol = (((lane & 7) ^ ((lane >> 3) & 7)) << 3);
  const size_t kg0 = ((size_t)(b * TSEQ + ksrow)) * TDIM + h * 64 + ksxcol;
  // V staging: 64 d x 32 s (64B rows), pre-swizzled global s-col (4 chunks, key=(row>>1)&3)
  const int vsrow = tid >> 2;
  const int vsxcol = (((tid & 3) ^ ((tid >> 3) & 3)) << 3);
  const size_t vg0 = ((size_t)((b * THEADS + h) * THDIM + vsrow)) * TSEQ + vsxcol;

  auto stage = [&](int kb, int bi) {
    const size_t ko = (size_t)kb * 32 * TDIM;
    const size_t vo = (size_t)kb * 32;
    const int wofs = wid * 1024;               // 64 lanes * 16B per wave
    gll16(Kh + kg0 + ko, (char*)sK[bi][0] + wofs);
    gll16(Kl + kg0 + ko, (char*)sK[bi][1] + wofs);
    gll16(Vth + vg0 + vo, (char*)sV[bi][0] + wofs);
    gll16(Vtl + vg0 + vo, (char*)sV[bi][1] + wofs);
  };

  const int nhalf = 2 * qb + 2;                // tiles per split
  const int kb0 = sp * nhalf, kb1 = kb0 + nhalf;
  stage(kb0, 0);
  asm volatile("s_waitcnt vmcnt(0)" ::: "memory");
  __builtin_amdgcn_s_barrier();

  for (int kb = kb0; kb < kb1; ++kb) {
    const int cur = (kb - kb0) & 1;
    if (kb + 1 < kb1) stage(kb + 1, cur ^ 1);

    const bool act0 = (kb * 32 <= qb * 128 + 63);   // hh=0 tile not fully masked; hh=1 always active

    // QK^T for BOTH halves, sharing each K-fragment read (2 nf x 2 kq x hi/lo = 8 reads)
    f32x4 sc[2][2];
    __builtin_amdgcn_s_setprio(1);
#pragma unroll
    for (int nf = 0; nf < 2; nf++) {
      f32x4 s0 = fzero(), s1 = fzero();
      const int krow = nf * 16 + (lane & 15);
#pragma unroll
      for (int kq = 0; kq < 2; kq++) {
        const int off = krow * 128 + (((kq * 4 + (lane >> 4)) ^ (lane & 7)) << 4);
        bf16x8 kfh = ldsread((char*)sK[cur][0] + off);
        bf16x8 kfl = ldsread((char*)sK[cur][1] + off);
        s0 = mm16(fqh[0][kq], kfh, s0);
        s0 = mm16(fqh[0][kq], kfl, s0);
        s0 = mm16(fql[0][kq], kfh, s0);
        s1 = mm16(fqh[1][kq], kfh, s1);
        s1 = mm16(fqh[1][kq], kfl, s1);
        s1 = mm16(fql[1][kq], kfh, s1);
      }
      sc[0][nf] = s0; sc[1][nf] = s1;
    }
    __builtin_amdgcn_s_setprio(0);

    bf16x8 pa_h[2], pa_l[2];
#pragma unroll
    for (int hh = 0; hh < 2; hh++) {
      if (hh == 0 && !act0) continue;

      const int qg = qb * 128 + hh * 64 + wid * 16 + ((lane >> 4) * 4);
      float pm[4] = {-INFINITY, -INFINITY, -INFINITY, -INFINITY};
#pragma unroll
      for (int nf = 0; nf < 2; nf++) {
        const int kg = kb * 32 + nf * 16 + (lane & 15);
#pragma unroll
        for (int r = 0; r < 4; r++) {
          float v = sc[hh][nf][r];               // already exp2-domain (Q pre-scaled)
          if (kg > qg + r) v = -INFINITY;
          sc[hh][nf][r] = v;
          pm[r] = fmaxf(pm[r], v);
        }
      }
#pragma unroll
      for (int r = 0; r < 4; r++)
#pragma unroll
        for (int d = 1; d < 16; d <<= 1) pm[r] = fmaxf(pm[r], __shfl_xor(pm[r], d, 64));

      // defer-max (T13): skip O/l rescale when tile max within 8 (exp2-domain) of running max.
      const float dm = fmaxf(fmaxf(pm[0] - m_run[hh][0], pm[1] - m_run[hh][1]),
                             fmaxf(pm[2] - m_run[hh][2], pm[3] - m_run[hh][3]));
      if (!__all(dm <= 8.0f)) {
#pragma unroll
        for (int r = 0; r < 4; r++) {
          const float mn = fmaxf(m_run[hh][r], pm[r]);
          const float esc = fexp2(m_run[hh][r] - mn);
          m_run[hh][r] = mn;
          l_lane[hh][r] *= esc;
#pragma unroll
          for (int nf = 0; nf < 4; nf++) oacc[hh][nf][r] *= esc;
        }
      }
      float ls[4] = {0.f, 0.f, 0.f, 0.f};
#pragma unroll
      for (int nf = 0; nf < 2; nf++)
#pragma unroll
        for (int r = 0; r < 4; r++) {
          float p = fexp2(sc[hh][nf][r] - m_run[hh][r]);
          sc[hh][nf][r] = p;
          ls[r] += p;
        }
#pragma unroll
      for (int r = 0; r < 4; r++) l_lane[hh][r] += ls[r];

      // P store (16x32 per warp, 64B rows, chunk-XOR swizzle; per-warp private, no barrier)
#pragma unroll
      for (int nf = 0; nf < 2; nf++)
#pragma unroll
        for (int r = 0; r < 4; r++) {
          float p = sc[hh][nf][r];
          u16 ph = f2bft(p);
          const int prow = (lane >> 4) * 4 + r;
          const int pbyte = (prow * 64 + (nf * 16 + (lane & 15)) * 2) ^ (((prow >> 1) & 3) << 4);
          *(u16*)((char*)sP[0][wid] + pbyte) = ph;
          *(u16*)((char*)sP[1][wid] + pbyte) = f2bft(p - bf2f(ph));
        }

      // read this half's P fragment BEFORE the other half overwrites sP (same-wave ordering)
      {
        const int prow = lane & 15;
        const int poff = (prow * 64 + ((lane >> 4) << 4)) ^ ((((prow >> 1) & 3)) << 4);
        pa_h[hh] = ldsread((char*)sP[0][wid] + poff);
        pa_l[hh] = ldsread((char*)sP[1][wid] + poff);
      }
    }

    // PV: V fragments shared across halves (4 nf x hi/lo = 8 reads)
    __builtin_amdgcn_s_setprio(1);
#pragma unroll
    for (int nf = 0; nf < 4; nf++) {
      const int vrow = nf * 16 + (lane & 15);
      const int voff = vrow * 64 + ((((lane >> 4) ^ ((lane >> 1) & 3)) & 3) << 4);
      bf16x8 vfh = ldsread((char*)sV[cur][0] + voff);
      bf16x8 vfl = ldsread((char*)sV[cur][1] + voff);
      if (act0) {
        oacc[0][nf] = mm16(pa_h[0], vfh, oacc[0][nf]);
        oacc[0][nf] = mm16(pa_h[0], vfl, oacc[0][nf]);
        oacc[0][nf] = mm16(pa_l[0], vfh, oacc[0][nf]);
      }
      oacc[1][nf] = mm16(pa_h[1], vfh, oacc[1][nf]);
      oacc[1][nf] = mm16(pa_h[1], vfl, oacc[1][nf]);
      oacc[1][nf] = mm16(pa_l[1], vfh, oacc[1][nf]);
    }
    __builtin_amdgcn_s_setprio(0);

    asm volatile("s_waitcnt vmcnt(0)" ::: "memory");
    __builtin_amdgcn_s_barrier();
  }

  // epilogue: unnormalized partial O (f32) + per-row (m, l)
#pragma unroll
  for (int hh = 0; hh < 2; hh++)
#pragma unroll
    for (int r = 0; r < 4; r++) {
      float lt = l_lane[hh][r];
#pragma unroll
      for (int d = 1; d < 16; d <<= 1) lt += __shfl_xor(lt, d, 64);
      const int t = b * TSEQ + qb * 128 + hh * 64 + wid * 16 + ((lane >> 4) * 4) + r;
      const size_t ob = ((size_t)sp * TTOK + t) * TDIM + h * 64 + (lane & 15);
#pragma unroll
      for (int nf = 0; nf < 4; nf++)
        Op[ob + nf * 16] = oacc[hh][nf][r];
      if ((lane & 15) == 0) {
        const size_t mo = (((size_t)sp * TTOK + t) * THEADS + h) * 2;
        ml[mo] = m_run[hh][r];
        ml[mo + 1] = lt;
      }
    }
}

// ---------- flash split combine: O = (w0*O0 + w1*O1) / (w0*l0 + w1*l1), w_i = exp2(m_i - max) ----------
__launch_bounds__(256)
__global__ void flash_comb_k(const float* __restrict__ Op, const float* __restrict__ ml,
                             u16* __restrict__ Oh, u16* __restrict__ Ol) {
  const int t = blockIdx.x, tid = threadIdx.x;
  const int h = tid >> 4;                      // 4 d-elems per thread, all within one head
  const size_t m0o = (((size_t)t) * THEADS + h) * 2;
  const size_t m1o = (((size_t)TTOK + t) * THEADS + h) * 2;
  const float m0 = ml[m0o], l0 = ml[m0o + 1];
  const float m1 = ml[m1o], l1 = ml[m1o + 1];
  const float M = fmaxf(m0, m1);
  float w0 = fexp2(m0 - M), w1 = fexp2(m1 - M);
  const float inv = 1.0f / (w0 * l0 + w1 * l1);
  w0 *= inv; w1 *= inv;
  const float4 o0 = ((const float4*)(Op + (size_t)t * TDIM))[tid];
  const float4 o1 = ((const float4*)(Op + ((size_t)TTOK + t) * TDIM))[tid];
  const float vx = o0.x * w0 + o1.x * w1;
  const float vy = o0.y * w0 + o1.y * w1;
  const float vz = o0.z * w0 + o1.z * w1;
  const float vw = o0.w * w0 + o1.w * w1;
  u16 hx = f2bft(vx), hy = f2bft(vy), hz = f2bft(vz), hw = f2bft(vw);
  uint2 ph; ph.x = (u32)hx | ((u32)hy << 16); ph.y = (u32)hz | ((u32)hw << 16);
  *(uint2*)(Oh + (size_t)t * TDIM + tid * 4) = ph;
  u16 lx = f2bft(vx - bf2f(hx)), ly = f2bft(vy - bf2f(hy));
  u16 lz = f2bft(vz - bf2f(hz)), lw = f2bft(vw - bf2f(hw));
  uint2 pl; pl.x = (u32)lx | ((u32)ly << 16); pl.y = (u32)lz | ((u32)lw << 16);
  *(uint2*)(Ol + (size_t)t * TDIM + tid * 4) = pl;
}

// ---------- router (+ writes ffn-norm bf16): f32 logits from h, top-2, histogram ----------
__launch_bounds__(256)
__global__ void router_k(const float* __restrict__ hres, const float* __restrict__ wn,
                         const float* __restrict__ rw, u16* __restrict__ hn,
                         int* __restrict__ idx01, float* __restrict__ gate01,
                         int* __restrict__ counts) {
  const int t = blockIdx.x, tid = threadIdx.x;
  const float4 xv = ((const float4*)(hres + (size_t)t * TDIM))[tid];
  float ss = xv.x*xv.x + xv.y*xv.y + xv.z*xv.z + xv.w*xv.w;
#pragma unroll
  for (int d = 1; d < 64; d <<= 1) ss += __shfl_xor(ss, d, 64);
  __shared__ float sp[4];
  __shared__ float sacc[4][8];
  if ((tid & 63) == 0) sp[tid >> 6] = ss;
  __syncthreads();
  const float rsc = rsqrtf((sp[0]+sp[1]+sp[2]+sp[3]) * (1.0f / TDIM) + 1e-6f);
  const float4 wv = ((const float4*)wn)[tid];
  const float x0 = xv.x*rsc*wv.x, x1 = xv.y*rsc*wv.y, x2 = xv.z*rsc*wv.z, x3 = xv.w*rsc*wv.w;
  {
    u16 h0 = f2bf(x0), h1 = f2bf(x1), h2 = f2bf(x2), h3 = f2bf(x3);
    uint2 ph; ph.x = (u32)h0 | ((u32)h1 << 16); ph.y = (u32)h2 | ((u32)h3 << 16);
    *(uint2*)(hn + (size_t)t * TDIM + tid * 4) = ph;
  }
  const float* rp = rw + (size_t)(tid * 4) * TEXP;
  float acc[8];
#pragma unroll
  for (int e = 0; e < 8; e++) acc[e] = x0*rp[e] + x1*rp[8+e] + x2*rp[16+e] + x3*rp[24+e];
#pragma unroll
  for (int e = 0; e < 8; e++)
#pragma unroll
    for (int d = 1; d < 64; d <<= 1) acc[e] += __shfl_xor(acc[e], d, 64);
  if ((tid & 63) == 0)
#pragma unroll
    for (int e = 0; e < 8; e++) sacc[tid >> 6][e] = acc[e];
  __syncthreads();
  if (tid == 0) {
    float lg[8];
#pragma unroll
    for (int e = 0; e < 8; e++) lg[e] = sacc[0][e] + sacc[1][e] + sacc[2][e] + sacc[3][e];
    int i1 = 0;
#pragma unroll
    for (int e = 1; e < 8; e++) if (lg[e] > lg[i1]) i1 = e;
    int i2 = (i1 == 0) ? 1 : 0;
#pragma unroll
    for (int e = 0; e < 8; e++) if (e != i1 && lg[e] > lg[i2]) i2 = e;
    const float g1 = 1.0f / (1.0f + __expf(lg[i2] - lg[i1]));
    idx01[t*2] = i1; idx01[t*2+1] = i2;
    gate01[t*2] = g1; gate01[t*2+1] = 1.0f - g1;
    atomicAdd(&counts[i1], 1);
    atomicAdd(&counts[i2], 1);
  }
}

__global__ void zero8_k(int* counts) { if (threadIdx.x < TEXP) counts[threadIdx.x] = 0; }

__global__ void offsets_k(const int* __restrict__ counts, int* __restrict__ cursor,
                          int* __restrict__ bm_e, int* __restrict__ bm_s0,
                          int* __restrict__ bm_end, int* __restrict__ n_active) {
  if (threadIdx.x != 0 || blockIdx.x != 0) return;
  int off = 0, nb = 0;
  for (int e = 0; e < TEXP; e++) {
    const int c = counts[e];
    cursor[e] = off;
    const int end = off + c;
    for (int mb = 0; mb * 128 < c; mb++) { bm_e[nb] = e; bm_s0[nb] = off + mb * 128; bm_end[nb] = end; nb++; }
    off = end;
  }
  *n_active = nb;
}

__global__ void scatter_k(const int* __restrict__ idx01, int* __restrict__ cursor,
                          int* __restrict__ slot_of, int* __restrict__ perm) {
  const int t = blockIdx.x * 256 + threadIdx.x;
  if (t >= TTOK) return;
#pragma unroll
  for (int k = 0; k < 2; k++) {
    const int e = idx01[t*2+k];
    const int slot = atomicAdd(&cursor[e], 1);
    slot_of[t*2+k] = slot;
    perm[slot] = t;
  }
}

// ---------- MoE GEMM1: gathered rows, fused w1/w3, silu(z1)*z3 -> hbuf (dbuf + prefetch) ----------
__launch_bounds__(256)
__global__ void moe_gemm1_k(const u16* __restrict__ hn, const u16* __restrict__ w1t,
                            const u16* __restrict__ w3t, const int* __restrict__ perm,
                            const int* __restrict__ bm_e, const int* __restrict__ bm_s0,
                            const int* __restrict__ bm_end, const int* __restrict__ n_active,
                            u16* __restrict__ hbuf) {
  if ((int)blockIdx.x >= *n_active) return;
  __shared__ u16 sA[2][128 * 32], sB1[2][64 * 32], sB3[2][64 * 32];
  const int tid = threadIdx.x, wid = tid >> 6, lane = tid & 63;
  const int e = bm_e[blockIdx.x], slot0 = bm_s0[blockIdx.x], send = bm_end[blockIdx.x];
  const int n0 = blockIdx.y * 64;
  const int wr = wid >> 1, wc = wid & 1;
  const int srow = tid >> 2;
  const int scol = (((tid & 3) ^ ((tid >> 3) & 3)) * 8);
  const int sa0 = slot0 + srow, sa1 = slot0 + srow + 64;
  const int ta = (sa0 < send) ? perm[sa0] : 0;
  const int tb2 = (sa1 < send) ? perm[sa1] : 0;
  const size_t a0 = (size_t)ta * TDIM + scol;
  const size_t a1 = (size_t)tb2 * TDIM + scol;
  const size_t bb = (size_t)e * TDIM * TFF + (size_t)(n0 + srow) * TDIM + scol;
  const int ldsw = wid * 1024;
  f32x4 ac1[4][2], ac3[4][2];
#pragma unroll
  for (int i = 0; i < 4; i++)
#pragma unroll
    for (int j = 0; j < 2; j++) { ac1[i][j] = fzero(); ac3[i][j] = fzero(); }
  const int g = (lane >> 1) & 3;
  int aoffs[4], boffs[2];
#pragma unroll
  for (int mf = 0; mf < 4; mf++)
    aoffs[mf] = (wr*64 + mf*16 + (lane & 15)) * 64 + ((((lane >> 4)) ^ g) << 4);
#pragma unroll
  for (int nf = 0; nf < 2; nf++)
    boffs[nf] = (wc*32 + nf*16 + (lane & 15)) * 64 + ((((lane >> 4)) ^ g) << 4);

  auto stage = [&](int kk, int bi) {
    const int ke = kk * 32;
    gll16(hn + a0 + ke, (char*)sA[bi] + ldsw);
    gll16(hn + a1 + ke, (char*)sA[bi] + 4096 + ldsw);
    gll16(w1t + bb + ke, (char*)sB1[bi] + ldsw);
    gll16(w3t + bb + ke, (char*)sB3[bi] + ldsw);
  };

  stage(0, 0);
  asm volatile("s_waitcnt vmcnt(0)" ::: "memory");
  __builtin_amdgcn_s_barrier();

  for (int kk = 0; kk < 32; ++kk) {
    const int cur = kk & 1;
    if (kk + 1 < 32) stage(kk + 1, cur ^ 1);
    bf16x8 fa[4], f1[2], f3[2];
#pragma unroll
    for (int mf = 0; mf < 4; mf++) fa[mf] = ldsread((char*)sA[cur] + aoffs[mf]);
#pragma unroll
    for (int nf = 0; nf < 2; nf++) { f1[nf] = ldsread((char*)sB1[cur] + boffs[nf]); f3[nf] = ldsread((char*)sB3[cur] + boffs[nf]); }
#pragma unroll
    for (int mf = 0; mf < 4; mf++)
#pragma unroll
      for (int nf = 0; nf < 2; nf++) {
        ac1[mf][nf] = mm16(fa[mf], f1[nf], ac1[mf][nf]);
        ac3[mf][nf] = mm16(fa[mf], f3[nf], ac3[mf][nf]);
      }
    asm volatile("s_waitcnt vmcnt(0)" ::: "memory");
    __builtin_amdgcn_s_barrier();
  }

#pragma unroll
  for (int mf = 0; mf < 4; mf++)
#pragma unroll
    for (int nf = 0; nf < 2; nf++)
#pragma unroll
      for (int r = 0; r < 4; r++) {
        const int slot = slot0 + wr*64 + mf*16 + ((lane >> 4) * 4) + r;
        if (slot < send) {
          const int col = n0 + wc*32 + nf*16 + (lane & 15);
          const float z1 = ac1[mf][nf][r], z3 = ac3[mf][nf][r];
          const float hv = z1 / (1.0f + __expf(-z1)) * z3;
          hbuf[(size_t)slot * TFF + col] = f2bf(hv);
        }
      }
}

// ---------- MoE GEMM2: hbuf @ w2 -> pair outputs (dbuf + prefetch) ----------
__launch_bounds__(256)
__global__ void moe_gemm2_k(const u16* __restrict__ hbuf, const u16* __restrict__ w2t,
                            const int* __restrict__ bm_e, const int* __restrict__ bm_s0,
                            const int* __restrict__ bm_end, const int* __restrict__ n_active,
                            u16* __restrict__ pout) {
  if ((int)blockIdx.x >= *n_active) return;
  __shared__ u16 sA[2][128 * 32], sB[2][64 * 32];
  const int tid = threadIdx.x, wid = tid >> 6, lane = tid & 63;
  const int e = bm_e[blockIdx.x], slot0 = bm_s0[blockIdx.x], send = bm_end[blockIdx.x];
  const int n0 = blockIdx.y * 64;
  const int wr = wid >> 1, wc = wid & 1;
  const int srow = tid >> 2;
  const int scol = (((tid & 3) ^ ((tid >> 3) & 3)) * 8);
  int sa0 = slot0 + srow; if (sa0 > TPAIRS - 1) sa0 = TPAIRS - 1;
  int sa1 = slot0 + srow + 64; if (sa1 > TPAIRS - 1) sa1 = TPAIRS - 1;
  const size_t a0 = (size_t)sa0 * TFF + scol;
  const size_t a1 = (size_t)sa1 * TFF + scol;
  const size_t bb = (size_t)e * TDIM * TFF + (size_t)(n0 + srow) * TFF + scol;
  const int ldsw = wid * 1024;
  f32x4 acc[4][2];
#pragma unroll
  for (int i = 0; i < 4; i++)
#pragma unroll
    for (int j = 0; j < 2; j++) acc[i][j] = fzero();
  const int g = (lane >> 1) & 3;
  int aoffs[4], boffs[2];
#pragma unroll
  for (int mf = 0; mf < 4; mf++)
    aoffs[mf] = (wr*64 + mf*16 + (lane & 15)) * 64 + ((((lane >> 4)) ^ g) << 4);
#pragma unroll
  for (int nf = 0; nf < 2; nf++)
    boffs[nf] = (wc*32 + nf*16 + (lane & 15)) * 64 + ((((lane >> 4)) ^ g) << 4);

  auto stage = [&](int kk, int bi) {
    const int ke = kk * 32;
    gll16(hbuf + a0 + ke, (char*)sA[bi] + ldsw);
    gll16(hbuf + a1 + ke, (char*)sA[bi] + 4096 + ldsw);
    gll16(w2t + bb + ke, (char*)sB[bi] + ldsw);
  };

  stage(0, 0);
  asm volatile("s_waitcnt vmcnt(0)" ::: "memory");
  __builtin_amdgcn_s_barrier();

  for (int kk = 0; kk < 32; ++kk) {
    const int cur = kk & 1;
    if (kk + 1 < 32) stage(kk + 1, cur ^ 1);
    bf16x8 fa[4], fb[2];
#pragma unroll
    for (int mf = 0; mf < 4; mf++) fa[mf] = ldsread((char*)sA[cur] + aoffs[mf]);
#pragma unroll
    for (int nf = 0; nf < 2; nf++) fb[nf] = ldsread((char*)sB[cur] + boffs[nf]);
#pragma unroll
    for (int mf = 0; mf < 4; mf++)
#pragma unroll
      for (int nf = 0; nf < 2; nf++)
        acc[mf][nf] = mm16(fa[mf], fb[nf], acc[mf][nf]);
    asm volatile("s_waitcnt vmcnt(0)" ::: "memory");
    __builtin_amdgcn_s_barrier();
  }

#pragma unroll
  for (int mf = 0; mf < 4; mf++)
#pragma unroll
    for (int nf = 0; nf < 2; nf++)
#pragma unroll
      for (int r = 0; r < 4; r++) {
        const int slot = slot0 + wr*64 + mf*16 + ((lane >> 4) * 4) + r;
        if (slot < send) {
          const int col = n0 + wc*32 + nf*16 + (lane & 15);
          pout[(size_t)slot * TDIM + col] = f2bf(acc[mf][nf][r]);
        }
      }
}

// ---------- final combine: out = h + g0*pout[s0] + g1*pout[s1] ----------
__launch_bounds__(256)
__global__ void combine_k(const float* __restrict__ hres, const u16* __restrict__ pout,
                          const int* __restrict__ slot_of, const float* __restrict__ gate01,
                          float* __restrict__ out) {
  const int t = blockIdx.x, tid = threadIdx.x;
  const int s0 = slot_of[t*2], s1 = slot_of[t*2+1];
  const float g0 = gate01[t*2], g1 = gate01[t*2+1];
  const float4 hv = ((const float4*)(hres + (size_t)t * TDIM))[tid];
  const uint2 u0 = *(const uint2*)(pout + (size_t)s0 * TDIM + tid * 4);
  const uint2 u1 = *(const uint2*)(pout + (size_t)s1 * TDIM + tid * 4);
  float4 o;
  o.x = hv.x + g0 * bf2f((u16)(u0.x & 0xffff)) + g1 * bf2f((u16)(u1.x & 0xffff));
  o.y = hv.y + g0 * bf2f((u16)(u0.x >> 16))    + g1 * bf2f((u16)(u1.x >> 16));
  o.z = hv.z + g0 * bf2f((u16)(u0.y & 0xffff)) + g1 * bf2f((u16)(u1.y & 0xffff));
  o.w = hv.w + g0 * bf2f((u16)(u0.y >> 16))    + g1 * bf2f((u16)(u1.y >> 16));
  ((float4*)(out + (size_t)t * TDIM))[tid] = o;
}

extern "C" void kernel_launch(void* const* d_in, const int* in_sizes, int n_in,
                              void* d_out, int out_size, void* d_ws, size_t ws_size,
                              hipStream_t stream) {
  (void)in_sizes; (void)n_in; (void)out_size; (void)ws_size;
  const float* x   = (const float*)d_in[0];
  const float* anw = (const float*)d_in[1];
  const float* wq  = (const float*)d_in[2];
  const float* wk  = (const float*)d_in[3];
  const float* wv  = (const float*)d_in[4];
  const float* wo  = (const float*)d_in[5];
  const float* fnw = (const float*)d_in[6];
  const float* rw  = (const float*)d_in[7];
  const float* w1  = (const float*)d_in[8];
  const float* w3  = (const float*)d_in[9];
  const float* w2  = (const float*)d_in[10];
  float* out = (float*)d_out;

  char* ws = (char*)d_ws;
  size_t off = 0;
  auto take = [&](size_t bytes) -> char* {
    char* p = ws + off;
    off += (bytes + 255) & ~(size_t)255;
    return p;
  };
  const size_t SZ_W = (size_t)TDIM * TDIM * sizeof(u16);
  const size_t SZ_T = (size_t)TTOK * TDIM * sizeof(u16);
  u16* wqt_h = (u16*)take(SZ_W); u16* wqt_l = (u16*)take(SZ_W);
  u16* wkt_h = (u16*)take(SZ_W); u16* wkt_l = (u16*)take(SZ_W);
  u16* wvt_h = (u16*)take(SZ_W); u16* wvt_l = (u16*)take(SZ_W);
  u16* wot_h = (u16*)take(SZ_W); u16* wot_l = (u16*)take(SZ_W);
  u16* w1t = (u16*)take((size_t)TEXP * TDIM * TFF * sizeof(u16));
  u16* w3t = (u16*)take((size_t)TEXP * TDIM * TFF * sizeof(u16));
  u16* w2t = (u16*)take((size_t)TEXP * TDIM * TFF * sizeof(u16));
  u16* xnh = (u16*)take(SZ_T); u16* xnl = (u16*)take(SZ_T);
  u16* qh  = (u16*)take(SZ_T); u16* ql  = (u16*)take(SZ_T);
  u16* kh  = (u16*)take(SZ_T); u16* kl  = (u16*)take(SZ_T);
  u16* vth = (u16*)take(SZ_T); u16* vtl = (u16*)take(SZ_T);
  float* hres = (float*)take((size_t)TTOK * TDIM * sizeof(float));
  float* opart = (float*)take((size_t)2 * TTOK * TDIM * sizeof(float));   // split-KV partial O
  float* mlbuf = (float*)take((size_t)2 * TTOK * THEADS * 2 * sizeof(float));
  int*   idx01  = (int*)take(TTOK * 2 * 4);
  float* gate01 = (float*)take(TTOK * 2 * 4);
  int*   slot_of = (int*)take(TTOK * 2 * 4);
  int*   perm    = (int*)take(TPAIRS * 4);
  int*   counts  = (int*)take(256);
  int*   cursor  = (int*)take(256);
  int*   bm_e    = (int*)take(96 * 4);
  int*   bm_s0   = (int*)take(96 * 4);
  int*   bm_end  = (int*)take(96 * 4);
  int*   n_act   = (int*)take(256);
  u16* oh = xnh; u16* ol = xnl;
  u16* hn = qh;
  u16* hbuf = kh;
  u16* pout = vth;

  transpose_all_k<<<28672, dim3(32, 8), 0, stream>>>(wq, wk, wv, wo, w1, w3, w2,
                                                     wqt_h, wqt_l, wkt_h, wkt_l, wvt_h, wvt_l,
                                                     wot_h, wot_l, w1t, w3t, w2t);
  zero8_k<<<1, 64, 0, stream>>>(counts);
  rmsnorm_k<<<TTOK, 256, 0, stream>>>(x, anw, xnh, xnl);
  gemm_qkv_k<<<dim3(TTOK/128, 48), 256, 0, stream>>>(xnh, xnl, wqt_h, wqt_l, wkt_h, wkt_l,
                                                     wvt_h, wvt_l, qh, ql, kh, kl, vth, vtl);
  flash_k<<<dim3(TSEQ/128, TBATCH*THEADS, 2), 256, 0, stream>>>(qh, ql, kh, kl, vth, vtl, opart, mlbuf);
  flash_comb_k<<<TTOK, 256, 0, stream>>>(opart, mlbuf, oh, ol);
  gemm_x3_k<2><<<dim3(TTOK/128, TDIM/64), 256, 0, stream>>>(oh, ol, wot_h, wot_l, nullptr, nullptr, hres, x, TTOK, TDIM, TDIM);
  router_k<<<TTOK, 256, 0, stream>>>(hres, fnw, rw, hn, idx01, gate01, counts);
  offsets_k<<<1, 1, 0, stream>>>(counts, cursor, bm_e, bm_s0, bm_end, n_act);
  scatter_k<<<TTOK/256, 256, 0, stream>>>(idx01, cursor, slot_of, perm);
  moe_gemm1_k<<<dim3(72, TFF/64), 256, 0, stream>>>(hn, w1t, w3t, perm, bm_e, bm_s0, bm_end, n_act, hbuf);
  moe_gemm2_k<<<dim3(72, TDIM/64), 256, 0, stream>>>(hbuf, w2t, bm_e, bm_s0, bm_end, n_act, pout);
  combine_k<<<TTOK, 256, 0, stream>>>(hres, pout, slot_of, gate01, out);
}

// Round 26
// 621.495 us; speedup vs baseline: 1.2781x; 1.2781x over previous
//
#include <hip/hip_runtime.h>
#include <cstdint>
#include <math.h>

typedef unsigned short u16;
typedef unsigned int u32;
typedef __bf16 bf16x8 __attribute__((ext_vector_type(8)));
typedef float f32x4 __attribute__((ext_vector_type(4)));

#define TBATCH 2
#define TSEQ   2048
#define TDIM   1024
#define THEADS 16
#define THDIM  64
#define TEXP   8
#define TFF    1024
#define TTOK   (TBATCH*TSEQ)
#define TPAIRS (TTOK*2)

__device__ __forceinline__ u16 f2bf(float f) {
  u32 u = __float_as_uint(f);
  u += 0x7FFFu + ((u >> 16) & 1u);
  return (u16)(u >> 16);
}
__device__ __forceinline__ u16 f2bft(float f) {        // truncating split (1 op)
  return (u16)(__float_as_uint(f) >> 16);
}
__device__ __forceinline__ float bf2f(u16 h) { return __uint_as_float(((u32)h) << 16); }
__device__ __forceinline__ float fexp2(float x) {      // raw v_exp_f32 (exp2)
  float r;
  asm("v_exp_f32 %0, %1" : "=v"(r) : "v"(x));
  return r;
}

__device__ __forceinline__ void gll16(const void* g, void* l) {
  __builtin_amdgcn_global_load_lds((const __attribute__((address_space(1))) void*)g,
                                   (__attribute__((address_space(3))) void*)l, 16, 0, 0);
}
__device__ __forceinline__ bf16x8 ldsread(const void* p) { return *(const bf16x8*)p; }
__device__ __forceinline__ f32x4 mm16(bf16x8 a, bf16x8 b, f32x4 c) {
  return __builtin_amdgcn_mfma_f32_16x16x32_bf16(a, b, c, 0, 0, 0);
}
__device__ __forceinline__ f32x4 fzero() { f32x4 z = {0.f, 0.f, 0.f, 0.f}; return z; }

// ---------- ALL weight transposes in ONE launch: f32 [z][1024][1024] -> bf16 [z][1024][1024]^T ----------
__global__ void transpose_all_k(const float* __restrict__ wq, const float* __restrict__ wk,
                                const float* __restrict__ wv, const float* __restrict__ wo,
                                const float* __restrict__ w1, const float* __restrict__ w3,
                                const float* __restrict__ w2,
                                u16* __restrict__ qth, u16* __restrict__ qtl,
                                u16* __restrict__ kth, u16* __restrict__ ktl,
                                u16* __restrict__ vth_, u16* __restrict__ vtl_,
                                u16* __restrict__ oth, u16* __restrict__ otl,
                                u16* __restrict__ w1t, u16* __restrict__ w3t, u16* __restrict__ w2t) {
  __shared__ float t[32][33];
  int id = (int)blockIdx.x;
  const float* in; u16* outh; u16* outl = nullptr;
  size_t bo = 0;
  int tile;
  if (id < 4096) {
    const int wi = id >> 10;
    in   = (wi == 0) ? wq  : (wi == 1) ? wk  : (wi == 2) ? wv   : wo;
    outh = (wi == 0) ? qth : (wi == 1) ? kth : (wi == 2) ? vth_ : oth;
    outl = (wi == 0) ? qtl : (wi == 1) ? ktl : (wi == 2) ? vtl_ : otl;
    tile = id & 1023;
  } else {
    const int id2 = id - 4096;
    const int wi = id2 >> 13;                 // 0=w1 1=w3 2=w2
    const int rem = id2 & 8191;
    bo = (size_t)(rem >> 10) << 20;           // z * 1024*1024
    in   = (wi == 0) ? w1  : (wi == 1) ? w3  : w2;
    outh = (wi == 0) ? w1t : (wi == 1) ? w3t : w2t;
    tile = rem & 1023;
  }
  const int c0 = (tile & 31) * 32, r0 = (tile >> 5) * 32;
  const int tx = threadIdx.x, ty = threadIdx.y;
#pragma unroll
  for (int j = 0; j < 32; j += 8)
    t[ty + j][tx] = in[bo + (size_t)(r0 + ty + j) * 1024 + (c0 + tx)];
  __syncthreads();
#pragma unroll
  for (int j = 0; j < 32; j += 8) {
    float v = t[tx][ty + j];
    u16 hv = f2bf(v);
    size_t o = bo + (size_t)(c0 + ty + j) * 1024 + (r0 + tx);
    outh[o] = hv;
    if (outl != nullptr) outl[o] = f2bf(v - bf2f(hv));
  }
}

// ---------- RMSNorm: f32 [T][D] -> bf16 split (attn input) ----------
__launch_bounds__(256)
__global__ void rmsnorm_k(const float* __restrict__ x, const float* __restrict__ w,
                          u16* __restrict__ oh, u16* __restrict__ ol) {
  const int t = blockIdx.x, tid = threadIdx.x;
  const float4 xv = ((const float4*)(x + (size_t)t * TDIM))[tid];
  float ss = xv.x*xv.x + xv.y*xv.y + xv.z*xv.z + xv.w*xv.w;
#pragma unroll
  for (int d = 1; d < 64; d <<= 1) ss += __shfl_xor(ss, d, 64);
  __shared__ float sp[4];
  if ((tid & 63) == 0) sp[tid >> 6] = ss;
  __syncthreads();
  const float rsc = rsqrtf((sp[0] + sp[1] + sp[2] + sp[3]) * (1.0f / TDIM) + 1e-6f);
  const float4 wv = ((const float4*)w)[tid];
  float v0 = xv.x*rsc*wv.x, v1 = xv.y*rsc*wv.y, v2 = xv.z*rsc*wv.z, v3 = xv.w*rsc*wv.w;
  u16 h0 = f2bf(v0), h1 = f2bf(v1), h2 = f2bf(v2), h3 = f2bf(v3);
  uint2 ph; ph.x = (u32)h0 | ((u32)h1 << 16); ph.y = (u32)h2 | ((u32)h3 << 16);
  *(uint2*)(oh + (size_t)t * TDIM + tid * 4) = ph;
  u16 l0 = f2bf(v0 - bf2f(h0)), l1 = f2bf(v1 - bf2f(h1));
  u16 l2 = f2bf(v2 - bf2f(h2)), l3 = f2bf(v3 - bf2f(h3));
  uint2 pl; pl.x = (u32)l0 | ((u32)l1 << 16); pl.y = (u32)l2 | ((u32)l3 << 16);
  *(uint2*)(ol + (size_t)t * TDIM + tid * 4) = pl;
}

// ---------- fused QKV bf16x3 GEMM: one launch, blockIdx.y selects Q/K/V (grid 32 x 48) ----------
// Q output is pre-scaled by 1/sqrt(HD)*log2(e) so flash_k's softmax works directly in exp2 domain.
__launch_bounds__(256)
__global__ void gemm_qkv_k(const u16* __restrict__ Ah, const u16* __restrict__ Al,
                           const u16* __restrict__ Bqh, const u16* __restrict__ Bql,
                           const u16* __restrict__ Bkh, const u16* __restrict__ Bkl,
                           const u16* __restrict__ Bvh, const u16* __restrict__ Bvl,
                           u16* __restrict__ qh, u16* __restrict__ ql,
                           u16* __restrict__ kh, u16* __restrict__ kl,
                           u16* __restrict__ vth, u16* __restrict__ vtl) {
  __shared__ u16 sAh[2][128 * 32], sAl[2][128 * 32], sBh[2][64 * 32], sBl[2][64 * 32];
  const int tid = threadIdx.x, wid = tid >> 6, lane = tid & 63;
  const int which = blockIdx.y >> 4;                 // 0=Q 1=K 2=V (block-uniform)
  const int m0 = blockIdx.x * 128, n0 = (blockIdx.y & 15) * 64;
  const int wr = wid >> 1, wc = wid & 1;
  const u16* Bth = (which == 0) ? Bqh : (which == 1) ? Bkh : Bvh;
  const u16* Btl = (which == 0) ? Bql : (which == 1) ? Bkl : Bvl;
  u16* outh = (which == 0) ? qh : kh;
  u16* outl = (which == 0) ? ql : kl;

  f32x4 acc[4][2];
#pragma unroll
  for (int i = 0; i < 4; i++)
#pragma unroll
    for (int j = 0; j < 2; j++) acc[i][j] = fzero();

  const int srow = tid >> 2;
  const int scol = (((tid & 3) ^ ((tid >> 3) & 3)) * 8);
  const size_t a0 = (size_t)(m0 + srow) * TDIM + scol;
  const size_t a1 = (size_t)(m0 + srow + 64) * TDIM + scol;
  const size_t b0 = (size_t)(n0 + srow) * TDIM + scol;
  const int ldsw = wid * 1024;

  const int g = (lane >> 1) & 3;
  int aoffs[4], boffs[2];
#pragma unroll
  for (int mf = 0; mf < 4; mf++)
    aoffs[mf] = (wr*64 + mf*16 + (lane & 15)) * 64 + ((((lane >> 4)) ^ g) << 4);
#pragma unroll
  for (int nf = 0; nf < 2; nf++)
    boffs[nf] = (wc*32 + nf*16 + (lane & 15)) * 64 + ((((lane >> 4)) ^ g) << 4);

  auto stage = [&](int kk, int bi) {
    const int ke = kk * 32;
    gll16(Ah + a0 + ke, (char*)sAh[bi] + ldsw);
    gll16(Ah + a1 + ke, (char*)sAh[bi] + 4096 + ldsw);
    gll16(Al + a0 + ke, (char*)sAl[bi] + ldsw);
    gll16(Al + a1 + ke, (char*)sAl[bi] + 4096 + ldsw);
    gll16(Bth + b0 + ke, (char*)sBh[bi] + ldsw);
    gll16(Btl + b0 + ke, (char*)sBl[bi] + ldsw);
  };

  stage(0, 0);
  asm volatile("s_waitcnt vmcnt(0)" ::: "memory");
  __builtin_amdgcn_s_barrier();

  for (int kk = 0; kk < 32; ++kk) {
    const int cur = kk & 1;
    if (kk + 1 < 32) stage(kk + 1, cur ^ 1);
    bf16x8 fah[4], fal[4], fbh[2], fbl[2];
#pragma unroll
    for (int mf = 0; mf < 4; mf++) { fah[mf] = ldsread((char*)sAh[cur] + aoffs[mf]); fal[mf] = ldsread((char*)sAl[cur] + aoffs[mf]); }
#pragma unroll
    for (int nf = 0; nf < 2; nf++) { fbh[nf] = ldsread((char*)sBh[cur] + boffs[nf]); fbl[nf] = ldsread((char*)sBl[cur] + boffs[nf]); }
#pragma unroll
    for (int mf = 0; mf < 4; mf++)
#pragma unroll
      for (int nf = 0; nf < 2; nf++) {
        acc[mf][nf] = mm16(fah[mf], fbh[nf], acc[mf][nf]);
        acc[mf][nf] = mm16(fah[mf], fbl[nf], acc[mf][nf]);
        acc[mf][nf] = mm16(fal[mf], fbh[nf], acc[mf][nf]);
      }
    asm volatile("s_waitcnt vmcnt(0)" ::: "memory");
    __builtin_amdgcn_s_barrier();
  }

  const float qscale = (which == 0) ? 0.18033688011112042f : 1.0f;  // 0.125 * log2(e)
#pragma unroll
  for (int mf = 0; mf < 4; mf++)
#pragma unroll
    for (int nf = 0; nf < 2; nf++)
#pragma unroll
      for (int r = 0; r < 4; r++) {
        const int grow = m0 + wr*64 + mf*16 + ((lane >> 4) * 4) + r;
        const int gcol = n0 + wc*32 + nf*16 + (lane & 15);
        const float v = acc[mf][nf][r] * qscale;
        u16 hv = f2bf(v);
        u16 lv = f2bf(v - bf2f(hv));
        if (which < 2) {
          const size_t o = (size_t)grow * TDIM + gcol;
          outh[o] = hv; outl[o] = lv;
        } else {
          const int b = grow >> 11, s = grow & (TSEQ - 1);
          const int hh = gcol >> 6, hd = gcol & 63;
          const size_t o = ((size_t)((b * THEADS + hh) * THDIM + hd)) * TSEQ + s;
          vth[o] = hv; vtl[o] = lv;
        }
      }
}

// ---------- bf16x3 GEMM (WO): 2-buffer + prefetch; EPI2 = f32 out + resid ----------
template<int EPI>
__launch_bounds__(256)
__global__ void gemm_x3_k(const u16* __restrict__ Ah, const u16* __restrict__ Al,
                          const u16* __restrict__ Bth, const u16* __restrict__ Btl,
                          u16* __restrict__ outh, u16* __restrict__ outl,
                          float* __restrict__ outf, const float* __restrict__ resid,
                          int M, int N, int K) {
  __shared__ u16 sAh[2][128 * 32], sAl[2][128 * 32], sBh[2][64 * 32], sBl[2][64 * 32];
  const int tid = threadIdx.x, wid = tid >> 6, lane = tid & 63;
  const int m0 = blockIdx.x * 128, n0 = blockIdx.y * 64;
  const int wr = wid >> 1, wc = wid & 1;

  f32x4 acc[4][2];
#pragma unroll
  for (int i = 0; i < 4; i++)
#pragma unroll
    for (int j = 0; j < 2; j++) acc[i][j] = fzero();

  const int srow = tid >> 2;
  const int scol = (((tid & 3) ^ ((tid >> 3) & 3)) * 8);
  const size_t a0 = (size_t)(m0 + srow) * K + scol;
  const size_t a1 = (size_t)(m0 + srow + 64) * K + scol;
  const size_t b0 = (size_t)(n0 + srow) * K + scol;
  const int ldsw = wid * 1024;

  const int g = (lane >> 1) & 3;
  int aoffs[4], boffs[2];
#pragma unroll
  for (int mf = 0; mf < 4; mf++)
    aoffs[mf] = (wr*64 + mf*16 + (lane & 15)) * 64 + ((((lane >> 4)) ^ g) << 4);
#pragma unroll
  for (int nf = 0; nf < 2; nf++)
    boffs[nf] = (wc*32 + nf*16 + (lane & 15)) * 64 + ((((lane >> 4)) ^ g) << 4);

  auto stage = [&](int kk, int bi) {
    const int ke = kk * 32;
    gll16(Ah + a0 + ke, (char*)sAh[bi] + ldsw);
    gll16(Ah + a1 + ke, (char*)sAh[bi] + 4096 + ldsw);
    gll16(Al + a0 + ke, (char*)sAl[bi] + ldsw);
    gll16(Al + a1 + ke, (char*)sAl[bi] + 4096 + ldsw);
    gll16(Bth + b0 + ke, (char*)sBh[bi] + ldsw);
    gll16(Btl + b0 + ke, (char*)sBl[bi] + ldsw);
  };

  const int nk = K >> 5;
  stage(0, 0);
  asm volatile("s_waitcnt vmcnt(0)" ::: "memory");
  __builtin_amdgcn_s_barrier();

  for (int kk = 0; kk < nk; ++kk) {
    const int cur = kk & 1;
    if (kk + 1 < nk) stage(kk + 1, cur ^ 1);
    bf16x8 fah[4], fal[4], fbh[2], fbl[2];
#pragma unroll
    for (int mf = 0; mf < 4; mf++) { fah[mf] = ldsread((char*)sAh[cur] + aoffs[mf]); fal[mf] = ldsread((char*)sAl[cur] + aoffs[mf]); }
#pragma unroll
    for (int nf = 0; nf < 2; nf++) { fbh[nf] = ldsread((char*)sBh[cur] + boffs[nf]); fbl[nf] = ldsread((char*)sBl[cur] + boffs[nf]); }
#pragma unroll
    for (int mf = 0; mf < 4; mf++)
#pragma unroll
      for (int nf = 0; nf < 2; nf++) {
        acc[mf][nf] = mm16(fah[mf], fbh[nf], acc[mf][nf]);
        acc[mf][nf] = mm16(fah[mf], fbl[nf], acc[mf][nf]);
        acc[mf][nf] = mm16(fal[mf], fbh[nf], acc[mf][nf]);
      }
    asm volatile("s_waitcnt vmcnt(0)" ::: "memory");
    __builtin_amdgcn_s_barrier();
  }

#pragma unroll
  for (int mf = 0; mf < 4; mf++)
#pragma unroll
    for (int nf = 0; nf < 2; nf++)
#pragma unroll
      for (int r = 0; r < 4; r++) {
        const int grow = m0 + wr*64 + mf*16 + ((lane >> 4) * 4) + r;
        const int gcol = n0 + wc*32 + nf*16 + (lane & 15);
        const float v = acc[mf][nf][r];
        if (EPI == 0) {
          const size_t o = (size_t)grow * N + gcol;
          u16 hv = f2bf(v);
          outh[o] = hv; outl[o] = f2bf(v - bf2f(hv));
        } else if (EPI == 1) {
          const int b = grow >> 11, s = grow & (TSEQ - 1);
          const int hh = gcol >> 6, hd = gcol & 63;
          const size_t o = ((size_t)((b * THEADS + hh) * THDIM + hd)) * TSEQ + s;
          u16 hv = f2bf(v);
          outh[o] = hv; outl[o] = f2bf(v - bf2f(hv));
        } else {
          const size_t o = (size_t)grow * N + gcol;
          outf[o] = v + resid[o];
        }
      }
}

// ---------- causal flash attention, split-KV(2), KVBLK=32, 40KB LDS, VGPR-capped (no spill) ----------
__launch_bounds__(256, 3)
__global__ void flash_k(const u16* __restrict__ Qh, const u16* __restrict__ Ql,
                        const u16* __restrict__ Kh, const u16* __restrict__ Kl,
                        const u16* __restrict__ Vth, const u16* __restrict__ Vtl,
                        float* __restrict__ Op, float* __restrict__ ml) {
  __shared__ u16 sK[2][2][2048];   // [buf][hi/lo][32x64] rows 128B, 16KB
  __shared__ u16 sV[2][2][2048];   // [buf][hi/lo][64x32] rows 64B, 16KB
  __shared__ u16 sP[2][4][512];    // [hi/lo][warp][16x32] rows 64B, 8KB
  const int tid = threadIdx.x, wid = tid >> 6, lane = tid & 63;
  const int qb = (int)(gridDim.x - 1 - blockIdx.x);   // longest-first
  const int bh = blockIdx.y;
  const int b = bh >> 4, h = bh & 15;
  const int sp = blockIdx.z;                          // KV split index (0/1)

  // Q fragments for both 64-row halves (Q pre-scaled by 0.125*log2(e) in gemm_qkv_k)
  bf16x8 fqh[2][2], fql[2][2];
#pragma unroll
  for (int hh = 0; hh < 2; hh++) {
    const size_t qbase = ((size_t)(b * TSEQ + qb * 128 + hh * 64 + wid * 16 + (lane & 15))) * TDIM + h * 64;
#pragma unroll
    for (int kq = 0; kq < 2; kq++) {
      fqh[hh][kq] = *(const bf16x8*)(Qh + qbase + (kq * 4 + (lane >> 4)) * 8);
      fql[hh][kq] = *(const bf16x8*)(Ql + qbase + (kq * 4 + (lane >> 4)) * 8);
    }
  }

  f32x4 oacc[2][4];
  float m_run[2][4], l_lane[2][4];
#pragma unroll
  for (int hh = 0; hh < 2; hh++)
#pragma unroll
    for (int i = 0; i < 4; i++) { oacc[hh][i] = fzero(); m_run[hh][i] = -INFINITY; l_lane[hh][i] = 0.f; }

  // K staging: 32 tokens x 64 d (128B rows), pre-swizzled global col (8 chunks, key=row&7)
  const int ksrow = tid >> 3;
  const int ksxcol = (((lane & 7) ^ ((lane >> 3) & 7)) << 3);
  const size_t kg0 = ((size_t)(b * TSEQ + ksrow)) * TDIM + h * 64 + ksxcol;
  // V staging: 64 d x 32 s (64B rows), pre-swizzled global s-col (4 chunks, key=(row>>1)&3)
  const int vsrow = tid >> 2;
  const int vsxcol = (((tid & 3) ^ ((tid >> 3) & 3)) << 3);
  const size_t vg0 = ((size_t)((b * THEADS + h) * THDIM + vsrow)) * TSEQ + vsxcol;

  auto stage = [&](int kb, int bi) {
    const size_t ko = (size_t)kb * 32 * TDIM;
    const size_t vo = (size_t)kb * 32;
    const int wofs = wid * 1024;               // 64 lanes * 16B per wave
    gll16(Kh + kg0 + ko, (char*)sK[bi][0] + wofs);
    gll16(Kl + kg0 + ko, (char*)sK[bi][1] + wofs);
    gll16(Vth + vg0 + vo, (char*)sV[bi][0] + wofs);
    gll16(Vtl + vg0 + vo, (char*)sV[bi][1] + wofs);
  };

  const int nhalf = 2 * qb + 2;                // tiles per split
  const int kb0 = sp * nhalf, kb1 = kb0 + nhalf;
  stage(kb0, 0);
  asm volatile("s_waitcnt vmcnt(0)" ::: "memory");
  __builtin_amdgcn_s_barrier();

  for (int kb = kb0; kb < kb1; ++kb) {
    const int cur = (kb - kb0) & 1;
    if (kb + 1 < kb1) stage(kb + 1, cur ^ 1);

    const bool act0 = (kb * 32 <= qb * 128 + 63);   // hh=0 tile not fully masked; hh=1 always active

    // QK^T for BOTH halves, sharing each K-fragment read (2 nf x 2 kq x hi/lo = 8 reads)
    f32x4 sc[2][2];
    __builtin_amdgcn_s_setprio(1);
#pragma unroll
    for (int nf = 0; nf < 2; nf++) {
      f32x4 s0 = fzero(), s1 = fzero();
      const int krow = nf * 16 + (lane & 15);
#pragma unroll
      for (int kq = 0; kq < 2; kq++) {
        const int off = krow * 128 + (((kq * 4 + (lane >> 4)) ^ (lane & 7)) << 4);
        bf16x8 kfh = ldsread((char*)sK[cur][0] + off);
        bf16x8 kfl = ldsread((char*)sK[cur][1] + off);
        s0 = mm16(fqh[0][kq], kfh, s0);
        s0 = mm16(fqh[0][kq], kfl, s0);
        s0 = mm16(fql[0][kq], kfh, s0);
        s1 = mm16(fqh[1][kq], kfh, s1);
        s1 = mm16(fqh[1][kq], kfl, s1);
        s1 = mm16(fql[1][kq], kfh, s1);
      }
      sc[0][nf] = s0; sc[1][nf] = s1;
    }
    __builtin_amdgcn_s_setprio(0);

    bf16x8 pa_h[2], pa_l[2];
#pragma unroll
    for (int hh = 0; hh < 2; hh++) {
      if (hh == 0 && !act0) continue;

      const int qg = qb * 128 + hh * 64 + wid * 16 + ((lane >> 4) * 4);
      float pm[4] = {-INFINITY, -INFINITY, -INFINITY, -INFINITY};
#pragma unroll
      for (int nf = 0; nf < 2; nf++) {
        const int kg = kb * 32 + nf * 16 + (lane & 15);
#pragma unroll
        for (int r = 0; r < 4; r++) {
          float v = sc[hh][nf][r];               // already exp2-domain (Q pre-scaled)
          if (kg > qg + r) v = -INFINITY;
          sc[hh][nf][r] = v;
          pm[r] = fmaxf(pm[r], v);
        }
      }
#pragma unroll
      for (int r = 0; r < 4; r++)
#pragma unroll
        for (int d = 1; d < 16; d <<= 1) pm[r] = fmaxf(pm[r], __shfl_xor(pm[r], d, 64));

      // defer-max (T13): skip O/l rescale when tile max within 8 (exp2-domain) of running max.
      const float dm = fmaxf(fmaxf(pm[0] - m_run[hh][0], pm[1] - m_run[hh][1]),
                             fmaxf(pm[2] - m_run[hh][2], pm[3] - m_run[hh][3]));
      if (!__all(dm <= 8.0f)) {
#pragma unroll
        for (int r = 0; r < 4; r++) {
          const float mn = fmaxf(m_run[hh][r], pm[r]);
          const float esc = fexp2(m_run[hh][r] - mn);
          m_run[hh][r] = mn;
          l_lane[hh][r] *= esc;
#pragma unroll
          for (int nf = 0; nf < 4; nf++) oacc[hh][nf][r] *= esc;
        }
      }
      float ls[4] = {0.f, 0.f, 0.f, 0.f};
#pragma unroll
      for (int nf = 0; nf < 2; nf++)
#pragma unroll
        for (int r = 0; r < 4; r++) {
          float p = fexp2(sc[hh][nf][r] - m_run[hh][r]);
          sc[hh][nf][r] = p;
          ls[r] += p;
        }
#pragma unroll
      for (int r = 0; r < 4; r++) l_lane[hh][r] += ls[r];

      // P store (16x32 per warp, 64B rows, chunk-XOR swizzle; per-warp private, no barrier)
#pragma unroll
      for (int nf = 0; nf < 2; nf++)
#pragma unroll
        for (int r = 0; r < 4; r++) {
          float p = sc[hh][nf][r];
          u16 ph = f2bft(p);
          const int prow = (lane >> 4) * 4 + r;
          const int pbyte = (prow * 64 + (nf * 16 + (lane & 15)) * 2) ^ (((prow >> 1) & 3) << 4);
          *(u16*)((char*)sP[0][wid] + pbyte) = ph;
          *(u16*)((char*)sP[1][wid] + pbyte) = f2bft(p - bf2f(ph));
        }

      // read this half's P fragment BEFORE the other half overwrites sP (same-wave ordering)
      {
        const int prow = lane & 15;
        const int poff = (prow * 64 + ((lane >> 4) << 4)) ^ ((((prow >> 1) & 3)) << 4);
        pa_h[hh] = ldsread((char*)sP[0][wid] + poff);
        pa_l[hh] = ldsread((char*)sP[1][wid] + poff);
      }
    }

    // PV: V fragments shared across halves (4 nf x hi/lo = 8 reads)
    __builtin_amdgcn_s_setprio(1);
#pragma unroll
    for (int nf = 0; nf < 4; nf++) {
      const int vrow = nf * 16 + (lane & 15);
      const int voff = vrow * 64 + ((((lane >> 4) ^ ((lane >> 1) & 3)) & 3) << 4);
      bf16x8 vfh = ldsread((char*)sV[cur][0] + voff);
      bf16x8 vfl = ldsread((char*)sV[cur][1] + voff);
      if (act0) {
        oacc[0][nf] = mm16(pa_h[0], vfh, oacc[0][nf]);
        oacc[0][nf] = mm16(pa_h[0], vfl, oacc[0][nf]);
        oacc[0][nf] = mm16(pa_l[0], vfh, oacc[0][nf]);
      }
      oacc[1][nf] = mm16(pa_h[1], vfh, oacc[1][nf]);
      oacc[1][nf] = mm16(pa_h[1], vfl, oacc[1][nf]);
      oacc[1][nf] = mm16(pa_l[1], vfh, oacc[1][nf]);
    }
    __builtin_amdgcn_s_setprio(0);

    asm volatile("s_waitcnt vmcnt(0)" ::: "memory");
    __builtin_amdgcn_s_barrier();
  }

  // epilogue: unnormalized partial O (f32) + per-row (m, l)
#pragma unroll
  for (int hh = 0; hh < 2; hh++)
#pragma unroll
    for (int r = 0; r < 4; r++) {
      float lt = l_lane[hh][r];
#pragma unroll
      for (int d = 1; d < 16; d <<= 1) lt += __shfl_xor(lt, d, 64);
      const int t = b * TSEQ + qb * 128 + hh * 64 + wid * 16 + ((lane >> 4) * 4) + r;
      const size_t ob = ((size_t)sp * TTOK + t) * TDIM + h * 64 + (lane & 15);
#pragma unroll
      for (int nf = 0; nf < 4; nf++)
        Op[ob + nf * 16] = oacc[hh][nf][r];
      if ((lane & 15) == 0) {
        const size_t mo = (((size_t)sp * TTOK + t) * THEADS + h) * 2;
        ml[mo] = m_run[hh][r];
        ml[mo + 1] = lt;
      }
    }
}

// ---------- flash split combine: O = (w0*O0 + w1*O1) / (w0*l0 + w1*l1), w_i = exp2(m_i - max) ----------
__launch_bounds__(256)
__global__ void flash_comb_k(const float* __restrict__ Op, const float* __restrict__ ml,
                             u16* __restrict__ Oh, u16* __restrict__ Ol) {
  const int t = blockIdx.x, tid = threadIdx.x;
  const int h = tid >> 4;                      // 4 d-elems per thread, all within one head
  const size_t m0o = (((size_t)t) * THEADS + h) * 2;
  const size_t m1o = (((size_t)TTOK + t) * THEADS + h) * 2;
  const float m0 = ml[m0o], l0 = ml[m0o + 1];
  const float m1 = ml[m1o], l1 = ml[m1o + 1];
  const float M = fmaxf(m0, m1);
  float w0 = fexp2(m0 - M), w1 = fexp2(m1 - M);
  const float inv = 1.0f / (w0 * l0 + w1 * l1);
  w0 *= inv; w1 *= inv;
  const float4 o0 = ((const float4*)(Op + (size_t)t * TDIM))[tid];
  const float4 o1 = ((const float4*)(Op + ((size_t)TTOK + t) * TDIM))[tid];
  const float vx = o0.x * w0 + o1.x * w1;
  const float vy = o0.y * w0 + o1.y * w1;
  const float vz = o0.z * w0 + o1.z * w1;
  const float vw = o0.w * w0 + o1.w * w1;
  u16 hx = f2bft(vx), hy = f2bft(vy), hz = f2bft(vz), hw = f2bft(vw);
  uint2 ph; ph.x = (u32)hx | ((u32)hy << 16); ph.y = (u32)hz | ((u32)hw << 16);
  *(uint2*)(Oh + (size_t)t * TDIM + tid * 4) = ph;
  u16 lx = f2bft(vx - bf2f(hx)), ly = f2bft(vy - bf2f(hy));
  u16 lz = f2bft(vz - bf2f(hz)), lw = f2bft(vw - bf2f(hw));
  uint2 pl; pl.x = (u32)lx | ((u32)ly << 16); pl.y = (u32)lz | ((u32)lw << 16);
  *(uint2*)(Ol + (size_t)t * TDIM + tid * 4) = pl;
}

// ---------- router (+ writes ffn-norm bf16): f32 logits from h, top-2, histogram ----------
__launch_bounds__(256)
__global__ void router_k(const float* __restrict__ hres, const float* __restrict__ wn,
                         const float* __restrict__ rw, u16* __restrict__ hn,
                         int* __restrict__ idx01, float* __restrict__ gate01,
                         int* __restrict__ counts) {
  const int t = blockIdx.x, tid = threadIdx.x;
  const float4 xv = ((const float4*)(hres + (size_t)t * TDIM))[tid];
  float ss = xv.x*xv.x + xv.y*xv.y + xv.z*xv.z + xv.w*xv.w;
#pragma unroll
  for (int d = 1; d < 64; d <<= 1) ss += __shfl_xor(ss, d, 64);
  __shared__ float sp[4];
  __shared__ float sacc[4][8];
  if ((tid & 63) == 0) sp[tid >> 6] = ss;
  __syncthreads();
  const float rsc = rsqrtf((sp[0]+sp[1]+sp[2]+sp[3]) * (1.0f / TDIM) + 1e-6f);
  const float4 wv = ((const float4*)wn)[tid];
  const float x0 = xv.x*rsc*wv.x, x1 = xv.y*rsc*wv.y, x2 = xv.z*rsc*wv.z, x3 = xv.w*rsc*wv.w;
  {
    u16 h0 = f2bf(x0), h1 = f2bf(x1), h2 = f2bf(x2), h3 = f2bf(x3);
    uint2 ph; ph.x = (u32)h0 | ((u32)h1 << 16); ph.y = (u32)h2 | ((u32)h3 << 16);
    *(uint2*)(hn + (size_t)t * TDIM + tid * 4) = ph;
  }
  const float* rp = rw + (size_t)(tid * 4) * TEXP;
  float acc[8];
#pragma unroll
  for (int e = 0; e < 8; e++) acc[e] = x0*rp[e] + x1*rp[8+e] + x2*rp[16+e] + x3*rp[24+e];
#pragma unroll
  for (int e = 0; e < 8; e++)
#pragma unroll
    for (int d = 1; d < 64; d <<= 1) acc[e] += __shfl_xor(acc[e], d, 64);
  if ((tid & 63) == 0)
#pragma unroll
    for (int e = 0; e < 8; e++) sacc[tid >> 6][e] = acc[e];
  __syncthreads();
  if (tid == 0) {
    float lg[8];
#pragma unroll
    for (int e = 0; e < 8; e++) lg[e] = sacc[0][e] + sacc[1][e] + sacc[2][e] + sacc[3][e];
    int i1 = 0;
#pragma unroll
    for (int e = 1; e < 8; e++) if (lg[e] > lg[i1]) i1 = e;
    int i2 = (i1 == 0) ? 1 : 0;
#pragma unroll
    for (int e = 0; e < 8; e++) if (e != i1 && lg[e] > lg[i2]) i2 = e;
    const float g1 = 1.0f / (1.0f + __expf(lg[i2] - lg[i1]));
    idx01[t*2] = i1; idx01[t*2+1] = i2;
    gate01[t*2] = g1; gate01[t*2+1] = 1.0f - g1;
    atomicAdd(&counts[i1], 1);
    atomicAdd(&counts[i2], 1);
  }
}

__global__ void zero8_k(int* counts) { if (threadIdx.x < TEXP) counts[threadIdx.x] = 0; }

__global__ void offsets_k(const int* __restrict__ counts, int* __restrict__ cursor,
                          int* __restrict__ bm_e, int* __restrict__ bm_s0,
                          int* __restrict__ bm_end, int* __restrict__ n_active) {
  if (threadIdx.x != 0 || blockIdx.x != 0) return;
  int off = 0, nb = 0;
  for (int e = 0; e < TEXP; e++) {
    const int c = counts[e];
    cursor[e] = off;
    const int end = off + c;
    for (int mb = 0; mb * 128 < c; mb++) { bm_e[nb] = e; bm_s0[nb] = off + mb * 128; bm_end[nb] = end; nb++; }
    off = end;
  }
  *n_active = nb;
}

__global__ void scatter_k(const int* __restrict__ idx01, int* __restrict__ cursor,
                          int* __restrict__ slot_of, int* __restrict__ perm) {
  const int t = blockIdx.x * 256 + threadIdx.x;
  if (t >= TTOK) return;
#pragma unroll
  for (int k = 0; k < 2; k++) {
    const int e = idx01[t*2+k];
    const int slot = atomicAdd(&cursor[e], 1);
    slot_of[t*2+k] = slot;
    perm[slot] = t;
  }
}

// ---------- MoE GEMM1: gathered rows, fused w1/w3, silu(z1)*z3 -> hbuf (dbuf + prefetch) ----------
__launch_bounds__(256)
__global__ void moe_gemm1_k(const u16* __restrict__ hn, const u16* __restrict__ w1t,
                            const u16* __restrict__ w3t, const int* __restrict__ perm,
                            const int* __restrict__ bm_e, const int* __restrict__ bm_s0,
                            const int* __restrict__ bm_end, const int* __restrict__ n_active,
                            u16* __restrict__ hbuf) {
  if ((int)blockIdx.x >= *n_active) return;
  __shared__ u16 sA[2][128 * 32], sB1[2][64 * 32], sB3[2][64 * 32];
  const int tid = threadIdx.x, wid = tid >> 6, lane = tid & 63;
  const int e = bm_e[blockIdx.x], slot0 = bm_s0[blockIdx.x], send = bm_end[blockIdx.x];
  const int n0 = blockIdx.y * 64;
  const int wr = wid >> 1, wc = wid & 1;
  const int srow = tid >> 2;
  const int scol = (((tid & 3) ^ ((tid >> 3) & 3)) * 8);
  const int sa0 = slot0 + srow, sa1 = slot0 + srow + 64;
  const int ta = (sa0 < send) ? perm[sa0] : 0;
  const int tb2 = (sa1 < send) ? perm[sa1] : 0;
  const size_t a0 = (size_t)ta * TDIM + scol;
  const size_t a1 = (size_t)tb2 * TDIM + scol;
  const size_t bb = (size_t)e * TDIM * TFF + (size_t)(n0 + srow) * TDIM + scol;
  const int ldsw = wid * 1024;
  f32x4 ac1[4][2], ac3[4][2];
#pragma unroll
  for (int i = 0; i < 4; i++)
#pragma unroll
    for (int j = 0; j < 2; j++) { ac1[i][j] = fzero(); ac3[i][j] = fzero(); }
  const int g = (lane >> 1) & 3;
  int aoffs[4], boffs[2];
#pragma unroll
  for (int mf = 0; mf < 4; mf++)
    aoffs[mf] = (wr*64 + mf*16 + (lane & 15)) * 64 + ((((lane >> 4)) ^ g) << 4);
#pragma unroll
  for (int nf = 0; nf < 2; nf++)
    boffs[nf] = (wc*32 + nf*16 + (lane & 15)) * 64 + ((((lane >> 4)) ^ g) << 4);

  auto stage = [&](int kk, int bi) {
    const int ke = kk * 32;
    gll16(hn + a0 + ke, (char*)sA[bi] + ldsw);
    gll16(hn + a1 + ke, (char*)sA[bi] + 4096 + ldsw);
    gll16(w1t + bb + ke, (char*)sB1[bi] + ldsw);
    gll16(w3t + bb + ke, (char*)sB3[bi] + ldsw);
  };

  stage(0, 0);
  asm volatile("s_waitcnt vmcnt(0)" ::: "memory");
  __builtin_amdgcn_s_barrier();

  for (int kk = 0; kk < 32; ++kk) {
    const int cur = kk & 1;
    if (kk + 1 < 32) stage(kk + 1, cur ^ 1);
    bf16x8 fa[4], f1[2], f3[2];
#pragma unroll
    for (int mf = 0; mf < 4; mf++) fa[mf] = ldsread((char*)sA[cur] + aoffs[mf]);
#pragma unroll
    for (int nf = 0; nf < 2; nf++) { f1[nf] = ldsread((char*)sB1[cur] + boffs[nf]); f3[nf] = ldsread((char*)sB3[cur] + boffs[nf]); }
#pragma unroll
    for (int mf = 0; mf < 4; mf++)
#pragma unroll
      for (int nf = 0; nf < 2; nf++) {
        ac1[mf][nf] = mm16(fa[mf], f1[nf], ac1[mf][nf]);
        ac3[mf][nf] = mm16(fa[mf], f3[nf], ac3[mf][nf]);
      }
    asm volatile("s_waitcnt vmcnt(0)" ::: "memory");
    __builtin_amdgcn_s_barrier();
  }

#pragma unroll
  for (int mf = 0; mf < 4; mf++)
#pragma unroll
    for (int nf = 0; nf < 2; nf++)
#pragma unroll
      for (int r = 0; r < 4; r++) {
        const int slot = slot0 + wr*64 + mf*16 + ((lane >> 4) * 4) + r;
        if (slot < send) {
          const int col = n0 + wc*32 + nf*16 + (lane & 15);
          const float z1 = ac1[mf][nf][r], z3 = ac3[mf][nf][r];
          const float hv = z1 / (1.0f + __expf(-z1)) * z3;
          hbuf[(size_t)slot * TFF + col] = f2bf(hv);
        }
      }
}

// ---------- MoE GEMM2: hbuf @ w2 -> pair outputs (dbuf + prefetch) ----------
__launch_bounds__(256)
__global__ void moe_gemm2_k(const u16* __restrict__ hbuf, const u16* __restrict__ w2t,
                            const int* __restrict__ bm_e, const int* __restrict__ bm_s0,
                            const int* __restrict__ bm_end, const int* __restrict__ n_active,
                            u16* __restrict__ pout) {
  if ((int)blockIdx.x >= *n_active) return;
  __shared__ u16 sA[2][128 * 32], sB[2][64 * 32];
  const int tid = threadIdx.x, wid = tid >> 6, lane = tid & 63;
  const int e = bm_e[blockIdx.x], slot0 = bm_s0[blockIdx.x], send = bm_end[blockIdx.x];
  const int n0 = blockIdx.y * 64;
  const int wr = wid >> 1, wc = wid & 1;
  const int srow = tid >> 2;
  const int scol = (((tid & 3) ^ ((tid >> 3) & 3)) * 8);
  int sa0 = slot0 + srow; if (sa0 > TPAIRS - 1) sa0 = TPAIRS - 1;
  int sa1 = slot0 + srow + 64; if (sa1 > TPAIRS - 1) sa1 = TPAIRS - 1;
  const size_t a0 = (size_t)sa0 * TFF + scol;
  const size_t a1 = (size_t)sa1 * TFF + scol;
  const size_t bb = (size_t)e * TDIM * TFF + (size_t)(n0 + srow) * TFF + scol;
  const int ldsw = wid * 1024;
  f32x4 acc[4][2];
#pragma unroll
  for (int i = 0; i < 4; i++)
#pragma unroll
    for (int j = 0; j < 2; j++) acc[i][j] = fzero();
  const int g = (lane >> 1) & 3;
  int aoffs[4], boffs[2];
#pragma unroll
  for (int mf = 0; mf < 4; mf++)
    aoffs[mf] = (wr*64 + mf*16 + (lane & 15)) * 64 + ((((lane >> 4)) ^ g) << 4);
#pragma unroll
  for (int nf = 0; nf < 2; nf++)
    boffs[nf] = (wc*32 + nf*16 + (lane & 15)) * 64 + ((((lane >> 4)) ^ g) << 4);

  auto stage = [&](int kk, int bi) {
    const int ke = kk * 32;
    gll16(hbuf + a0 + ke, (char*)sA[bi] + ldsw);
    gll16(hbuf + a1 + ke, (char*)sA[bi] + 4096 + ldsw);
    gll16(w2t + bb + ke, (char*)sB[bi] + ldsw);
  };

  stage(0, 0);
  asm volatile("s_waitcnt vmcnt(0)" ::: "memory");
  __builtin_amdgcn_s_barrier();

  for (int kk = 0; kk < 32; ++kk) {
    const int cur = kk & 1;
    if (kk + 1 < 32) stage(kk + 1, cur ^ 1);
    bf16x8 fa[4], fb[2];
#pragma unroll
    for (int mf = 0; mf < 4; mf++) fa[mf] = ldsread((char*)sA[cur] + aoffs[mf]);
#pragma unroll
    for (int nf = 0; nf < 2; nf++) fb[nf] = ldsread((char*)sB[cur] + boffs[nf]);
#pragma unroll
    for (int mf = 0; mf < 4; mf++)
#pragma unroll
      for (int nf = 0; nf < 2; nf++)
        acc[mf][nf] = mm16(fa[mf], fb[nf], acc[mf][nf]);
    asm volatile("s_waitcnt vmcnt(0)" ::: "memory");
    __builtin_amdgcn_s_barrier();
  }

#pragma unroll
  for (int mf = 0; mf < 4; mf++)
#pragma unroll
    for (int nf = 0; nf < 2; nf++)
#pragma unroll
      for (int r = 0; r < 4; r++) {
        const int slot = slot0 + wr*64 + mf*16 + ((lane >> 4) * 4) + r;
        if (slot < send) {
          const int col = n0 + wc*32 + nf*16 + (lane & 15);
          pout[(size_t)slot * TDIM + col] = f2bf(acc[mf][nf][r]);
        }
      }
}

// ---------- final combine: out = h + g0*pout[s0] + g1*pout[s1] ----------
__launch_bounds__(256)
__global__ void combine_k(const float* __restrict__ hres, const u16* __restrict__ pout,
                          const int* __restrict__ slot_of, const float* __restrict__ gate01,
                          float* __restrict__ out) {
  const int t = blockIdx.x, tid = threadIdx.x;
  const int s0 = slot_of[t*2], s1 = slot_of[t*2+1];
  const float g0 = gate01[t*2], g1 = gate01[t*2+1];
  const float4 hv = ((const float4*)(hres + (size_t)t * TDIM))[tid];
  const uint2 u0 = *(const uint2*)(pout + (size_t)s0 * TDIM + tid * 4);
  const uint2 u1 = *(const uint2*)(pout + (size_t)s1 * TDIM + tid * 4);
  float4 o;
  o.x = hv.x + g0 * bf2f((u16)(u0.x & 0xffff)) + g1 * bf2f((u16)(u1.x & 0xffff));
  o.y = hv.y + g0 * bf2f((u16)(u0.x >> 16))    + g1 * bf2f((u16)(u1.x >> 16));
  o.z = hv.z + g0 * bf2f((u16)(u0.y & 0xffff)) + g1 * bf2f((u16)(u1.y & 0xffff));
  o.w = hv.w + g0 * bf2f((u16)(u0.y >> 16))    + g1 * bf2f((u16)(u1.y >> 16));
  ((float4*)(out + (size_t)t * TDIM))[tid] = o;
}

extern "C" void kernel_launch(void* const* d_in, const int* in_sizes, int n_in,
                              void* d_out, int out_size, void* d_ws, size_t ws_size,
                              hipStream_t stream) {
  (void)in_sizes; (void)n_in; (void)out_size; (void)ws_size;
  const float* x   = (const float*)d_in[0];
  const float* anw = (const float*)d_in[1];
  const float* wq  = (const float*)d_in[2];
  const float* wk  = (const float*)d_in[3];
  const float* wv  = (const float*)d_in[4];
  const float* wo  = (const float*)d_in[5];
  const float* fnw = (const float*)d_in[6];
  const float* rw  = (const float*)d_in[7];
  const float* w1  = (const float*)d_in[8];
  const float* w3  = (const float*)d_in[9];
  const float* w2  = (const float*)d_in[10];
  float* out = (float*)d_out;

  char* ws = (char*)d_ws;
  size_t off = 0;
  auto take = [&](size_t bytes) -> char* {
    char* p = ws + off;
    off += (bytes + 255) & ~(size_t)255;
    return p;
  };
  const size_t SZ_W = (size_t)TDIM * TDIM * sizeof(u16);
  const size_t SZ_T = (size_t)TTOK * TDIM * sizeof(u16);
  u16* wqt_h = (u16*)take(SZ_W); u16* wqt_l = (u16*)take(SZ_W);
  u16* wkt_h = (u16*)take(SZ_W); u16* wkt_l = (u16*)take(SZ_W);
  u16* wvt_h = (u16*)take(SZ_W); u16* wvt_l = (u16*)take(SZ_W);
  u16* wot_h = (u16*)take(SZ_W); u16* wot_l = (u16*)take(SZ_W);
  u16* w1t = (u16*)take((size_t)TEXP * TDIM * TFF * sizeof(u16));
  u16* w3t = (u16*)take((size_t)TEXP * TDIM * TFF * sizeof(u16));
  u16* w2t = (u16*)take((size_t)TEXP * TDIM * TFF * sizeof(u16));
  u16* xnh = (u16*)take(SZ_T); u16* xnl = (u16*)take(SZ_T);
  u16* qh  = (u16*)take(SZ_T); u16* ql  = (u16*)take(SZ_T);
  u16* kh  = (u16*)take(SZ_T); u16* kl  = (u16*)take(SZ_T);
  u16* vth = (u16*)take(SZ_T); u16* vtl = (u16*)take(SZ_T);
  float* hres = (float*)take((size_t)TTOK * TDIM * sizeof(float));
  float* opart = (float*)take((size_t)2 * TTOK * TDIM * sizeof(float));   // split-KV partial O
  float* mlbuf = (float*)take((size_t)2 * TTOK * THEADS * 2 * sizeof(float));
  int*   idx01  = (int*)take(TTOK * 2 * 4);
  float* gate01 = (float*)take(TTOK * 2 * 4);
  int*   slot_of = (int*)take(TTOK * 2 * 4);
  int*   perm    = (int*)take(TPAIRS * 4);
  int*   counts  = (int*)take(256);
  int*   cursor  = (int*)take(256);
  int*   bm_e    = (int*)take(96 * 4);
  int*   bm_s0   = (int*)take(96 * 4);
  int*   bm_end  = (int*)take(96 * 4);
  int*   n_act   = (int*)take(256);
  u16* oh = xnh; u16* ol = xnl;
  u16* hn = qh;
  u16* hbuf = kh;
  u16* pout = vth;

  transpose_all_k<<<28672, dim3(32, 8), 0, stream>>>(wq, wk, wv, wo, w1, w3, w2,
                                                     wqt_h, wqt_l, wkt_h, wkt_l, wvt_h, wvt_l,
                                                     wot_h, wot_l, w1t, w3t, w2t);
  zero8_k<<<1, 64, 0, stream>>>(counts);
  rmsnorm_k<<<TTOK, 256, 0, stream>>>(x, anw, xnh, xnl);
  gemm_qkv_k<<<dim3(TTOK/128, 48), 256, 0, stream>>>(xnh, xnl, wqt_h, wqt_l, wkt_h, wkt_l,
                                                     wvt_h, wvt_l, qh, ql, kh, kl, vth, vtl);
  flash_k<<<dim3(TSEQ/128, TBATCH*THEADS, 2), 256, 0, stream>>>(qh, ql, kh, kl, vth, vtl, opart, mlbuf);
  flash_comb_k<<<TTOK, 256, 0, stream>>>(opart, mlbuf, oh, ol);
  gemm_x3_k<2><<<dim3(TTOK/128, TDIM/64), 256, 0, stream>>>(oh, ol, wot_h, wot_l, nullptr, nullptr, hres, x, TTOK, TDIM, TDIM);
  router_k<<<TTOK, 256, 0, stream>>>(hres, fnw, rw, hn, idx01, gate01, counts);
  offsets_k<<<1, 1, 0, stream>>>(counts, cursor, bm_e, bm_s0, bm_end, n_act);
  scatter_k<<<TTOK/256, 256, 0, stream>>>(idx01, cursor, slot_of, perm);
  moe_gemm1_k<<<dim3(72, TFF/64), 256, 0, stream>>>(hn, w1t, w3t, perm, bm_e, bm_s0, bm_end, n_act, hbuf);
  moe_gemm2_k<<<dim3(72, TDIM/64), 256, 0, stream>>>(hbuf, w2t, bm_e, bm_s0, bm_end, n_act, pout);
  combine_k<<<TTOK, 256, 0, stream>>>(hres, pout, slot_of, gate01, out);
}

// Round 27
// 575.896 us; speedup vs baseline: 1.3794x; 1.0792x over previous
//
#include <hip/hip_runtime.h>
#include <cstdint>
#include <math.h>

typedef unsigned short u16;
typedef unsigned int u32;
typedef __bf16 bf16x8 __attribute__((ext_vector_type(8)));
typedef float f32x4 __attribute__((ext_vector_type(4)));

#define TBATCH 2
#define TSEQ   2048
#define TDIM   1024
#define THEADS 16
#define THDIM  64
#define TEXP   8
#define TFF    1024
#define TTOK   (TBATCH*TSEQ)
#define TPAIRS (TTOK*2)

__device__ __forceinline__ u16 f2bf(float f) {
  u32 u = __float_as_uint(f);
  u += 0x7FFFu + ((u >> 16) & 1u);
  return (u16)(u >> 16);
}
__device__ __forceinline__ u16 f2bft(float f) {        // truncating split (1 op)
  return (u16)(__float_as_uint(f) >> 16);
}
__device__ __forceinline__ float bf2f(u16 h) { return __uint_as_float(((u32)h) << 16); }
__device__ __forceinline__ float fexp2(float x) {      // raw v_exp_f32 (exp2)
  float r;
  asm("v_exp_f32 %0, %1" : "=v"(r) : "v"(x));
  return r;
}

__device__ __forceinline__ void gll16(const void* g, void* l) {
  __builtin_amdgcn_global_load_lds((const __attribute__((address_space(1))) void*)g,
                                   (__attribute__((address_space(3))) void*)l, 16, 0, 0);
}
__device__ __forceinline__ bf16x8 ldsread(const void* p) { return *(const bf16x8*)p; }
__device__ __forceinline__ f32x4 mm16(bf16x8 a, bf16x8 b, f32x4 c) {
  return __builtin_amdgcn_mfma_f32_16x16x32_bf16(a, b, c, 0, 0, 0);
}
__device__ __forceinline__ f32x4 fzero() { f32x4 z = {0.f, 0.f, 0.f, 0.f}; return z; }

// ---------- ALL weight transposes in ONE launch: f32 [z][1024][1024] -> bf16 [z][1024][1024]^T ----------
__global__ void transpose_all_k(const float* __restrict__ wq, const float* __restrict__ wk,
                                const float* __restrict__ wv, const float* __restrict__ wo,
                                const float* __restrict__ w1, const float* __restrict__ w3,
                                const float* __restrict__ w2,
                                u16* __restrict__ qth, u16* __restrict__ qtl,
                                u16* __restrict__ kth, u16* __restrict__ ktl,
                                u16* __restrict__ vth_, u16* __restrict__ vtl_,
                                u16* __restrict__ oth, u16* __restrict__ otl,
                                u16* __restrict__ w1t, u16* __restrict__ w3t, u16* __restrict__ w2t) {
  __shared__ float t[32][33];
  int id = (int)blockIdx.x;
  const float* in; u16* outh; u16* outl = nullptr;
  size_t bo = 0;
  int tile;
  if (id < 4096) {
    const int wi = id >> 10;
    in   = (wi == 0) ? wq  : (wi == 1) ? wk  : (wi == 2) ? wv   : wo;
    outh = (wi == 0) ? qth : (wi == 1) ? kth : (wi == 2) ? vth_ : oth;
    outl = (wi == 0) ? qtl : (wi == 1) ? ktl : (wi == 2) ? vtl_ : otl;
    tile = id & 1023;
  } else {
    const int id2 = id - 4096;
    const int wi = id2 >> 13;                 // 0=w1 1=w3 2=w2
    const int rem = id2 & 8191;
    bo = (size_t)(rem >> 10) << 20;           // z * 1024*1024
    in   = (wi == 0) ? w1  : (wi == 1) ? w3  : w2;
    outh = (wi == 0) ? w1t : (wi == 1) ? w3t : w2t;
    tile = rem & 1023;
  }
  const int c0 = (tile & 31) * 32, r0 = (tile >> 5) * 32;
  const int tx = threadIdx.x, ty = threadIdx.y;
#pragma unroll
  for (int j = 0; j < 32; j += 8)
    t[ty + j][tx] = in[bo + (size_t)(r0 + ty + j) * 1024 + (c0 + tx)];
  __syncthreads();
#pragma unroll
  for (int j = 0; j < 32; j += 8) {
    float v = t[tx][ty + j];
    u16 hv = f2bf(v);
    size_t o = bo + (size_t)(c0 + ty + j) * 1024 + (r0 + tx);
    outh[o] = hv;
    if (outl != nullptr) outl[o] = f2bf(v - bf2f(hv));
  }
}

// ---------- RMSNorm: f32 [T][D] -> bf16 split (attn input) ----------
__launch_bounds__(256)
__global__ void rmsnorm_k(const float* __restrict__ x, const float* __restrict__ w,
                          u16* __restrict__ oh, u16* __restrict__ ol) {
  const int t = blockIdx.x, tid = threadIdx.x;
  const float4 xv = ((const float4*)(x + (size_t)t * TDIM))[tid];
  float ss = xv.x*xv.x + xv.y*xv.y + xv.z*xv.z + xv.w*xv.w;
#pragma unroll
  for (int d = 1; d < 64; d <<= 1) ss += __shfl_xor(ss, d, 64);
  __shared__ float sp[4];
  if ((tid & 63) == 0) sp[tid >> 6] = ss;
  __syncthreads();
  const float rsc = rsqrtf((sp[0] + sp[1] + sp[2] + sp[3]) * (1.0f / TDIM) + 1e-6f);
  const float4 wv = ((const float4*)w)[tid];
  float v0 = xv.x*rsc*wv.x, v1 = xv.y*rsc*wv.y, v2 = xv.z*rsc*wv.z, v3 = xv.w*rsc*wv.w;
  u16 h0 = f2bf(v0), h1 = f2bf(v1), h2 = f2bf(v2), h3 = f2bf(v3);
  uint2 ph; ph.x = (u32)h0 | ((u32)h1 << 16); ph.y = (u32)h2 | ((u32)h3 << 16);
  *(uint2*)(oh + (size_t)t * TDIM + tid * 4) = ph;
  u16 l0 = f2bf(v0 - bf2f(h0)), l1 = f2bf(v1 - bf2f(h1));
  u16 l2 = f2bf(v2 - bf2f(h2)), l3 = f2bf(v3 - bf2f(h3));
  uint2 pl; pl.x = (u32)l0 | ((u32)l1 << 16); pl.y = (u32)l2 | ((u32)l3 << 16);
  *(uint2*)(ol + (size_t)t * TDIM + tid * 4) = pl;
}

// ---------- fused QKV bf16x3 GEMM: one launch, blockIdx.y selects Q/K/V (grid 32 x 48) ----------
// Q output is pre-scaled by 1/sqrt(HD)*log2(e) so flash_k's softmax works directly in exp2 domain.
__launch_bounds__(256)
__global__ void gemm_qkv_k(const u16* __restrict__ Ah, const u16* __restrict__ Al,
                           const u16* __restrict__ Bqh, const u16* __restrict__ Bql,
                           const u16* __restrict__ Bkh, const u16* __restrict__ Bkl,
                           const u16* __restrict__ Bvh, const u16* __restrict__ Bvl,
                           u16* __restrict__ qh, u16* __restrict__ ql,
                           u16* __restrict__ kh, u16* __restrict__ kl,
                           u16* __restrict__ vth, u16* __restrict__ vtl) {
  __shared__ u16 sAh[2][128 * 32], sAl[2][128 * 32], sBh[2][64 * 32], sBl[2][64 * 32];
  const int tid = threadIdx.x, wid = tid >> 6, lane = tid & 63;
  const int which = blockIdx.y >> 4;                 // 0=Q 1=K 2=V (block-uniform)
  const int m0 = blockIdx.x * 128, n0 = (blockIdx.y & 15) * 64;
  const int wr = wid >> 1, wc = wid & 1;
  const u16* Bth = (which == 0) ? Bqh : (which == 1) ? Bkh : Bvh;
  const u16* Btl = (which == 0) ? Bql : (which == 1) ? Bkl : Bvl;
  u16* outh = (which == 0) ? qh : kh;
  u16* outl = (which == 0) ? ql : kl;

  f32x4 acc[4][2];
#pragma unroll
  for (int i = 0; i < 4; i++)
#pragma unroll
    for (int j = 0; j < 2; j++) acc[i][j] = fzero();

  const int srow = tid >> 2;
  const int scol = (((tid & 3) ^ ((tid >> 3) & 3)) * 8);
  const size_t a0 = (size_t)(m0 + srow) * TDIM + scol;
  const size_t a1 = (size_t)(m0 + srow + 64) * TDIM + scol;
  const size_t b0 = (size_t)(n0 + srow) * TDIM + scol;
  const int ldsw = wid * 1024;

  const int g = (lane >> 1) & 3;
  int aoffs[4], boffs[2];
#pragma unroll
  for (int mf = 0; mf < 4; mf++)
    aoffs[mf] = (wr*64 + mf*16 + (lane & 15)) * 64 + ((((lane >> 4)) ^ g) << 4);
#pragma unroll
  for (int nf = 0; nf < 2; nf++)
    boffs[nf] = (wc*32 + nf*16 + (lane & 15)) * 64 + ((((lane >> 4)) ^ g) << 4);

  auto stage = [&](int kk, int bi) {
    const int ke = kk * 32;
    gll16(Ah + a0 + ke, (char*)sAh[bi] + ldsw);
    gll16(Ah + a1 + ke, (char*)sAh[bi] + 4096 + ldsw);
    gll16(Al + a0 + ke, (char*)sAl[bi] + ldsw);
    gll16(Al + a1 + ke, (char*)sAl[bi] + 4096 + ldsw);
    gll16(Bth + b0 + ke, (char*)sBh[bi] + ldsw);
    gll16(Btl + b0 + ke, (char*)sBl[bi] + ldsw);
  };

  stage(0, 0);
  asm volatile("s_waitcnt vmcnt(0)" ::: "memory");
  __builtin_amdgcn_s_barrier();

  for (int kk = 0; kk < 32; ++kk) {
    const int cur = kk & 1;
    if (kk + 1 < 32) stage(kk + 1, cur ^ 1);
    bf16x8 fah[4], fal[4], fbh[2], fbl[2];
#pragma unroll
    for (int mf = 0; mf < 4; mf++) { fah[mf] = ldsread((char*)sAh[cur] + aoffs[mf]); fal[mf] = ldsread((char*)sAl[cur] + aoffs[mf]); }
#pragma unroll
    for (int nf = 0; nf < 2; nf++) { fbh[nf] = ldsread((char*)sBh[cur] + boffs[nf]); fbl[nf] = ldsread((char*)sBl[cur] + boffs[nf]); }
#pragma unroll
    for (int mf = 0; mf < 4; mf++)
#pragma unroll
      for (int nf = 0; nf < 2; nf++) {
        acc[mf][nf] = mm16(fah[mf], fbh[nf], acc[mf][nf]);
        acc[mf][nf] = mm16(fah[mf], fbl[nf], acc[mf][nf]);
        acc[mf][nf] = mm16(fal[mf], fbh[nf], acc[mf][nf]);
      }
    asm volatile("s_waitcnt vmcnt(0)" ::: "memory");
    __builtin_amdgcn_s_barrier();
  }

  const float qscale = (which == 0) ? 0.18033688011112042f : 1.0f;  // 0.125 * log2(e)
#pragma unroll
  for (int mf = 0; mf < 4; mf++)
#pragma unroll
    for (int nf = 0; nf < 2; nf++)
#pragma unroll
      for (int r = 0; r < 4; r++) {
        const int grow = m0 + wr*64 + mf*16 + ((lane >> 4) * 4) + r;
        const int gcol = n0 + wc*32 + nf*16 + (lane & 15);
        const float v = acc[mf][nf][r] * qscale;
        u16 hv = f2bf(v);
        u16 lv = f2bf(v - bf2f(hv));
        if (which < 2) {
          const size_t o = (size_t)grow * TDIM + gcol;
          outh[o] = hv; outl[o] = lv;
        } else {
          const int b = grow >> 11, s = grow & (TSEQ - 1);
          const int hh = gcol >> 6, hd = gcol & 63;
          const size_t o = ((size_t)((b * THEADS + hh) * THDIM + hd)) * TSEQ + s;
          vth[o] = hv; vtl[o] = lv;
        }
      }
}

// ---------- bf16x3 GEMM (WO): 2-buffer + prefetch; EPI2 = f32 out + resid ----------
template<int EPI>
__launch_bounds__(256)
__global__ void gemm_x3_k(const u16* __restrict__ Ah, const u16* __restrict__ Al,
                          const u16* __restrict__ Bth, const u16* __restrict__ Btl,
                          u16* __restrict__ outh, u16* __restrict__ outl,
                          float* __restrict__ outf, const float* __restrict__ resid,
                          int M, int N, int K) {
  __shared__ u16 sAh[2][128 * 32], sAl[2][128 * 32], sBh[2][64 * 32], sBl[2][64 * 32];
  const int tid = threadIdx.x, wid = tid >> 6, lane = tid & 63;
  const int m0 = blockIdx.x * 128, n0 = blockIdx.y * 64;
  const int wr = wid >> 1, wc = wid & 1;

  f32x4 acc[4][2];
#pragma unroll
  for (int i = 0; i < 4; i++)
#pragma unroll
    for (int j = 0; j < 2; j++) acc[i][j] = fzero();

  const int srow = tid >> 2;
  const int scol = (((tid & 3) ^ ((tid >> 3) & 3)) * 8);
  const size_t a0 = (size_t)(m0 + srow) * K + scol;
  const size_t a1 = (size_t)(m0 + srow + 64) * K + scol;
  const size_t b0 = (size_t)(n0 + srow) * K + scol;
  const int ldsw = wid * 1024;

  const int g = (lane >> 1) & 3;
  int aoffs[4], boffs[2];
#pragma unroll
  for (int mf = 0; mf < 4; mf++)
    aoffs[mf] = (wr*64 + mf*16 + (lane & 15)) * 64 + ((((lane >> 4)) ^ g) << 4);
#pragma unroll
  for (int nf = 0; nf < 2; nf++)
    boffs[nf] = (wc*32 + nf*16 + (lane & 15)) * 64 + ((((lane >> 4)) ^ g) << 4);

  auto stage = [&](int kk, int bi) {
    const int ke = kk * 32;
    gll16(Ah + a0 + ke, (char*)sAh[bi] + ldsw);
    gll16(Ah + a1 + ke, (char*)sAh[bi] + 4096 + ldsw);
    gll16(Al + a0 + ke, (char*)sAl[bi] + ldsw);
    gll16(Al + a1 + ke, (char*)sAl[bi] + 4096 + ldsw);
    gll16(Bth + b0 + ke, (char*)sBh[bi] + ldsw);
    gll16(Btl + b0 + ke, (char*)sBl[bi] + ldsw);
  };

  const int nk = K >> 5;
  stage(0, 0);
  asm volatile("s_waitcnt vmcnt(0)" ::: "memory");
  __builtin_amdgcn_s_barrier();

  for (int kk = 0; kk < nk; ++kk) {
    const int cur = kk & 1;
    if (kk + 1 < nk) stage(kk + 1, cur ^ 1);
    bf16x8 fah[4], fal[4], fbh[2], fbl[2];
#pragma unroll
    for (int mf = 0; mf < 4; mf++) { fah[mf] = ldsread((char*)sAh[cur] + aoffs[mf]); fal[mf] = ldsread((char*)sAl[cur] + aoffs[mf]); }
#pragma unroll
    for (int nf = 0; nf < 2; nf++) { fbh[nf] = ldsread((char*)sBh[cur] + boffs[nf]); fbl[nf] = ldsread((char*)sBl[cur] + boffs[nf]); }
#pragma unroll
    for (int mf = 0; mf < 4; mf++)
#pragma unroll
      for (int nf = 0; nf < 2; nf++) {
        acc[mf][nf] = mm16(fah[mf], fbh[nf], acc[mf][nf]);
        acc[mf][nf] = mm16(fah[mf], fbl[nf], acc[mf][nf]);
        acc[mf][nf] = mm16(fal[mf], fbh[nf], acc[mf][nf]);
      }
    asm volatile("s_waitcnt vmcnt(0)" ::: "memory");
    __builtin_amdgcn_s_barrier();
  }

#pragma unroll
  for (int mf = 0; mf < 4; mf++)
#pragma unroll
    for (int nf = 0; nf < 2; nf++)
#pragma unroll
      for (int r = 0; r < 4; r++) {
        const int grow = m0 + wr*64 + mf*16 + ((lane >> 4) * 4) + r;
        const int gcol = n0 + wc*32 + nf*16 + (lane & 15);
        const float v = acc[mf][nf][r];
        if (EPI == 0) {
          const size_t o = (size_t)grow * N + gcol;
          u16 hv = f2bf(v);
          outh[o] = hv; outl[o] = f2bf(v - bf2f(hv));
        } else if (EPI == 1) {
          const int b = grow >> 11, s = grow & (TSEQ - 1);
          const int hh = gcol >> 6, hd = gcol & 63;
          const size_t o = ((size_t)((b * THEADS + hh) * THDIM + hd)) * TSEQ + s;
          u16 hv = f2bf(v);
          outh[o] = hv; outl[o] = f2bf(v - bf2f(hv));
        } else {
          const size_t o = (size_t)grow * N + gcol;
          outf[o] = v + resid[o];
        }
      }
}

// ---------- causal flash attention, bf16x3, QBLK=128: shared K reads, hoisted P reads, defer-max, setprio ----------
__launch_bounds__(256)
__global__ void flash_k(const u16* __restrict__ Qh, const u16* __restrict__ Ql,
                        const u16* __restrict__ Kh, const u16* __restrict__ Kl,
                        const u16* __restrict__ Vth, const u16* __restrict__ Vtl,
                        u16* __restrict__ Oh, u16* __restrict__ Ol) {
  __shared__ u16 sK[2][2][4096];   // [buf][hi/lo][64x64] rows 128B
  __shared__ u16 sV[2][2][4096];
  __shared__ u16 sP[2][4][1024];   // [hi/lo][warp][16x64], reused by both halves
  const int tid = threadIdx.x, wid = tid >> 6, lane = tid & 63;
  const int qb = (int)(gridDim.x - 1 - blockIdx.x);   // longest-first
  const int bh = blockIdx.y;
  const int b = bh >> 4, h = bh & 15;
  const int srow = tid >> 3;
  const int sxcol = (((lane & 7) ^ ((lane >> 3) & 7)) << 3);
  const int ldsw = wid * 1024;

  // Q fragments for both 64-row halves, straight from global (16B/lane contiguous).
  // Q is pre-scaled by 0.125*log2(e) in gemm_qkv_k -> scores arrive in exp2 domain.
  bf16x8 fqh[2][2], fql[2][2];
#pragma unroll
  for (int hh = 0; hh < 2; hh++) {
    const size_t qbase = ((size_t)(b * TSEQ + qb * 128 + hh * 64 + wid * 16 + (lane & 15))) * TDIM + h * 64;
#pragma unroll
    for (int kq = 0; kq < 2; kq++) {
      fqh[hh][kq] = *(const bf16x8*)(Qh + qbase + (kq * 4 + (lane >> 4)) * 8);
      fql[hh][kq] = *(const bf16x8*)(Ql + qbase + (kq * 4 + (lane >> 4)) * 8);
    }
  }

  f32x4 oacc[2][4];
  float m_run[2][4], l_lane[2][4];
#pragma unroll
  for (int hh = 0; hh < 2; hh++)
#pragma unroll
    for (int i = 0; i < 4; i++) { oacc[hh][i] = fzero(); m_run[hh][i] = -INFINITY; l_lane[hh][i] = 0.f; }

  const size_t kg0 = ((size_t)(b * TSEQ + srow)) * TDIM + h * 64 + sxcol;
  const size_t kg1 = kg0 + (size_t)32 * TDIM;
  const size_t vg0 = ((size_t)((b * THEADS + h) * THDIM + srow)) * TSEQ + sxcol;
  const size_t vg1 = vg0 + (size_t)32 * TSEQ;

  auto stage = [&](int kb, int bi) {
    const size_t ko = (size_t)kb * 64 * TDIM;
    const size_t vo = (size_t)kb * 64;
    gll16(Kh + kg0 + ko, (char*)sK[bi][0] + ldsw);
    gll16(Kh + kg1 + ko, (char*)sK[bi][0] + 4096 + ldsw);
    gll16(Kl + kg0 + ko, (char*)sK[bi][1] + ldsw);
    gll16(Kl + kg1 + ko, (char*)sK[bi][1] + 4096 + ldsw);
    gll16(Vth + vg0 + vo, (char*)sV[bi][0] + ldsw);
    gll16(Vth + vg1 + vo, (char*)sV[bi][0] + 4096 + ldsw);
    gll16(Vtl + vg0 + vo, (char*)sV[bi][1] + ldsw);
    gll16(Vtl + vg1 + vo, (char*)sV[bi][1] + 4096 + ldsw);
  };

  const int nkb = 2 * qb + 2;
  stage(0, 0);
  asm volatile("s_waitcnt vmcnt(0)" ::: "memory");
  __builtin_amdgcn_s_barrier();

  for (int kb = 0; kb < nkb; ++kb) {
    const int cur = kb & 1;
    if (kb + 1 < nkb) stage(kb + 1, cur ^ 1);

    // QK^T for BOTH halves, sharing each K-fragment read (16 -> 8 reads/iter)
    f32x4 sc[2][4];
    __builtin_amdgcn_s_setprio(1);
#pragma unroll
    for (int nf = 0; nf < 4; nf++) {
      f32x4 s0 = fzero(), s1 = fzero();
      const int krow = nf * 16 + (lane & 15);
#pragma unroll
      for (int kq = 0; kq < 2; kq++) {
        const int off = krow * 128 + (((kq * 4 + (lane >> 4)) ^ (lane & 7)) << 4);
        bf16x8 kfh = ldsread((char*)sK[cur][0] + off);
        bf16x8 kfl = ldsread((char*)sK[cur][1] + off);
        s0 = mm16(fqh[0][kq], kfh, s0);
        s0 = mm16(fqh[0][kq], kfl, s0);
        s0 = mm16(fql[0][kq], kfh, s0);
        s1 = mm16(fqh[1][kq], kfh, s1);
        s1 = mm16(fqh[1][kq], kfl, s1);
        s1 = mm16(fql[1][kq], kfh, s1);
      }
      sc[0][nf] = s0; sc[1][nf] = s1;
    }
    __builtin_amdgcn_s_setprio(0);

#pragma unroll
    for (int hh = 0; hh < 2; hh++) {
      // half hh covers q rows [qb*128+hh*64, +64); skip softmax/PV if fully masked
      if (kb * 64 > qb * 128 + hh * 64 + 63) continue;

      const int qg = qb * 128 + hh * 64 + wid * 16 + ((lane >> 4) * 4);
      float pm[4] = {-INFINITY, -INFINITY, -INFINITY, -INFINITY};
#pragma unroll
      for (int nf = 0; nf < 4; nf++) {
        const int kg = kb * 64 + nf * 16 + (lane & 15);
#pragma unroll
        for (int r = 0; r < 4; r++) {
          float v = sc[hh][nf][r];               // already exp2-domain (Q pre-scaled)
          if (kg > qg + r) v = -INFINITY;
          sc[hh][nf][r] = v;
          pm[r] = fmaxf(pm[r], v);
        }
      }
#pragma unroll
      for (int r = 0; r < 4; r++)
#pragma unroll
        for (int d = 1; d < 16; d <<= 1) pm[r] = fmaxf(pm[r], __shfl_xor(pm[r], d, 64));

      // defer-max (T13): skip O/l rescale when tile max within 8 (exp2-domain) of running max.
      // P then bounded by 2^8; f32 accumulators have ample headroom. First tile: m_run=-inf -> taken.
      const float dm = fmaxf(fmaxf(pm[0] - m_run[hh][0], pm[1] - m_run[hh][1]),
                             fmaxf(pm[2] - m_run[hh][2], pm[3] - m_run[hh][3]));
      if (!__all(dm <= 8.0f)) {
#pragma unroll
        for (int r = 0; r < 4; r++) {
          const float mn = fmaxf(m_run[hh][r], pm[r]);
          const float esc = fexp2(m_run[hh][r] - mn);
          m_run[hh][r] = mn;
          l_lane[hh][r] *= esc;
#pragma unroll
          for (int nf = 0; nf < 4; nf++) oacc[hh][nf][r] *= esc;
        }
      }
      float ls[4] = {0.f, 0.f, 0.f, 0.f};
#pragma unroll
      for (int nf = 0; nf < 4; nf++)
#pragma unroll
        for (int r = 0; r < 4; r++) {
          float p = fexp2(sc[hh][nf][r] - m_run[hh][r]);
          sc[hh][nf][r] = p;
          ls[r] += p;
        }
#pragma unroll
      for (int r = 0; r < 4; r++) l_lane[hh][r] += ls[r];

      // P store (truncating hi/lo split; per-warp private, swizzled, no barrier)
#pragma unroll
      for (int nf = 0; nf < 4; nf++)
#pragma unroll
        for (int r = 0; r < 4; r++) {
          float p = sc[hh][nf][r];
          u16 ph = f2bft(p);
          const int prow = (lane >> 4) * 4 + r;
          const int pbyte = (prow * 128 + (nf * 16 + (lane & 15)) * 2) ^ ((prow & 7) << 4);
          *(u16*)((char*)sP[0][wid] + pbyte) = ph;
          *(u16*)((char*)sP[1][wid] + pbyte) = f2bft(p - bf2f(ph));
        }

      // PV: kq-outer so P fragments are read ONCE per kq (16 -> 4 reads/iter total)
      __builtin_amdgcn_s_setprio(1);
#pragma unroll
      for (int kq = 0; kq < 2; kq++) {
        const int prow = lane & 15;
        const int poff = prow * 128 + (((kq * 4 + (lane >> 4)) ^ (prow & 7)) << 4);
        bf16x8 pah = ldsread((char*)sP[0][wid] + poff);
        bf16x8 pal = ldsread((char*)sP[1][wid] + poff);
#pragma unroll
        for (int nf = 0; nf < 4; nf++) {
          const int vrow = nf * 16 + (lane & 15);
          const int voff = vrow * 128 + (((kq * 4 + (lane >> 4)) ^ (lane & 7)) << 4);
          bf16x8 vfh = ldsread((char*)sV[cur][0] + voff);
          bf16x8 vfl = ldsread((char*)sV[cur][1] + voff);
          oacc[hh][nf] = mm16(pah, vfh, oacc[hh][nf]);
          oacc[hh][nf] = mm16(pah, vfl, oacc[hh][nf]);
          oacc[hh][nf] = mm16(pal, vfh, oacc[hh][nf]);
        }
      }
      __builtin_amdgcn_s_setprio(0);
    }
    asm volatile("s_waitcnt vmcnt(0)" ::: "memory");
    __builtin_amdgcn_s_barrier();
  }

#pragma unroll
  for (int hh = 0; hh < 2; hh++)
#pragma unroll
    for (int r = 0; r < 4; r++) {
      float lt = l_lane[hh][r];
#pragma unroll
      for (int d = 1; d < 16; d <<= 1) lt += __shfl_xor(lt, d, 64);
      const float inv = 1.0f / lt;
      const int t = b * TSEQ + qb * 128 + hh * 64 + wid * 16 + ((lane >> 4) * 4) + r;
#pragma unroll
      for (int nf = 0; nf < 4; nf++) {
        const float v = oacc[hh][nf][r] * inv;
        const size_t o = (size_t)t * TDIM + h * 64 + nf * 16 + (lane & 15);
        u16 hv = f2bft(v);
        Oh[o] = hv; Ol[o] = f2bft(v - bf2f(hv));
      }
    }
}

// ---------- router (+ writes ffn-norm bf16): f32 logits from h, top-2, histogram ----------
__launch_bounds__(256)
__global__ void router_k(const float* __restrict__ hres, const float* __restrict__ wn,
                         const float* __restrict__ rw, u16* __restrict__ hn,
                         int* __restrict__ idx01, float* __restrict__ gate01,
                         int* __restrict__ counts) {
  const int t = blockIdx.x, tid = threadIdx.x;
  const float4 xv = ((const float4*)(hres + (size_t)t * TDIM))[tid];
  float ss = xv.x*xv.x + xv.y*xv.y + xv.z*xv.z + xv.w*xv.w;
#pragma unroll
  for (int d = 1; d < 64; d <<= 1) ss += __shfl_xor(ss, d, 64);
  __shared__ float sp[4];
  __shared__ float sacc[4][8];
  if ((tid & 63) == 0) sp[tid >> 6] = ss;
  __syncthreads();
  const float rsc = rsqrtf((sp[0]+sp[1]+sp[2]+sp[3]) * (1.0f / TDIM) + 1e-6f);
  const float4 wv = ((const float4*)wn)[tid];
  const float x0 = xv.x*rsc*wv.x, x1 = xv.y*rsc*wv.y, x2 = xv.z*rsc*wv.z, x3 = xv.w*rsc*wv.w;
  {
    u16 h0 = f2bf(x0), h1 = f2bf(x1), h2 = f2bf(x2), h3 = f2bf(x3);
    uint2 ph; ph.x = (u32)h0 | ((u32)h1 << 16); ph.y = (u32)h2 | ((u32)h3 << 16);
    *(uint2*)(hn + (size_t)t * TDIM + tid * 4) = ph;
  }
  const float* rp = rw + (size_t)(tid * 4) * TEXP;
  float acc[8];
#pragma unroll
  for (int e = 0; e < 8; e++) acc[e] = x0*rp[e] + x1*rp[8+e] + x2*rp[16+e] + x3*rp[24+e];
#pragma unroll
  for (int e = 0; e < 8; e++)
#pragma unroll
    for (int d = 1; d < 64; d <<= 1) acc[e] += __shfl_xor(acc[e], d, 64);
  if ((tid & 63) == 0)
#pragma unroll
    for (int e = 0; e < 8; e++) sacc[tid >> 6][e] = acc[e];
  __syncthreads();
  if (tid == 0) {
    float lg[8];
#pragma unroll
    for (int e = 0; e < 8; e++) lg[e] = sacc[0][e] + sacc[1][e] + sacc[2][e] + sacc[3][e];
    int i1 = 0;
#pragma unroll
    for (int e = 1; e < 8; e++) if (lg[e] > lg[i1]) i1 = e;
    int i2 = (i1 == 0) ? 1 : 0;
#pragma unroll
    for (int e = 0; e < 8; e++) if (e != i1 && lg[e] > lg[i2]) i2 = e;
    const float g1 = 1.0f / (1.0f + __expf(lg[i2] - lg[i1]));
    idx01[t*2] = i1; idx01[t*2+1] = i2;
    gate01[t*2] = g1; gate01[t*2+1] = 1.0f - g1;
    atomicAdd(&counts[i1], 1);
    atomicAdd(&counts[i2], 1);
  }
}

__global__ void zero8_k(int* counts) { if (threadIdx.x < TEXP) counts[threadIdx.x] = 0; }

__global__ void offsets_k(const int* __restrict__ counts, int* __restrict__ cursor,
                          int* __restrict__ bm_e, int* __restrict__ bm_s0,
                          int* __restrict__ bm_end, int* __restrict__ n_active) {
  if (threadIdx.x != 0 || blockIdx.x != 0) return;
  int off = 0, nb = 0;
  for (int e = 0; e < TEXP; e++) {
    const int c = counts[e];
    cursor[e] = off;
    const int end = off + c;
    for (int mb = 0; mb * 128 < c; mb++) { bm_e[nb] = e; bm_s0[nb] = off + mb * 128; bm_end[nb] = end; nb++; }
    off = end;
  }
  *n_active = nb;
}

__global__ void scatter_k(const int* __restrict__ idx01, int* __restrict__ cursor,
                          int* __restrict__ slot_of, int* __restrict__ perm) {
  const int t = blockIdx.x * 256 + threadIdx.x;
  if (t >= TTOK) return;
#pragma unroll
  for (int k = 0; k < 2; k++) {
    const int e = idx01[t*2+k];
    const int slot = atomicAdd(&cursor[e], 1);
    slot_of[t*2+k] = slot;
    perm[slot] = t;
  }
}

// ---------- MoE GEMM1: gathered rows, fused w1/w3, silu(z1)*z3 -> hbuf (dbuf + prefetch) ----------
__launch_bounds__(256)
__global__ void moe_gemm1_k(const u16* __restrict__ hn, const u16* __restrict__ w1t,
                            const u16* __restrict__ w3t, const int* __restrict__ perm,
                            const int* __restrict__ bm_e, const int* __restrict__ bm_s0,
                            const int* __restrict__ bm_end, const int* __restrict__ n_active,
                            u16* __restrict__ hbuf) {
  if ((int)blockIdx.x >= *n_active) return;
  __shared__ u16 sA[2][128 * 32], sB1[2][64 * 32], sB3[2][64 * 32];
  const int tid = threadIdx.x, wid = tid >> 6, lane = tid & 63;
  const int e = bm_e[blockIdx.x], slot0 = bm_s0[blockIdx.x], send = bm_end[blockIdx.x];
  const int n0 = blockIdx.y * 64;
  const int wr = wid >> 1, wc = wid & 1;
  const int srow = tid >> 2;
  const int scol = (((tid & 3) ^ ((tid >> 3) & 3)) * 8);
  const int sa0 = slot0 + srow, sa1 = slot0 + srow + 64;
  const int ta = (sa0 < send) ? perm[sa0] : 0;
  const int tb2 = (sa1 < send) ? perm[sa1] : 0;
  const size_t a0 = (size_t)ta * TDIM + scol;
  const size_t a1 = (size_t)tb2 * TDIM + scol;
  const size_t bb = (size_t)e * TDIM * TFF + (size_t)(n0 + srow) * TDIM + scol;
  const int ldsw = wid * 1024;
  f32x4 ac1[4][2], ac3[4][2];
#pragma unroll
  for (int i = 0; i < 4; i++)
#pragma unroll
    for (int j = 0; j < 2; j++) { ac1[i][j] = fzero(); ac3[i][j] = fzero(); }
  const int g = (lane >> 1) & 3;
  int aoffs[4], boffs[2];
#pragma unroll
  for (int mf = 0; mf < 4; mf++)
    aoffs[mf] = (wr*64 + mf*16 + (lane & 15)) * 64 + ((((lane >> 4)) ^ g) << 4);
#pragma unroll
  for (int nf = 0; nf < 2; nf++)
    boffs[nf] = (wc*32 + nf*16 + (lane & 15)) * 64 + ((((lane >> 4)) ^ g) << 4);

  auto stage = [&](int kk, int bi) {
    const int ke = kk * 32;
    gll16(hn + a0 + ke, (char*)sA[bi] + ldsw);
    gll16(hn + a1 + ke, (char*)sA[bi] + 4096 + ldsw);
    gll16(w1t + bb + ke, (char*)sB1[bi] + ldsw);
    gll16(w3t + bb + ke, (char*)sB3[bi] + ldsw);
  };

  stage(0, 0);
  asm volatile("s_waitcnt vmcnt(0)" ::: "memory");
  __builtin_amdgcn_s_barrier();

  for (int kk = 0; kk < 32; ++kk) {
    const int cur = kk & 1;
    if (kk + 1 < 32) stage(kk + 1, cur ^ 1);
    bf16x8 fa[4], f1[2], f3[2];
#pragma unroll
    for (int mf = 0; mf < 4; mf++) fa[mf] = ldsread((char*)sA[cur] + aoffs[mf]);
#pragma unroll
    for (int nf = 0; nf < 2; nf++) { f1[nf] = ldsread((char*)sB1[cur] + boffs[nf]); f3[nf] = ldsread((char*)sB3[cur] + boffs[nf]); }
#pragma unroll
    for (int mf = 0; mf < 4; mf++)
#pragma unroll
      for (int nf = 0; nf < 2; nf++) {
        ac1[mf][nf] = mm16(fa[mf], f1[nf], ac1[mf][nf]);
        ac3[mf][nf] = mm16(fa[mf], f3[nf], ac3[mf][nf]);
      }
    asm volatile("s_waitcnt vmcnt(0)" ::: "memory");
    __builtin_amdgcn_s_barrier();
  }

#pragma unroll
  for (int mf = 0; mf < 4; mf++)
#pragma unroll
    for (int nf = 0; nf < 2; nf++)
#pragma unroll
      for (int r = 0; r < 4; r++) {
        const int slot = slot0 + wr*64 + mf*16 + ((lane >> 4) * 4) + r;
        if (slot < send) {
          const int col = n0 + wc*32 + nf*16 + (lane & 15);
          const float z1 = ac1[mf][nf][r], z3 = ac3[mf][nf][r];
          const float hv = z1 / (1.0f + __expf(-z1)) * z3;
          hbuf[(size_t)slot * TFF + col] = f2bf(hv);
        }
      }
}

// ---------- MoE GEMM2: hbuf @ w2 -> pair outputs (dbuf + prefetch) ----------
__launch_bounds__(256)
__global__ void moe_gemm2_k(const u16* __restrict__ hbuf, const u16* __restrict__ w2t,
                            const int* __restrict__ bm_e, const int* __restrict__ bm_s0,
                            const int* __restrict__ bm_end, const int* __restrict__ n_active,
                            u16* __restrict__ pout) {
  if ((int)blockIdx.x >= *n_active) return;
  __shared__ u16 sA[2][128 * 32], sB[2][64 * 32];
  const int tid = threadIdx.x, wid = tid >> 6, lane = tid & 63;
  const int e = bm_e[blockIdx.x], slot0 = bm_s0[blockIdx.x], send = bm_end[blockIdx.x];
  const int n0 = blockIdx.y * 64;
  const int wr = wid >> 1, wc = wid & 1;
  const int srow = tid >> 2;
  const int scol = (((tid & 3) ^ ((tid >> 3) & 3)) * 8);
  int sa0 = slot0 + srow; if (sa0 > TPAIRS - 1) sa0 = TPAIRS - 1;
  int sa1 = slot0 + srow + 64; if (sa1 > TPAIRS - 1) sa1 = TPAIRS - 1;
  const size_t a0 = (size_t)sa0 * TFF + scol;
  const size_t a1 = (size_t)sa1 * TFF + scol;
  const size_t bb = (size_t)e * TDIM * TFF + (size_t)(n0 + srow) * TFF + scol;
  const int ldsw = wid * 1024;
  f32x4 acc[4][2];
#pragma unroll
  for (int i = 0; i < 4; i++)
#pragma unroll
    for (int j = 0; j < 2; j++) acc[i][j] = fzero();
  const int g = (lane >> 1) & 3;
  int aoffs[4], boffs[2];
#pragma unroll
  for (int mf = 0; mf < 4; mf++)
    aoffs[mf] = (wr*64 + mf*16 + (lane & 15)) * 64 + ((((lane >> 4)) ^ g) << 4);
#pragma unroll
  for (int nf = 0; nf < 2; nf++)
    boffs[nf] = (wc*32 + nf*16 + (lane & 15)) * 64 + ((((lane >> 4)) ^ g) << 4);

  auto stage = [&](int kk, int bi) {
    const int ke = kk * 32;
    gll16(hbuf + a0 + ke, (char*)sA[bi] + ldsw);
    gll16(hbuf + a1 + ke, (char*)sA[bi] + 4096 + ldsw);
    gll16(w2t + bb + ke, (char*)sB[bi] + ldsw);
  };

  stage(0, 0);
  asm volatile("s_waitcnt vmcnt(0)" ::: "memory");
  __builtin_amdgcn_s_barrier();

  for (int kk = 0; kk < 32; ++kk) {
    const int cur = kk & 1;
    if (kk + 1 < 32) stage(kk + 1, cur ^ 1);
    bf16x8 fa[4], fb[2];
#pragma unroll
    for (int mf = 0; mf < 4; mf++) fa[mf] = ldsread((char*)sA[cur] + aoffs[mf]);
#pragma unroll
    for (int nf = 0; nf < 2; nf++) fb[nf] = ldsread((char*)sB[cur] + boffs[nf]);
#pragma unroll
    for (int mf = 0; mf < 4; mf++)
#pragma unroll
      for (int nf = 0; nf < 2; nf++)
        acc[mf][nf] = mm16(fa[mf], fb[nf], acc[mf][nf]);
    asm volatile("s_waitcnt vmcnt(0)" ::: "memory");
    __builtin_amdgcn_s_barrier();
  }

#pragma unroll
  for (int mf = 0; mf < 4; mf++)
#pragma unroll
    for (int nf = 0; nf < 2; nf++)
#pragma unroll
      for (int r = 0; r < 4; r++) {
        const int slot = slot0 + wr*64 + mf*16 + ((lane >> 4) * 4) + r;
        if (slot < send) {
          const int col = n0 + wc*32 + nf*16 + (lane & 15);
          pout[(size_t)slot * TDIM + col] = f2bf(acc[mf][nf][r]);
        }
      }
}

// ---------- final combine: out = h + g0*pout[s0] + g1*pout[s1] ----------
__launch_bounds__(256)
__global__ void combine_k(const float* __restrict__ hres, const u16* __restrict__ pout,
                          const int* __restrict__ slot_of, const float* __restrict__ gate01,
                          float* __restrict__ out) {
  const int t = blockIdx.x, tid = threadIdx.x;
  const int s0 = slot_of[t*2], s1 = slot_of[t*2+1];
  const float g0 = gate01[t*2], g1 = gate01[t*2+1];
  const float4 hv = ((const float4*)(hres + (size_t)t * TDIM))[tid];
  const uint2 u0 = *(const uint2*)(pout + (size_t)s0 * TDIM + tid * 4);
  const uint2 u1 = *(const uint2*)(pout + (size_t)s1 * TDIM + tid * 4);
  float4 o;
  o.x = hv.x + g0 * bf2f((u16)(u0.x & 0xffff)) + g1 * bf2f((u16)(u1.x & 0xffff));
  o.y = hv.y + g0 * bf2f((u16)(u0.x >> 16))    + g1 * bf2f((u16)(u1.x >> 16));
  o.z = hv.z + g0 * bf2f((u16)(u0.y & 0xffff)) + g1 * bf2f((u16)(u1.y & 0xffff));
  o.w = hv.w + g0 * bf2f((u16)(u0.y >> 16))    + g1 * bf2f((u16)(u1.y >> 16));
  ((float4*)(out + (size_t)t * TDIM))[tid] = o;
}

extern "C" void kernel_launch(void* const* d_in, const int* in_sizes, int n_in,
                              void* d_out, int out_size, void* d_ws, size_t ws_size,
                              hipStream_t stream) {
  (void)in_sizes; (void)n_in; (void)out_size; (void)ws_size;
  const float* x   = (const float*)d_in[0];
  const float* anw = (const float*)d_in[1];
  const float* wq  = (const float*)d_in[2];
  const float* wk  = (const float*)d_in[3];
  const float* wv  = (const float*)d_in[4];
  const float* wo  = (const float*)d_in[5];
  const float* fnw = (const float*)d_in[6];
  const float* rw  = (const float*)d_in[7];
  const float* w1  = (const float*)d_in[8];
  const float* w3  = (const float*)d_in[9];
  const float* w2  = (const float*)d_in[10];
  float* out = (float*)d_out;

  char* ws = (char*)d_ws;
  size_t off = 0;
  auto take = [&](size_t bytes) -> char* {
    char* p = ws + off;
    off += (bytes + 255) & ~(size_t)255;
    return p;
  };
  const size_t SZ_W = (size_t)TDIM * TDIM * sizeof(u16);
  const size_t SZ_T = (size_t)TTOK * TDIM * sizeof(u16);
  u16* wqt_h = (u16*)take(SZ_W); u16* wqt_l = (u16*)take(SZ_W);
  u16* wkt_h = (u16*)take(SZ_W); u16* wkt_l = (u16*)take(SZ_W);
  u16* wvt_h = (u16*)take(SZ_W); u16* wvt_l = (u16*)take(SZ_W);
  u16* wot_h = (u16*)take(SZ_W); u16* wot_l = (u16*)take(SZ_W);
  u16* w1t = (u16*)take((size_t)TEXP * TDIM * TFF * sizeof(u16));
  u16* w3t = (u16*)take((size_t)TEXP * TDIM * TFF * sizeof(u16));
  u16* w2t = (u16*)take((size_t)TEXP * TDIM * TFF * sizeof(u16));
  u16* xnh = (u16*)take(SZ_T); u16* xnl = (u16*)take(SZ_T);
  u16* qh  = (u16*)take(SZ_T); u16* ql  = (u16*)take(SZ_T);
  u16* kh  = (u16*)take(SZ_T); u16* kl  = (u16*)take(SZ_T);
  u16* vth = (u16*)take(SZ_T); u16* vtl = (u16*)take(SZ_T);
  float* hres = (float*)take((size_t)TTOK * TDIM * sizeof(float));
  int*   idx01  = (int*)take(TTOK * 2 * 4);
  float* gate01 = (float*)take(TTOK * 2 * 4);
  int*   slot_of = (int*)take(TTOK * 2 * 4);
  int*   perm    = (int*)take(TPAIRS * 4);
  int*   counts  = (int*)take(256);
  int*   cursor  = (int*)take(256);
  int*   bm_e    = (int*)take(96 * 4);
  int*   bm_s0   = (int*)take(96 * 4);
  int*   bm_end  = (int*)take(96 * 4);
  int*   n_act   = (int*)take(256);
  u16* oh = xnh; u16* ol = xnl;
  u16* hn = qh;
  u16* hbuf = kh;
  u16* pout = vth;

  transpose_all_k<<<28672, dim3(32, 8), 0, stream>>>(wq, wk, wv, wo, w1, w3, w2,
                                                     wqt_h, wqt_l, wkt_h, wkt_l, wvt_h, wvt_l,
                                                     wot_h, wot_l, w1t, w3t, w2t);
  zero8_k<<<1, 64, 0, stream>>>(counts);
  rmsnorm_k<<<TTOK, 256, 0, stream>>>(x, anw, xnh, xnl);
  gemm_qkv_k<<<dim3(TTOK/128, 48), 256, 0, stream>>>(xnh, xnl, wqt_h, wqt_l, wkt_h, wkt_l,
                                                     wvt_h, wvt_l, qh, ql, kh, kl, vth, vtl);
  flash_k<<<dim3(TSEQ/128, TBATCH*THEADS), 256, 0, stream>>>(qh, ql, kh, kl, vth, vtl, oh, ol);
  gemm_x3_k<2><<<dim3(TTOK/128, TDIM/64), 256, 0, stream>>>(oh, ol, wot_h, wot_l, nullptr, nullptr, hres, x, TTOK, TDIM, TDIM);
  router_k<<<TTOK, 256, 0, stream>>>(hres, fnw, rw, hn, idx01, gate01, counts);
  offsets_k<<<1, 1, 0, stream>>>(counts, cursor, bm_e, bm_s0, bm_end, n_act);
  scatter_k<<<TTOK/256, 256, 0, stream>>>(idx01, cursor, slot_of, perm);
  moe_gemm1_k<<<dim3(72, TFF/64), 256, 0, stream>>>(hn, w1t, w3t, perm, bm_e, bm_s0, bm_end, n_act, hbuf);
  moe_gemm2_k<<<dim3(72, TDIM/64), 256, 0, stream>>>(hbuf, w2t, bm_e, bm_s0, bm_end, n_act, pout);
  combine_k<<<TTOK, 256, 0, stream>>>(hres, pout, slot_of, gate01, out);
}

// Round 28
// 574.330 us; speedup vs baseline: 1.3831x; 1.0027x over previous
//
#include <hip/hip_runtime.h>
#include <cstdint>
#include <math.h>

typedef unsigned short u16;
typedef unsigned int u32;
typedef __bf16 bf16x8 __attribute__((ext_vector_type(8)));
typedef float f32x4 __attribute__((ext_vector_type(4)));

#define TBATCH 2
#define TSEQ   2048
#define TDIM   1024
#define THEADS 16
#define THDIM  64
#define TEXP   8
#define TFF    1024
#define TTOK   (TBATCH*TSEQ)
#define TPAIRS (TTOK*2)

__device__ __forceinline__ u16 f2bf(float f) {
  u32 u = __float_as_uint(f);
  u += 0x7FFFu + ((u >> 16) & 1u);
  return (u16)(u >> 16);
}
__device__ __forceinline__ u16 f2bft(float f) {        // truncating split (1 op)
  return (u16)(__float_as_uint(f) >> 16);
}
__device__ __forceinline__ float bf2f(u16 h) { return __uint_as_float(((u32)h) << 16); }
__device__ __forceinline__ float fexp2(float x) {      // raw v_exp_f32 (exp2)
  float r;
  asm("v_exp_f32 %0, %1" : "=v"(r) : "v"(x));
  return r;
}

__device__ __forceinline__ void gll16(const void* g, void* l) {
  __builtin_amdgcn_global_load_lds((const __attribute__((address_space(1))) void*)g,
                                   (__attribute__((address_space(3))) void*)l, 16, 0, 0);
}
__device__ __forceinline__ bf16x8 ldsread(const void* p) { return *(const bf16x8*)p; }
__device__ __forceinline__ f32x4 mm16(bf16x8 a, bf16x8 b, f32x4 c) {
  return __builtin_amdgcn_mfma_f32_16x16x32_bf16(a, b, c, 0, 0, 0);
}
__device__ __forceinline__ f32x4 fzero() { f32x4 z = {0.f, 0.f, 0.f, 0.f}; return z; }

// ---------- ALL weight transposes in ONE launch: f32 [z][1024][1024] -> bf16 [z][1024][1024]^T ----------
__global__ void transpose_all_k(const float* __restrict__ wq, const float* __restrict__ wk,
                                const float* __restrict__ wv, const float* __restrict__ wo,
                                const float* __restrict__ w1, const float* __restrict__ w3,
                                const float* __restrict__ w2,
                                u16* __restrict__ qth, u16* __restrict__ qtl,
                                u16* __restrict__ kth, u16* __restrict__ ktl,
                                u16* __restrict__ vth_, u16* __restrict__ vtl_,
                                u16* __restrict__ oth, u16* __restrict__ otl,
                                u16* __restrict__ w1t, u16* __restrict__ w3t, u16* __restrict__ w2t) {
  __shared__ float t[32][33];
  int id = (int)blockIdx.x;
  const float* in; u16* outh; u16* outl = nullptr;
  size_t bo = 0;
  int tile;
  if (id < 4096) {
    const int wi = id >> 10;
    in   = (wi == 0) ? wq  : (wi == 1) ? wk  : (wi == 2) ? wv   : wo;
    outh = (wi == 0) ? qth : (wi == 1) ? kth : (wi == 2) ? vth_ : oth;
    outl = (wi == 0) ? qtl : (wi == 1) ? ktl : (wi == 2) ? vtl_ : otl;
    tile = id & 1023;
  } else {
    const int id2 = id - 4096;
    const int wi = id2 >> 13;                 // 0=w1 1=w3 2=w2
    const int rem = id2 & 8191;
    bo = (size_t)(rem >> 10) << 20;           // z * 1024*1024
    in   = (wi == 0) ? w1  : (wi == 1) ? w3  : w2;
    outh = (wi == 0) ? w1t : (wi == 1) ? w3t : w2t;
    tile = rem & 1023;
  }
  const int c0 = (tile & 31) * 32, r0 = (tile >> 5) * 32;
  const int tx = threadIdx.x, ty = threadIdx.y;
#pragma unroll
  for (int j = 0; j < 32; j += 8)
    t[ty + j][tx] = in[bo + (size_t)(r0 + ty + j) * 1024 + (c0 + tx)];
  __syncthreads();
#pragma unroll
  for (int j = 0; j < 32; j += 8) {
    float v = t[tx][ty + j];
    u16 hv = f2bf(v);
    size_t o = bo + (size_t)(c0 + ty + j) * 1024 + (r0 + tx);
    outh[o] = hv;
    if (outl != nullptr) outl[o] = f2bf(v - bf2f(hv));
  }
}

// ---------- RMSNorm: f32 [T][D] -> bf16 split (attn input) ----------
__launch_bounds__(256)
__global__ void rmsnorm_k(const float* __restrict__ x, const float* __restrict__ w,
                          u16* __restrict__ oh, u16* __restrict__ ol) {
  const int t = blockIdx.x, tid = threadIdx.x;
  const float4 xv = ((const float4*)(x + (size_t)t * TDIM))[tid];
  float ss = xv.x*xv.x + xv.y*xv.y + xv.z*xv.z + xv.w*xv.w;
#pragma unroll
  for (int d = 1; d < 64; d <<= 1) ss += __shfl_xor(ss, d, 64);
  __shared__ float sp[4];
  if ((tid & 63) == 0) sp[tid >> 6] = ss;
  __syncthreads();
  const float rsc = rsqrtf((sp[0] + sp[1] + sp[2] + sp[3]) * (1.0f / TDIM) + 1e-6f);
  const float4 wv = ((const float4*)w)[tid];
  float v0 = xv.x*rsc*wv.x, v1 = xv.y*rsc*wv.y, v2 = xv.z*rsc*wv.z, v3 = xv.w*rsc*wv.w;
  u16 h0 = f2bf(v0), h1 = f2bf(v1), h2 = f2bf(v2), h3 = f2bf(v3);
  uint2 ph; ph.x = (u32)h0 | ((u32)h1 << 16); ph.y = (u32)h2 | ((u32)h3 << 16);
  *(uint2*)(oh + (size_t)t * TDIM + tid * 4) = ph;
  u16 l0 = f2bf(v0 - bf2f(h0)), l1 = f2bf(v1 - bf2f(h1));
  u16 l2 = f2bf(v2 - bf2f(h2)), l3 = f2bf(v3 - bf2f(h3));
  uint2 pl; pl.x = (u32)l0 | ((u32)l1 << 16); pl.y = (u32)l2 | ((u32)l3 << 16);
  *(uint2*)(ol + (size_t)t * TDIM + tid * 4) = pl;
}

// ---------- fused QKV bf16x3 GEMM: one launch, blockIdx.y selects Q/K/V (grid 32 x 48) ----------
// Q output is pre-scaled by 1/sqrt(HD)*log2(e) so flash_k's softmax works directly in exp2 domain.
__launch_bounds__(256)
__global__ void gemm_qkv_k(const u16* __restrict__ Ah, const u16* __restrict__ Al,
                           const u16* __restrict__ Bqh, const u16* __restrict__ Bql,
                           const u16* __restrict__ Bkh, const u16* __restrict__ Bkl,
                           const u16* __restrict__ Bvh, const u16* __restrict__ Bvl,
                           u16* __restrict__ qh, u16* __restrict__ ql,
                           u16* __restrict__ kh, u16* __restrict__ kl,
                           u16* __restrict__ vth, u16* __restrict__ vtl) {
  __shared__ u16 sAh[2][128 * 32], sAl[2][128 * 32], sBh[2][64 * 32], sBl[2][64 * 32];
  const int tid = threadIdx.x, wid = tid >> 6, lane = tid & 63;
  const int which = blockIdx.y >> 4;                 // 0=Q 1=K 2=V (block-uniform)
  const int m0 = blockIdx.x * 128, n0 = (blockIdx.y & 15) * 64;
  const int wr = wid >> 1, wc = wid & 1;
  const u16* Bth = (which == 0) ? Bqh : (which == 1) ? Bkh : Bvh;
  const u16* Btl = (which == 0) ? Bql : (which == 1) ? Bkl : Bvl;
  u16* outh = (which == 0) ? qh : kh;
  u16* outl = (which == 0) ? ql : kl;

  f32x4 acc[4][2];
#pragma unroll
  for (int i = 0; i < 4; i++)
#pragma unroll
    for (int j = 0; j < 2; j++) acc[i][j] = fzero();

  const int srow = tid >> 2;
  const int scol = (((tid & 3) ^ ((tid >> 3) & 3)) * 8);
  const size_t a0 = (size_t)(m0 + srow) * TDIM + scol;
  const size_t a1 = (size_t)(m0 + srow + 64) * TDIM + scol;
  const size_t b0 = (size_t)(n0 + srow) * TDIM + scol;
  const int ldsw = wid * 1024;

  const int g = (lane >> 1) & 3;
  int aoffs[4], boffs[2];
#pragma unroll
  for (int mf = 0; mf < 4; mf++)
    aoffs[mf] = (wr*64 + mf*16 + (lane & 15)) * 64 + ((((lane >> 4)) ^ g) << 4);
#pragma unroll
  for (int nf = 0; nf < 2; nf++)
    boffs[nf] = (wc*32 + nf*16 + (lane & 15)) * 64 + ((((lane >> 4)) ^ g) << 4);

  auto stage = [&](int kk, int bi) {
    const int ke = kk * 32;
    gll16(Ah + a0 + ke, (char*)sAh[bi] + ldsw);
    gll16(Ah + a1 + ke, (char*)sAh[bi] + 4096 + ldsw);
    gll16(Al + a0 + ke, (char*)sAl[bi] + ldsw);
    gll16(Al + a1 + ke, (char*)sAl[bi] + 4096 + ldsw);
    gll16(Bth + b0 + ke, (char*)sBh[bi] + ldsw);
    gll16(Btl + b0 + ke, (char*)sBl[bi] + ldsw);
  };

  stage(0, 0);
  asm volatile("s_waitcnt vmcnt(0)" ::: "memory");
  __builtin_amdgcn_s_barrier();

  for (int kk = 0; kk < 32; ++kk) {
    const int cur = kk & 1;
    if (kk + 1 < 32) stage(kk + 1, cur ^ 1);
    bf16x8 fah[4], fal[4], fbh[2], fbl[2];
#pragma unroll
    for (int mf = 0; mf < 4; mf++) { fah[mf] = ldsread((char*)sAh[cur] + aoffs[mf]); fal[mf] = ldsread((char*)sAl[cur] + aoffs[mf]); }
#pragma unroll
    for (int nf = 0; nf < 2; nf++) { fbh[nf] = ldsread((char*)sBh[cur] + boffs[nf]); fbl[nf] = ldsread((char*)sBl[cur] + boffs[nf]); }
#pragma unroll
    for (int mf = 0; mf < 4; mf++)
#pragma unroll
      for (int nf = 0; nf < 2; nf++) {
        acc[mf][nf] = mm16(fah[mf], fbh[nf], acc[mf][nf]);
        acc[mf][nf] = mm16(fah[mf], fbl[nf], acc[mf][nf]);
        acc[mf][nf] = mm16(fal[mf], fbh[nf], acc[mf][nf]);
      }
    asm volatile("s_waitcnt vmcnt(0)" ::: "memory");
    __builtin_amdgcn_s_barrier();
  }

  const float qscale = (which == 0) ? 0.18033688011112042f : 1.0f;  // 0.125 * log2(e)
#pragma unroll
  for (int mf = 0; mf < 4; mf++)
#pragma unroll
    for (int nf = 0; nf < 2; nf++)
#pragma unroll
      for (int r = 0; r < 4; r++) {
        const int grow = m0 + wr*64 + mf*16 + ((lane >> 4) * 4) + r;
        const int gcol = n0 + wc*32 + nf*16 + (lane & 15);
        const float v = acc[mf][nf][r] * qscale;
        u16 hv = f2bf(v);
        u16 lv = f2bf(v - bf2f(hv));
        if (which < 2) {
          const size_t o = (size_t)grow * TDIM + gcol;
          outh[o] = hv; outl[o] = lv;
        } else {
          const int b = grow >> 11, s = grow & (TSEQ - 1);
          const int hh = gcol >> 6, hd = gcol & 63;
          const size_t o = ((size_t)((b * THEADS + hh) * THDIM + hd)) * TSEQ + s;
          vth[o] = hv; vtl[o] = lv;
        }
      }
}

// ---------- bf16x3 GEMM (WO): 2-buffer + prefetch; EPI2 = f32 out + resid ----------
template<int EPI>
__launch_bounds__(256)
__global__ void gemm_x3_k(const u16* __restrict__ Ah, const u16* __restrict__ Al,
                          const u16* __restrict__ Bth, const u16* __restrict__ Btl,
                          u16* __restrict__ outh, u16* __restrict__ outl,
                          float* __restrict__ outf, const float* __restrict__ resid,
                          int M, int N, int K) {
  __shared__ u16 sAh[2][128 * 32], sAl[2][128 * 32], sBh[2][64 * 32], sBl[2][64 * 32];
  const int tid = threadIdx.x, wid = tid >> 6, lane = tid & 63;
  const int m0 = blockIdx.x * 128, n0 = blockIdx.y * 64;
  const int wr = wid >> 1, wc = wid & 1;

  f32x4 acc[4][2];
#pragma unroll
  for (int i = 0; i < 4; i++)
#pragma unroll
    for (int j = 0; j < 2; j++) acc[i][j] = fzero();

  const int srow = tid >> 2;
  const int scol = (((tid & 3) ^ ((tid >> 3) & 3)) * 8);
  const size_t a0 = (size_t)(m0 + srow) * K + scol;
  const size_t a1 = (size_t)(m0 + srow + 64) * K + scol;
  const size_t b0 = (size_t)(n0 + srow) * K + scol;
  const int ldsw = wid * 1024;

  const int g = (lane >> 1) & 3;
  int aoffs[4], boffs[2];
#pragma unroll
  for (int mf = 0; mf < 4; mf++)
    aoffs[mf] = (wr*64 + mf*16 + (lane & 15)) * 64 + ((((lane >> 4)) ^ g) << 4);
#pragma unroll
  for (int nf = 0; nf < 2; nf++)
    boffs[nf] = (wc*32 + nf*16 + (lane & 15)) * 64 + ((((lane >> 4)) ^ g) << 4);

  auto stage = [&](int kk, int bi) {
    const int ke = kk * 32;
    gll16(Ah + a0 + ke, (char*)sAh[bi] + ldsw);
    gll16(Ah + a1 + ke, (char*)sAh[bi] + 4096 + ldsw);
    gll16(Al + a0 + ke, (char*)sAl[bi] + ldsw);
    gll16(Al + a1 + ke, (char*)sAl[bi] + 4096 + ldsw);
    gll16(Bth + b0 + ke, (char*)sBh[bi] + ldsw);
    gll16(Btl + b0 + ke, (char*)sBl[bi] + ldsw);
  };

  const int nk = K >> 5;
  stage(0, 0);
  asm volatile("s_waitcnt vmcnt(0)" ::: "memory");
  __builtin_amdgcn_s_barrier();

  for (int kk = 0; kk < nk; ++kk) {
    const int cur = kk & 1;
    if (kk + 1 < nk) stage(kk + 1, cur ^ 1);
    bf16x8 fah[4], fal[4], fbh[2], fbl[2];
#pragma unroll
    for (int mf = 0; mf < 4; mf++) { fah[mf] = ldsread((char*)sAh[cur] + aoffs[mf]); fal[mf] = ldsread((char*)sAl[cur] + aoffs[mf]); }
#pragma unroll
    for (int nf = 0; nf < 2; nf++) { fbh[nf] = ldsread((char*)sBh[cur] + boffs[nf]); fbl[nf] = ldsread((char*)sBl[cur] + boffs[nf]); }
#pragma unroll
    for (int mf = 0; mf < 4; mf++)
#pragma unroll
      for (int nf = 0; nf < 2; nf++) {
        acc[mf][nf] = mm16(fah[mf], fbh[nf], acc[mf][nf]);
        acc[mf][nf] = mm16(fah[mf], fbl[nf], acc[mf][nf]);
        acc[mf][nf] = mm16(fal[mf], fbh[nf], acc[mf][nf]);
      }
    asm volatile("s_waitcnt vmcnt(0)" ::: "memory");
    __builtin_amdgcn_s_barrier();
  }

#pragma unroll
  for (int mf = 0; mf < 4; mf++)
#pragma unroll
    for (int nf = 0; nf < 2; nf++)
#pragma unroll
      for (int r = 0; r < 4; r++) {
        const int grow = m0 + wr*64 + mf*16 + ((lane >> 4) * 4) + r;
        const int gcol = n0 + wc*32 + nf*16 + (lane & 15);
        const float v = acc[mf][nf][r];
        if (EPI == 0) {
          const size_t o = (size_t)grow * N + gcol;
          u16 hv = f2bf(v);
          outh[o] = hv; outl[o] = f2bf(v - bf2f(hv));
        } else if (EPI == 1) {
          const int b = grow >> 11, s = grow & (TSEQ - 1);
          const int hh = gcol >> 6, hd = gcol & 63;
          const size_t o = ((size_t)((b * THEADS + hh) * THDIM + hd)) * TSEQ + s;
          u16 hv = f2bf(v);
          outh[o] = hv; outl[o] = f2bf(v - bf2f(hv));
        } else {
          const size_t o = (size_t)grow * N + gcol;
          outf[o] = v + resid[o];
        }
      }
}

// ---------- causal flash attention, bf16x3, QBLK=128: shared K reads, hoisted P reads, defer-max, setprio,
// ---------- fully-visible-tile fast path (skips causal compare/select on below-diagonal tiles) ----------
__launch_bounds__(256)
__global__ void flash_k(const u16* __restrict__ Qh, const u16* __restrict__ Ql,
                        const u16* __restrict__ Kh, const u16* __restrict__ Kl,
                        const u16* __restrict__ Vth, const u16* __restrict__ Vtl,
                        u16* __restrict__ Oh, u16* __restrict__ Ol) {
  __shared__ u16 sK[2][2][4096];   // [buf][hi/lo][64x64] rows 128B
  __shared__ u16 sV[2][2][4096];
  __shared__ u16 sP[2][4][1024];   // [hi/lo][warp][16x64], reused by both halves
  const int tid = threadIdx.x, wid = tid >> 6, lane = tid & 63;
  const int qb = (int)(gridDim.x - 1 - blockIdx.x);   // longest-first
  const int bh = blockIdx.y;
  const int b = bh >> 4, h = bh & 15;
  const int srow = tid >> 3;
  const int sxcol = (((lane & 7) ^ ((lane >> 3) & 7)) << 3);
  const int ldsw = wid * 1024;

  // Q fragments for both 64-row halves, straight from global (16B/lane contiguous).
  // Q is pre-scaled by 0.125*log2(e) in gemm_qkv_k -> scores arrive in exp2 domain.
  bf16x8 fqh[2][2], fql[2][2];
#pragma unroll
  for (int hh = 0; hh < 2; hh++) {
    const size_t qbase = ((size_t)(b * TSEQ + qb * 128 + hh * 64 + wid * 16 + (lane & 15))) * TDIM + h * 64;
#pragma unroll
    for (int kq = 0; kq < 2; kq++) {
      fqh[hh][kq] = *(const bf16x8*)(Qh + qbase + (kq * 4 + (lane >> 4)) * 8);
      fql[hh][kq] = *(const bf16x8*)(Ql + qbase + (kq * 4 + (lane >> 4)) * 8);
    }
  }

  f32x4 oacc[2][4];
  float m_run[2][4], l_lane[2][4];
#pragma unroll
  for (int hh = 0; hh < 2; hh++)
#pragma unroll
    for (int i = 0; i < 4; i++) { oacc[hh][i] = fzero(); m_run[hh][i] = -INFINITY; l_lane[hh][i] = 0.f; }

  const size_t kg0 = ((size_t)(b * TSEQ + srow)) * TDIM + h * 64 + sxcol;
  const size_t kg1 = kg0 + (size_t)32 * TDIM;
  const size_t vg0 = ((size_t)((b * THEADS + h) * THDIM + srow)) * TSEQ + sxcol;
  const size_t vg1 = vg0 + (size_t)32 * TSEQ;

  auto stage = [&](int kb, int bi) {
    const size_t ko = (size_t)kb * 64 * TDIM;
    const size_t vo = (size_t)kb * 64;
    gll16(Kh + kg0 + ko, (char*)sK[bi][0] + ldsw);
    gll16(Kh + kg1 + ko, (char*)sK[bi][0] + 4096 + ldsw);
    gll16(Kl + kg0 + ko, (char*)sK[bi][1] + ldsw);
    gll16(Kl + kg1 + ko, (char*)sK[bi][1] + 4096 + ldsw);
    gll16(Vth + vg0 + vo, (char*)sV[bi][0] + ldsw);
    gll16(Vth + vg1 + vo, (char*)sV[bi][0] + 4096 + ldsw);
    gll16(Vtl + vg0 + vo, (char*)sV[bi][1] + ldsw);
    gll16(Vtl + vg1 + vo, (char*)sV[bi][1] + 4096 + ldsw);
  };

  const int nkb = 2 * qb + 2;
  stage(0, 0);
  asm volatile("s_waitcnt vmcnt(0)" ::: "memory");
  __builtin_amdgcn_s_barrier();

  for (int kb = 0; kb < nkb; ++kb) {
    const int cur = kb & 1;
    if (kb + 1 < nkb) stage(kb + 1, cur ^ 1);

    // QK^T for BOTH halves, sharing each K-fragment read (16 -> 8 reads/iter)
    f32x4 sc[2][4];
    __builtin_amdgcn_s_setprio(1);
#pragma unroll
    for (int nf = 0; nf < 4; nf++) {
      f32x4 s0 = fzero(), s1 = fzero();
      const int krow = nf * 16 + (lane & 15);
#pragma unroll
      for (int kq = 0; kq < 2; kq++) {
        const int off = krow * 128 + (((kq * 4 + (lane >> 4)) ^ (lane & 7)) << 4);
        bf16x8 kfh = ldsread((char*)sK[cur][0] + off);
        bf16x8 kfl = ldsread((char*)sK[cur][1] + off);
        s0 = mm16(fqh[0][kq], kfh, s0);
        s0 = mm16(fqh[0][kq], kfl, s0);
        s0 = mm16(fql[0][kq], kfh, s0);
        s1 = mm16(fqh[1][kq], kfh, s1);
        s1 = mm16(fqh[1][kq], kfl, s1);
        s1 = mm16(fql[1][kq], kfh, s1);
      }
      sc[0][nf] = s0; sc[1][nf] = s1;
    }
    __builtin_amdgcn_s_setprio(0);

#pragma unroll
    for (int hh = 0; hh < 2; hh++) {
      // half hh covers q rows [qb*128+hh*64, +64); skip softmax/PV if fully masked
      if (kb * 64 > qb * 128 + hh * 64 + 63) continue;

      const int qg = qb * 128 + hh * 64 + wid * 16 + ((lane >> 4) * 4);
      float pm[4] = {-INFINITY, -INFINITY, -INFINITY, -INFINITY};
      // fully-visible fast path: tile max kv index <= half's min q row -> no causal compare needed
      if (kb * 64 + 63 <= qb * 128 + hh * 64) {
#pragma unroll
        for (int nf = 0; nf < 4; nf++)
#pragma unroll
          for (int r = 0; r < 4; r++) pm[r] = fmaxf(pm[r], sc[hh][nf][r]);
      } else {
#pragma unroll
        for (int nf = 0; nf < 4; nf++) {
          const int kg = kb * 64 + nf * 16 + (lane & 15);
#pragma unroll
          for (int r = 0; r < 4; r++) {
            float v = sc[hh][nf][r];             // already exp2-domain (Q pre-scaled)
            if (kg > qg + r) v = -INFINITY;
            sc[hh][nf][r] = v;
            pm[r] = fmaxf(pm[r], v);
          }
        }
      }
#pragma unroll
      for (int r = 0; r < 4; r++)
#pragma unroll
        for (int d = 1; d < 16; d <<= 1) pm[r] = fmaxf(pm[r], __shfl_xor(pm[r], d, 64));

      // defer-max (T13): skip O/l rescale when tile max within 8 (exp2-domain) of running max.
      // P then bounded by 2^8; f32 accumulators have ample headroom. First tile: m_run=-inf -> taken.
      const float dm = fmaxf(fmaxf(pm[0] - m_run[hh][0], pm[1] - m_run[hh][1]),
                             fmaxf(pm[2] - m_run[hh][2], pm[3] - m_run[hh][3]));
      if (!__all(dm <= 8.0f)) {
#pragma unroll
        for (int r = 0; r < 4; r++) {
          const float mn = fmaxf(m_run[hh][r], pm[r]);
          const float esc = fexp2(m_run[hh][r] - mn);
          m_run[hh][r] = mn;
          l_lane[hh][r] *= esc;
#pragma unroll
          for (int nf = 0; nf < 4; nf++) oacc[hh][nf][r] *= esc;
        }
      }
      float ls[4] = {0.f, 0.f, 0.f, 0.f};
#pragma unroll
      for (int nf = 0; nf < 4; nf++)
#pragma unroll
        for (int r = 0; r < 4; r++) {
          float p = fexp2(sc[hh][nf][r] - m_run[hh][r]);
          sc[hh][nf][r] = p;
          ls[r] += p;
        }
#pragma unroll
      for (int r = 0; r < 4; r++) l_lane[hh][r] += ls[r];

      // P store (truncating hi/lo split; per-warp private, swizzled, no barrier)
#pragma unroll
      for (int nf = 0; nf < 4; nf++)
#pragma unroll
        for (int r = 0; r < 4; r++) {
          float p = sc[hh][nf][r];
          u16 ph = f2bft(p);
          const int prow = (lane >> 4) * 4 + r;
          const int pbyte = (prow * 128 + (nf * 16 + (lane & 15)) * 2) ^ ((prow & 7) << 4);
          *(u16*)((char*)sP[0][wid] + pbyte) = ph;
          *(u16*)((char*)sP[1][wid] + pbyte) = f2bft(p - bf2f(ph));
        }

      // PV: kq-outer so P fragments are read ONCE per kq (16 -> 4 reads/iter total)
      __builtin_amdgcn_s_setprio(1);
#pragma unroll
      for (int kq = 0; kq < 2; kq++) {
        const int prow = lane & 15;
        const int poff = prow * 128 + (((kq * 4 + (lane >> 4)) ^ (prow & 7)) << 4);
        bf16x8 pah = ldsread((char*)sP[0][wid] + poff);
        bf16x8 pal = ldsread((char*)sP[1][wid] + poff);
#pragma unroll
        for (int nf = 0; nf < 4; nf++) {
          const int vrow = nf * 16 + (lane & 15);
          const int voff = vrow * 128 + (((kq * 4 + (lane >> 4)) ^ (lane & 7)) << 4);
          bf16x8 vfh = ldsread((char*)sV[cur][0] + voff);
          bf16x8 vfl = ldsread((char*)sV[cur][1] + voff);
          oacc[hh][nf] = mm16(pah, vfh, oacc[hh][nf]);
          oacc[hh][nf] = mm16(pah, vfl, oacc[hh][nf]);
          oacc[hh][nf] = mm16(pal, vfh, oacc[hh][nf]);
        }
      }
      __builtin_amdgcn_s_setprio(0);
    }
    asm volatile("s_waitcnt vmcnt(0)" ::: "memory");
    __builtin_amdgcn_s_barrier();
  }

#pragma unroll
  for (int hh = 0; hh < 2; hh++)
#pragma unroll
    for (int r = 0; r < 4; r++) {
      float lt = l_lane[hh][r];
#pragma unroll
      for (int d = 1; d < 16; d <<= 1) lt += __shfl_xor(lt, d, 64);
      const float inv = 1.0f / lt;
      const int t = b * TSEQ + qb * 128 + hh * 64 + wid * 16 + ((lane >> 4) * 4) + r;
#pragma unroll
      for (int nf = 0; nf < 4; nf++) {
        const float v = oacc[hh][nf][r] * inv;
        const size_t o = (size_t)t * TDIM + h * 64 + nf * 16 + (lane & 15);
        u16 hv = f2bft(v);
        Oh[o] = hv; Ol[o] = f2bft(v - bf2f(hv));
      }
    }
}

// ---------- router (+ writes ffn-norm bf16): f32 logits from h, top-2, histogram ----------
__launch_bounds__(256)
__global__ void router_k(const float* __restrict__ hres, const float* __restrict__ wn,
                         const float* __restrict__ rw, u16* __restrict__ hn,
                         int* __restrict__ idx01, float* __restrict__ gate01,
                         int* __restrict__ counts) {
  const int t = blockIdx.x, tid = threadIdx.x;
  const float4 xv = ((const float4*)(hres + (size_t)t * TDIM))[tid];
  float ss = xv.x*xv.x + xv.y*xv.y + xv.z*xv.z + xv.w*xv.w;
#pragma unroll
  for (int d = 1; d < 64; d <<= 1) ss += __shfl_xor(ss, d, 64);
  __shared__ float sp[4];
  __shared__ float sacc[4][8];
  if ((tid & 63) == 0) sp[tid >> 6] = ss;
  __syncthreads();
  const float rsc = rsqrtf((sp[0]+sp[1]+sp[2]+sp[3]) * (1.0f / TDIM) + 1e-6f);
  const float4 wv = ((const float4*)wn)[tid];
  const float x0 = xv.x*rsc*wv.x, x1 = xv.y*rsc*wv.y, x2 = xv.z*rsc*wv.z, x3 = xv.w*rsc*wv.w;
  {
    u16 h0 = f2bf(x0), h1 = f2bf(x1), h2 = f2bf(x2), h3 = f2bf(x3);
    uint2 ph; ph.x = (u32)h0 | ((u32)h1 << 16); ph.y = (u32)h2 | ((u32)h3 << 16);
    *(uint2*)(hn + (size_t)t * TDIM + tid * 4) = ph;
  }
  const float* rp = rw + (size_t)(tid * 4) * TEXP;
  float acc[8];
#pragma unroll
  for (int e = 0; e < 8; e++) acc[e] = x0*rp[e] + x1*rp[8+e] + x2*rp[16+e] + x3*rp[24+e];
#pragma unroll
  for (int e = 0; e < 8; e++)
#pragma unroll
    for (int d = 1; d < 64; d <<= 1) acc[e] += __shfl_xor(acc[e], d, 64);
  if ((tid & 63) == 0)
#pragma unroll
    for (int e = 0; e < 8; e++) sacc[tid >> 6][e] = acc[e];
  __syncthreads();
  if (tid == 0) {
    float lg[8];
#pragma unroll
    for (int e = 0; e < 8; e++) lg[e] = sacc[0][e] + sacc[1][e] + sacc[2][e] + sacc[3][e];
    int i1 = 0;
#pragma unroll
    for (int e = 1; e < 8; e++) if (lg[e] > lg[i1]) i1 = e;
    int i2 = (i1 == 0) ? 1 : 0;
#pragma unroll
    for (int e = 0; e < 8; e++) if (e != i1 && lg[e] > lg[i2]) i2 = e;
    const float g1 = 1.0f / (1.0f + __expf(lg[i2] - lg[i1]));
    idx01[t*2] = i1; idx01[t*2+1] = i2;
    gate01[t*2] = g1; gate01[t*2+1] = 1.0f - g1;
    atomicAdd(&counts[i1], 1);
    atomicAdd(&counts[i2], 1);
  }
}

__global__ void zero8_k(int* counts) { if (threadIdx.x < TEXP) counts[threadIdx.x] = 0; }

__global__ void offsets_k(const int* __restrict__ counts, int* __restrict__ cursor,
                          int* __restrict__ bm_e, int* __restrict__ bm_s0,
                          int* __restrict__ bm_end, int* __restrict__ n_active) {
  if (threadIdx.x != 0 || blockIdx.x != 0) return;
  int off = 0, nb = 0;
  for (int e = 0; e < TEXP; e++) {
    const int c = counts[e];
    cursor[e] = off;
    const int end = off + c;
    for (int mb = 0; mb * 128 < c; mb++) { bm_e[nb] = e; bm_s0[nb] = off + mb * 128; bm_end[nb] = end; nb++; }
    off = end;
  }
  *n_active = nb;
}

__global__ void scatter_k(const int* __restrict__ idx01, int* __restrict__ cursor,
                          int* __restrict__ slot_of, int* __restrict__ perm) {
  const int t = blockIdx.x * 256 + threadIdx.x;
  if (t >= TTOK) return;
#pragma unroll
  for (int k = 0; k < 2; k++) {
    const int e = idx01[t*2+k];
    const int slot = atomicAdd(&cursor[e], 1);
    slot_of[t*2+k] = slot;
    perm[slot] = t;
  }
}

// ---------- MoE GEMM1: gathered rows, fused w1/w3, silu(z1)*z3 -> hbuf (dbuf + prefetch) ----------
__launch_bounds__(256)
__global__ void moe_gemm1_k(const u16* __restrict__ hn, const u16* __restrict__ w1t,
                            const u16* __restrict__ w3t, const int* __restrict__ perm,
                            const int* __restrict__ bm_e, const int* __restrict__ bm_s0,
                            const int* __restrict__ bm_end, const int* __restrict__ n_active,
                            u16* __restrict__ hbuf) {
  if ((int)blockIdx.x >= *n_active) return;
  __shared__ u16 sA[2][128 * 32], sB1[2][64 * 32], sB3[2][64 * 32];
  const int tid = threadIdx.x, wid = tid >> 6, lane = tid & 63;
  const int e = bm_e[blockIdx.x], slot0 = bm_s0[blockIdx.x], send = bm_end[blockIdx.x];
  const int n0 = blockIdx.y * 64;
  const int wr = wid >> 1, wc = wid & 1;
  const int srow = tid >> 2;
  const int scol = (((tid & 3) ^ ((tid >> 3) & 3)) * 8);
  const int sa0 = slot0 + srow, sa1 = slot0 + srow + 64;
  const int ta = (sa0 < send) ? perm[sa0] : 0;
  const int tb2 = (sa1 < send) ? perm[sa1] : 0;
  const size_t a0 = (size_t)ta * TDIM + scol;
  const size_t a1 = (size_t)tb2 * TDIM + scol;
  const size_t bb = (size_t)e * TDIM * TFF + (size_t)(n0 + srow) * TDIM + scol;
  const int ldsw = wid * 1024;
  f32x4 ac1[4][2], ac3[4][2];
#pragma unroll
  for (int i = 0; i < 4; i++)
#pragma unroll
    for (int j = 0; j < 2; j++) { ac1[i][j] = fzero(); ac3[i][j] = fzero(); }
  const int g = (lane >> 1) & 3;
  int aoffs[4], boffs[2];
#pragma unroll
  for (int mf = 0; mf < 4; mf++)
    aoffs[mf] = (wr*64 + mf*16 + (lane & 15)) * 64 + ((((lane >> 4)) ^ g) << 4);
#pragma unroll
  for (int nf = 0; nf < 2; nf++)
    boffs[nf] = (wc*32 + nf*16 + (lane & 15)) * 64 + ((((lane >> 4)) ^ g) << 4);

  auto stage = [&](int kk, int bi) {
    const int ke = kk * 32;
    gll16(hn + a0 + ke, (char*)sA[bi] + ldsw);
    gll16(hn + a1 + ke, (char*)sA[bi] + 4096 + ldsw);
    gll16(w1t + bb + ke, (char*)sB1[bi] + ldsw);
    gll16(w3t + bb + ke, (char*)sB3[bi] + ldsw);
  };

  stage(0, 0);
  asm volatile("s_waitcnt vmcnt(0)" ::: "memory");
  __builtin_amdgcn_s_barrier();

  for (int kk = 0; kk < 32; ++kk) {
    const int cur = kk & 1;
    if (kk + 1 < 32) stage(kk + 1, cur ^ 1);
    bf16x8 fa[4], f1[2], f3[2];
#pragma unroll
    for (int mf = 0; mf < 4; mf++) fa[mf] = ldsread((char*)sA[cur] + aoffs[mf]);
#pragma unroll
    for (int nf = 0; nf < 2; nf++) { f1[nf] = ldsread((char*)sB1[cur] + boffs[nf]); f3[nf] = ldsread((char*)sB3[cur] + boffs[nf]); }
#pragma unroll
    for (int mf = 0; mf < 4; mf++)
#pragma unroll
      for (int nf = 0; nf < 2; nf++) {
        ac1[mf][nf] = mm16(fa[mf], f1[nf], ac1[mf][nf]);
        ac3[mf][nf] = mm16(fa[mf], f3[nf], ac3[mf][nf]);
      }
    asm volatile("s_waitcnt vmcnt(0)" ::: "memory");
    __builtin_amdgcn_s_barrier();
  }

#pragma unroll
  for (int mf = 0; mf < 4; mf++)
#pragma unroll
    for (int nf = 0; nf < 2; nf++)
#pragma unroll
      for (int r = 0; r < 4; r++) {
        const int slot = slot0 + wr*64 + mf*16 + ((lane >> 4) * 4) + r;
        if (slot < send) {
          const int col = n0 + wc*32 + nf*16 + (lane & 15);
          const float z1 = ac1[mf][nf][r], z3 = ac3[mf][nf][r];
          const float hv = z1 / (1.0f + __expf(-z1)) * z3;
          hbuf[(size_t)slot * TFF + col] = f2bf(hv);
        }
      }
}

// ---------- MoE GEMM2: hbuf @ w2 -> pair outputs (dbuf + prefetch) ----------
__launch_bounds__(256)
__global__ void moe_gemm2_k(const u16* __restrict__ hbuf, const u16* __restrict__ w2t,
                            const int* __restrict__ bm_e, const int* __restrict__ bm_s0,
                            const int* __restrict__ bm_end, const int* __restrict__ n_active,
                            u16* __restrict__ pout) {
  if ((int)blockIdx.x >= *n_active) return;
  __shared__ u16 sA[2][128 * 32], sB[2][64 * 32];
  const int tid = threadIdx.x, wid = tid >> 6, lane = tid & 63;
  const int e = bm_e[blockIdx.x], slot0 = bm_s0[blockIdx.x], send = bm_end[blockIdx.x];
  const int n0 = blockIdx.y * 64;
  const int wr = wid >> 1, wc = wid & 1;
  const int srow = tid >> 2;
  const int scol = (((tid & 3) ^ ((tid >> 3) & 3)) * 8);
  int sa0 = slot0 + srow; if (sa0 > TPAIRS - 1) sa0 = TPAIRS - 1;
  int sa1 = slot0 + srow + 64; if (sa1 > TPAIRS - 1) sa1 = TPAIRS - 1;
  const size_t a0 = (size_t)sa0 * TFF + scol;
  const size_t a1 = (size_t)sa1 * TFF + scol;
  const size_t bb = (size_t)e * TDIM * TFF + (size_t)(n0 + srow) * TFF + scol;
  const int ldsw = wid * 1024;
  f32x4 acc[4][2];
#pragma unroll
  for (int i = 0; i < 4; i++)
#pragma unroll
    for (int j = 0; j < 2; j++) acc[i][j] = fzero();
  const int g = (lane >> 1) & 3;
  int aoffs[4], boffs[2];
#pragma unroll
  for (int mf = 0; mf < 4; mf++)
    aoffs[mf] = (wr*64 + mf*16 + (lane & 15)) * 64 + ((((lane >> 4)) ^ g) << 4);
#pragma unroll
  for (int nf = 0; nf < 2; nf++)
    boffs[nf] = (wc*32 + nf*16 + (lane & 15)) * 64 + ((((lane >> 4)) ^ g) << 4);

  auto stage = [&](int kk, int bi) {
    const int ke = kk * 32;
    gll16(hbuf + a0 + ke, (char*)sA[bi] + ldsw);
    gll16(hbuf + a1 + ke, (char*)sA[bi] + 4096 + ldsw);
    gll16(w2t + bb + ke, (char*)sB[bi] + ldsw);
  };

  stage(0, 0);
  asm volatile("s_waitcnt vmcnt(0)" ::: "memory");
  __builtin_amdgcn_s_barrier();

  for (int kk = 0; kk < 32; ++kk) {
    const int cur = kk & 1;
    if (kk + 1 < 32) stage(kk + 1, cur ^ 1);
    bf16x8 fa[4], fb[2];
#pragma unroll
    for (int mf = 0; mf < 4; mf++) fa[mf] = ldsread((char*)sA[cur] + aoffs[mf]);
#pragma unroll
    for (int nf = 0; nf < 2; nf++) fb[nf] = ldsread((char*)sB[cur] + boffs[nf]);
#pragma unroll
    for (int mf = 0; mf < 4; mf++)
#pragma unroll
      for (int nf = 0; nf < 2; nf++)
        acc[mf][nf] = mm16(fa[mf], fb[nf], acc[mf][nf]);
    asm volatile("s_waitcnt vmcnt(0)" ::: "memory");
    __builtin_amdgcn_s_barrier();
  }

#pragma unroll
  for (int mf = 0; mf < 4; mf++)
#pragma unroll
    for (int nf = 0; nf < 2; nf++)
#pragma unroll
      for (int r = 0; r < 4; r++) {
        const int slot = slot0 + wr*64 + mf*16 + ((lane >> 4) * 4) + r;
        if (slot < send) {
          const int col = n0 + wc*32 + nf*16 + (lane & 15);
          pout[(size_t)slot * TDIM + col] = f2bf(acc[mf][nf][r]);
        }
      }
}

// ---------- final combine: out = h + g0*pout[s0] + g1*pout[s1] ----------
__launch_bounds__(256)
__global__ void combine_k(const float* __restrict__ hres, const u16* __restrict__ pout,
                          const int* __restrict__ slot_of, const float* __restrict__ gate01,
                          float* __restrict__ out) {
  const int t = blockIdx.x, tid = threadIdx.x;
  const int s0 = slot_of[t*2], s1 = slot_of[t*2+1];
  const float g0 = gate01[t*2], g1 = gate01[t*2+1];
  const float4 hv = ((const float4*)(hres + (size_t)t * TDIM))[tid];
  const uint2 u0 = *(const uint2*)(pout + (size_t)s0 * TDIM + tid * 4);
  const uint2 u1 = *(const uint2*)(pout + (size_t)s1 * TDIM + tid * 4);
  float4 o;
  o.x = hv.x + g0 * bf2f((u16)(u0.x & 0xffff)) + g1 * bf2f((u16)(u1.x & 0xffff));
  o.y = hv.y + g0 * bf2f((u16)(u0.x >> 16))    + g1 * bf2f((u16)(u1.x >> 16));
  o.z = hv.z + g0 * bf2f((u16)(u0.y & 0xffff)) + g1 * bf2f((u16)(u1.y & 0xffff));
  o.w = hv.w + g0 * bf2f((u16)(u0.y >> 16))    + g1 * bf2f((u16)(u1.y >> 16));
  ((float4*)(out + (size_t)t * TDIM))[tid] = o;
}

extern "C" void kernel_launch(void* const* d_in, const int* in_sizes, int n_in,
                              void* d_out, int out_size, void* d_ws, size_t ws_size,
                              hipStream_t stream) {
  (void)in_sizes; (void)n_in; (void)out_size; (void)ws_size;
  const float* x   = (const float*)d_in[0];
  const float* anw = (const float*)d_in[1];
  const float* wq  = (const float*)d_in[2];
  const float* wk  = (const float*)d_in[3];
  const float* wv  = (const float*)d_in[4];
  const float* wo  = (const float*)d_in[5];
  const float* fnw = (const float*)d_in[6];
  const float* rw  = (const float*)d_in[7];
  const float* w1  = (const float*)d_in[8];
  const float* w3  = (const float*)d_in[9];
  const float* w2  = (const float*)d_in[10];
  float* out = (float*)d_out;

  char* ws = (char*)d_ws;
  size_t off = 0;
  auto take = [&](size_t bytes) -> char* {
    char* p = ws + off;
    off += (bytes + 255) & ~(size_t)255;
    return p;
  };
  const size_t SZ_W = (size_t)TDIM * TDIM * sizeof(u16);
  const size_t SZ_T = (size_t)TTOK * TDIM * sizeof(u16);
  u16* wqt_h = (u16*)take(SZ_W); u16* wqt_l = (u16*)take(SZ_W);
  u16* wkt_h = (u16*)take(SZ_W); u16* wkt_l = (u16*)take(SZ_W);
  u16* wvt_h = (u16*)take(SZ_W); u16* wvt_l = (u16*)take(SZ_W);
  u16* wot_h = (u16*)take(SZ_W); u16* wot_l = (u16*)take(SZ_W);
  u16* w1t = (u16*)take((size_t)TEXP * TDIM * TFF * sizeof(u16));
  u16* w3t = (u16*)take((size_t)TEXP * TDIM * TFF * sizeof(u16));
  u16* w2t = (u16*)take((size_t)TEXP * TDIM * TFF * sizeof(u16));
  u16* xnh = (u16*)take(SZ_T); u16* xnl = (u16*)take(SZ_T);
  u16* qh  = (u16*)take(SZ_T); u16* ql  = (u16*)take(SZ_T);
  u16* kh  = (u16*)take(SZ_T); u16* kl  = (u16*)take(SZ_T);
  u16* vth = (u16*)take(SZ_T); u16* vtl = (u16*)take(SZ_T);
  float* hres = (float*)take((size_t)TTOK * TDIM * sizeof(float));
  int*   idx01  = (int*)take(TTOK * 2 * 4);
  float* gate01 = (float*)take(TTOK * 2 * 4);
  int*   slot_of = (int*)take(TTOK * 2 * 4);
  int*   perm    = (int*)take(TPAIRS * 4);
  int*   counts  = (int*)take(256);
  int*   cursor  = (int*)take(256);
  int*   bm_e    = (int*)take(96 * 4);
  int*   bm_s0   = (int*)take(96 * 4);
  int*   bm_end  = (int*)take(96 * 4);
  int*   n_act   = (int*)take(256);
  u16* oh = xnh; u16* ol = xnl;
  u16* hn = qh;
  u16* hbuf = kh;
  u16* pout = vth;

  transpose_all_k<<<28672, dim3(32, 8), 0, stream>>>(wq, wk, wv, wo, w1, w3, w2,
                                                     wqt_h, wqt_l, wkt_h, wkt_l, wvt_h, wvt_l,
                                                     wot_h, wot_l, w1t, w3t, w2t);
  zero8_k<<<1, 64, 0, stream>>>(counts);
  rmsnorm_k<<<TTOK, 256, 0, stream>>>(x, anw, xnh, xnl);
  gemm_qkv_k<<<dim3(TTOK/128, 48), 256, 0, stream>>>(xnh, xnl, wqt_h, wqt_l, wkt_h, wkt_l,
                                                     wvt_h, wvt_l, qh, ql, kh, kl, vth, vtl);
  flash_k<<<dim3(TSEQ/128, TBATCH*THEADS), 256, 0, stream>>>(qh, ql, kh, kl, vth, vtl, oh, ol);
  gemm_x3_k<2><<<dim3(TTOK/128, TDIM/64), 256, 0, stream>>>(oh, ol, wot_h, wot_l, nullptr, nullptr, hres, x, TTOK, TDIM, TDIM);
  router_k<<<TTOK, 256, 0, stream>>>(hres, fnw, rw, hn, idx01, gate01, counts);
  offsets_k<<<1, 1, 0, stream>>>(counts, cursor, bm_e, bm_s0, bm_end, n_act);
  scatter_k<<<TTOK/256, 256, 0, stream>>>(idx01, cursor, slot_of, perm);
  moe_gemm1_k<<<dim3(72, TFF/64), 256, 0, stream>>>(hn, w1t, w3t, perm, bm_e, bm_s0, bm_end, n_act, hbuf);
  moe_gemm2_k<<<dim3(72, TDIM/64), 256, 0, stream>>>(hbuf, w2t, bm_e, bm_s0, bm_end, n_act, pout);
  combine_k<<<TTOK, 256, 0, stream>>>(hres, pout, slot_of, gate01, out);
}

// Round 29
// 571.887 us; speedup vs baseline: 1.3890x; 1.0043x over previous
//
#include <hip/hip_runtime.h>
#include <cstdint>
#include <math.h>

typedef unsigned short u16;
typedef unsigned int u32;
typedef __bf16 bf16x8 __attribute__((ext_vector_type(8)));
typedef float f32x4 __attribute__((ext_vector_type(4)));

#define TBATCH 2
#define TSEQ   2048
#define TDIM   1024
#define THEADS 16
#define THDIM  64
#define TEXP   8
#define TFF    1024
#define TTOK   (TBATCH*TSEQ)
#define TPAIRS (TTOK*2)

__device__ __forceinline__ u16 f2bf(float f) {
  u32 u = __float_as_uint(f);
  u += 0x7FFFu + ((u >> 16) & 1u);
  return (u16)(u >> 16);
}
__device__ __forceinline__ u16 f2bft(float f) {        // truncating split (1 op)
  return (u16)(__float_as_uint(f) >> 16);
}
__device__ __forceinline__ float bf2f(u16 h) { return __uint_as_float(((u32)h) << 16); }
__device__ __forceinline__ float fexp2(float x) {      // raw v_exp_f32 (exp2)
  float r;
  asm("v_exp_f32 %0, %1" : "=v"(r) : "v"(x));
  return r;
}

__device__ __forceinline__ void gll16(const void* g, void* l) {
  __builtin_amdgcn_global_load_lds((const __attribute__((address_space(1))) void*)g,
                                   (__attribute__((address_space(3))) void*)l, 16, 0, 0);
}
__device__ __forceinline__ bf16x8 ldsread(const void* p) { return *(const bf16x8*)p; }
__device__ __forceinline__ f32x4 mm16(bf16x8 a, bf16x8 b, f32x4 c) {
  return __builtin_amdgcn_mfma_f32_16x16x32_bf16(a, b, c, 0, 0, 0);
}
__device__ __forceinline__ f32x4 fzero() { f32x4 z = {0.f, 0.f, 0.f, 0.f}; return z; }

// ---------- ALL weight transposes in ONE launch: f32 [z][1024][1024] -> bf16 [z][1024][1024]^T ----------
__global__ void transpose_all_k(const float* __restrict__ wq, const float* __restrict__ wk,
                                const float* __restrict__ wv, const float* __restrict__ wo,
                                const float* __restrict__ w1, const float* __restrict__ w3,
                                const float* __restrict__ w2,
                                u16* __restrict__ qth, u16* __restrict__ qtl,
                                u16* __restrict__ kth, u16* __restrict__ ktl,
                                u16* __restrict__ vth_, u16* __restrict__ vtl_,
                                u16* __restrict__ oth, u16* __restrict__ otl,
                                u16* __restrict__ w1t, u16* __restrict__ w3t, u16* __restrict__ w2t) {
  __shared__ float t[32][33];
  int id = (int)blockIdx.x;
  const float* in; u16* outh; u16* outl = nullptr;
  size_t bo = 0;
  int tile;
  if (id < 4096) {
    const int wi = id >> 10;
    in   = (wi == 0) ? wq  : (wi == 1) ? wk  : (wi == 2) ? wv   : wo;
    outh = (wi == 0) ? qth : (wi == 1) ? kth : (wi == 2) ? vth_ : oth;
    outl = (wi == 0) ? qtl : (wi == 1) ? ktl : (wi == 2) ? vtl_ : otl;
    tile = id & 1023;
  } else {
    const int id2 = id - 4096;
    const int wi = id2 >> 13;                 // 0=w1 1=w3 2=w2
    const int rem = id2 & 8191;
    bo = (size_t)(rem >> 10) << 20;           // z * 1024*1024
    in   = (wi == 0) ? w1  : (wi == 1) ? w3  : w2;
    outh = (wi == 0) ? w1t : (wi == 1) ? w3t : w2t;
    tile = rem & 1023;
  }
  const int c0 = (tile & 31) * 32, r0 = (tile >> 5) * 32;
  const int tx = threadIdx.x, ty = threadIdx.y;
#pragma unroll
  for (int j = 0; j < 32; j += 8)
    t[ty + j][tx] = in[bo + (size_t)(r0 + ty + j) * 1024 + (c0 + tx)];
  __syncthreads();
#pragma unroll
  for (int j = 0; j < 32; j += 8) {
    float v = t[tx][ty + j];
    u16 hv = f2bf(v);
    size_t o = bo + (size_t)(c0 + ty + j) * 1024 + (r0 + tx);
    outh[o] = hv;
    if (outl != nullptr) outl[o] = f2bf(v - bf2f(hv));
  }
}

// ---------- RMSNorm: f32 [T][D] -> bf16 split (attn input); block 0 also zeroes router counts ----------
__launch_bounds__(256)
__global__ void rmsnorm_k(const float* __restrict__ x, const float* __restrict__ w,
                          u16* __restrict__ oh, u16* __restrict__ ol,
                          int* __restrict__ counts) {
  const int t = blockIdx.x, tid = threadIdx.x;
  if (t == 0 && tid < TEXP) counts[tid] = 0;   // folded zero8_k (stream-ordered before router_k)
  const float4 xv = ((const float4*)(x + (size_t)t * TDIM))[tid];
  float ss = xv.x*xv.x + xv.y*xv.y + xv.z*xv.z + xv.w*xv.w;
#pragma unroll
  for (int d = 1; d < 64; d <<= 1) ss += __shfl_xor(ss, d, 64);
  __shared__ float sp[4];
  if ((tid & 63) == 0) sp[tid >> 6] = ss;
  __syncthreads();
  const float rsc = rsqrtf((sp[0] + sp[1] + sp[2] + sp[3]) * (1.0f / TDIM) + 1e-6f);
  const float4 wv = ((const float4*)w)[tid];
  float v0 = xv.x*rsc*wv.x, v1 = xv.y*rsc*wv.y, v2 = xv.z*rsc*wv.z, v3 = xv.w*rsc*wv.w;
  u16 h0 = f2bf(v0), h1 = f2bf(v1), h2 = f2bf(v2), h3 = f2bf(v3);
  uint2 ph; ph.x = (u32)h0 | ((u32)h1 << 16); ph.y = (u32)h2 | ((u32)h3 << 16);
  *(uint2*)(oh + (size_t)t * TDIM + tid * 4) = ph;
  u16 l0 = f2bf(v0 - bf2f(h0)), l1 = f2bf(v1 - bf2f(h1));
  u16 l2 = f2bf(v2 - bf2f(h2)), l3 = f2bf(v3 - bf2f(h3));
  uint2 pl; pl.x = (u32)l0 | ((u32)l1 << 16); pl.y = (u32)l2 | ((u32)l3 << 16);
  *(uint2*)(ol + (size_t)t * TDIM + tid * 4) = pl;
}

// ---------- fused QKV bf16x3 GEMM: one launch, blockIdx.y selects Q/K/V (grid 32 x 48) ----------
// Q output is pre-scaled by 1/sqrt(HD)*log2(e) so flash_k's softmax works directly in exp2 domain.
__launch_bounds__(256)
__global__ void gemm_qkv_k(const u16* __restrict__ Ah, const u16* __restrict__ Al,
                           const u16* __restrict__ Bqh, const u16* __restrict__ Bql,
                           const u16* __restrict__ Bkh, const u16* __restrict__ Bkl,
                           const u16* __restrict__ Bvh, const u16* __restrict__ Bvl,
                           u16* __restrict__ qh, u16* __restrict__ ql,
                           u16* __restrict__ kh, u16* __restrict__ kl,
                           u16* __restrict__ vth, u16* __restrict__ vtl) {
  __shared__ u16 sAh[2][128 * 32], sAl[2][128 * 32], sBh[2][64 * 32], sBl[2][64 * 32];
  const int tid = threadIdx.x, wid = tid >> 6, lane = tid & 63;
  const int which = blockIdx.y >> 4;                 // 0=Q 1=K 2=V (block-uniform)
  const int m0 = blockIdx.x * 128, n0 = (blockIdx.y & 15) * 64;
  const int wr = wid >> 1, wc = wid & 1;
  const u16* Bth = (which == 0) ? Bqh : (which == 1) ? Bkh : Bvh;
  const u16* Btl = (which == 0) ? Bql : (which == 1) ? Bkl : Bvl;
  u16* outh = (which == 0) ? qh : kh;
  u16* outl = (which == 0) ? ql : kl;

  f32x4 acc[4][2];
#pragma unroll
  for (int i = 0; i < 4; i++)
#pragma unroll
    for (int j = 0; j < 2; j++) acc[i][j] = fzero();

  const int srow = tid >> 2;
  const int scol = (((tid & 3) ^ ((tid >> 3) & 3)) * 8);
  const size_t a0 = (size_t)(m0 + srow) * TDIM + scol;
  const size_t a1 = (size_t)(m0 + srow + 64) * TDIM + scol;
  const size_t b0 = (size_t)(n0 + srow) * TDIM + scol;
  const int ldsw = wid * 1024;

  const int g = (lane >> 1) & 3;
  int aoffs[4], boffs[2];
#pragma unroll
  for (int mf = 0; mf < 4; mf++)
    aoffs[mf] = (wr*64 + mf*16 + (lane & 15)) * 64 + ((((lane >> 4)) ^ g) << 4);
#pragma unroll
  for (int nf = 0; nf < 2; nf++)
    boffs[nf] = (wc*32 + nf*16 + (lane & 15)) * 64 + ((((lane >> 4)) ^ g) << 4);

  auto stage = [&](int kk, int bi) {
    const int ke = kk * 32;
    gll16(Ah + a0 + ke, (char*)sAh[bi] + ldsw);
    gll16(Ah + a1 + ke, (char*)sAh[bi] + 4096 + ldsw);
    gll16(Al + a0 + ke, (char*)sAl[bi] + ldsw);
    gll16(Al + a1 + ke, (char*)sAl[bi] + 4096 + ldsw);
    gll16(Bth + b0 + ke, (char*)sBh[bi] + ldsw);
    gll16(Btl + b0 + ke, (char*)sBl[bi] + ldsw);
  };

  stage(0, 0);
  asm volatile("s_waitcnt vmcnt(0)" ::: "memory");
  __builtin_amdgcn_s_barrier();

  for (int kk = 0; kk < 32; ++kk) {
    const int cur = kk & 1;
    if (kk + 1 < 32) stage(kk + 1, cur ^ 1);
    bf16x8 fah[4], fal[4], fbh[2], fbl[2];
#pragma unroll
    for (int mf = 0; mf < 4; mf++) { fah[mf] = ldsread((char*)sAh[cur] + aoffs[mf]); fal[mf] = ldsread((char*)sAl[cur] + aoffs[mf]); }
#pragma unroll
    for (int nf = 0; nf < 2; nf++) { fbh[nf] = ldsread((char*)sBh[cur] + boffs[nf]); fbl[nf] = ldsread((char*)sBl[cur] + boffs[nf]); }
#pragma unroll
    for (int mf = 0; mf < 4; mf++)
#pragma unroll
      for (int nf = 0; nf < 2; nf++) {
        acc[mf][nf] = mm16(fah[mf], fbh[nf], acc[mf][nf]);
        acc[mf][nf] = mm16(fah[mf], fbl[nf], acc[mf][nf]);
        acc[mf][nf] = mm16(fal[mf], fbh[nf], acc[mf][nf]);
      }
    asm volatile("s_waitcnt vmcnt(0)" ::: "memory");
    __builtin_amdgcn_s_barrier();
  }

  const float qscale = (which == 0) ? 0.18033688011112042f : 1.0f;  // 0.125 * log2(e)
#pragma unroll
  for (int mf = 0; mf < 4; mf++)
#pragma unroll
    for (int nf = 0; nf < 2; nf++)
#pragma unroll
      for (int r = 0; r < 4; r++) {
        const int grow = m0 + wr*64 + mf*16 + ((lane >> 4) * 4) + r;
        const int gcol = n0 + wc*32 + nf*16 + (lane & 15);
        const float v = acc[mf][nf][r] * qscale;
        u16 hv = f2bf(v);
        u16 lv = f2bf(v - bf2f(hv));
        if (which < 2) {
          const size_t o = (size_t)grow * TDIM + gcol;
          outh[o] = hv; outl[o] = lv;
        } else {
          const int b = grow >> 11, s = grow & (TSEQ - 1);
          const int hh = gcol >> 6, hd = gcol & 63;
          const size_t o = ((size_t)((b * THEADS + hh) * THDIM + hd)) * TSEQ + s;
          vth[o] = hv; vtl[o] = lv;
        }
      }
}

// ---------- bf16x3 GEMM (WO): 2-buffer + prefetch; EPI2 = f32 out + resid ----------
template<int EPI>
__launch_bounds__(256)
__global__ void gemm_x3_k(const u16* __restrict__ Ah, const u16* __restrict__ Al,
                          const u16* __restrict__ Bth, const u16* __restrict__ Btl,
                          u16* __restrict__ outh, u16* __restrict__ outl,
                          float* __restrict__ outf, const float* __restrict__ resid,
                          int M, int N, int K) {
  __shared__ u16 sAh[2][128 * 32], sAl[2][128 * 32], sBh[2][64 * 32], sBl[2][64 * 32];
  const int tid = threadIdx.x, wid = tid >> 6, lane = tid & 63;
  const int m0 = blockIdx.x * 128, n0 = blockIdx.y * 64;
  const int wr = wid >> 1, wc = wid & 1;

  f32x4 acc[4][2];
#pragma unroll
  for (int i = 0; i < 4; i++)
#pragma unroll
    for (int j = 0; j < 2; j++) acc[i][j] = fzero();

  const int srow = tid >> 2;
  const int scol = (((tid & 3) ^ ((tid >> 3) & 3)) * 8);
  const size_t a0 = (size_t)(m0 + srow) * K + scol;
  const size_t a1 = (size_t)(m0 + srow + 64) * K + scol;
  const size_t b0 = (size_t)(n0 + srow) * K + scol;
  const int ldsw = wid * 1024;

  const int g = (lane >> 1) & 3;
  int aoffs[4], boffs[2];
#pragma unroll
  for (int mf = 0; mf < 4; mf++)
    aoffs[mf] = (wr*64 + mf*16 + (lane & 15)) * 64 + ((((lane >> 4)) ^ g) << 4);
#pragma unroll
  for (int nf = 0; nf < 2; nf++)
    boffs[nf] = (wc*32 + nf*16 + (lane & 15)) * 64 + ((((lane >> 4)) ^ g) << 4);

  auto stage = [&](int kk, int bi) {
    const int ke = kk * 32;
    gll16(Ah + a0 + ke, (char*)sAh[bi] + ldsw);
    gll16(Ah + a1 + ke, (char*)sAh[bi] + 4096 + ldsw);
    gll16(Al + a0 + ke, (char*)sAl[bi] + ldsw);
    gll16(Al + a1 + ke, (char*)sAl[bi] + 4096 + ldsw);
    gll16(Bth + b0 + ke, (char*)sBh[bi] + ldsw);
    gll16(Btl + b0 + ke, (char*)sBl[bi] + ldsw);
  };

  const int nk = K >> 5;
  stage(0, 0);
  asm volatile("s_waitcnt vmcnt(0)" ::: "memory");
  __builtin_amdgcn_s_barrier();

  for (int kk = 0; kk < nk; ++kk) {
    const int cur = kk & 1;
    if (kk + 1 < nk) stage(kk + 1, cur ^ 1);
    bf16x8 fah[4], fal[4], fbh[2], fbl[2];
#pragma unroll
    for (int mf = 0; mf < 4; mf++) { fah[mf] = ldsread((char*)sAh[cur] + aoffs[mf]); fal[mf] = ldsread((char*)sAl[cur] + aoffs[mf]); }
#pragma unroll
    for (int nf = 0; nf < 2; nf++) { fbh[nf] = ldsread((char*)sBh[cur] + boffs[nf]); fbl[nf] = ldsread((char*)sBl[cur] + boffs[nf]); }
#pragma unroll
    for (int mf = 0; mf < 4; mf++)
#pragma unroll
      for (int nf = 0; nf < 2; nf++) {
        acc[mf][nf] = mm16(fah[mf], fbh[nf], acc[mf][nf]);
        acc[mf][nf] = mm16(fah[mf], fbl[nf], acc[mf][nf]);
        acc[mf][nf] = mm16(fal[mf], fbh[nf], acc[mf][nf]);
      }
    asm volatile("s_waitcnt vmcnt(0)" ::: "memory");
    __builtin_amdgcn_s_barrier();
  }

#pragma unroll
  for (int mf = 0; mf < 4; mf++)
#pragma unroll
    for (int nf = 0; nf < 2; nf++)
#pragma unroll
      for (int r = 0; r < 4; r++) {
        const int grow = m0 + wr*64 + mf*16 + ((lane >> 4) * 4) + r;
        const int gcol = n0 + wc*32 + nf*16 + (lane & 15);
        const float v = acc[mf][nf][r];
        if (EPI == 0) {
          const size_t o = (size_t)grow * N + gcol;
          u16 hv = f2bf(v);
          outh[o] = hv; outl[o] = f2bf(v - bf2f(hv));
        } else if (EPI == 1) {
          const int b = grow >> 11, s = grow & (TSEQ - 1);
          const int hh = gcol >> 6, hd = gcol & 63;
          const size_t o = ((size_t)((b * THEADS + hh) * THDIM + hd)) * TSEQ + s;
          u16 hv = f2bf(v);
          outh[o] = hv; outl[o] = f2bf(v - bf2f(hv));
        } else {
          const size_t o = (size_t)grow * N + gcol;
          outf[o] = v + resid[o];
        }
      }
}

// ---------- causal flash attention, bf16x3, QBLK=128: shared K reads, hoisted P reads, defer-max, setprio,
// ---------- fully-visible-tile fast path (skips causal compare/select on below-diagonal tiles) ----------
__launch_bounds__(256)
__global__ void flash_k(const u16* __restrict__ Qh, const u16* __restrict__ Ql,
                        const u16* __restrict__ Kh, const u16* __restrict__ Kl,
                        const u16* __restrict__ Vth, const u16* __restrict__ Vtl,
                        u16* __restrict__ Oh, u16* __restrict__ Ol) {
  __shared__ u16 sK[2][2][4096];   // [buf][hi/lo][64x64] rows 128B
  __shared__ u16 sV[2][2][4096];
  __shared__ u16 sP[2][4][1024];   // [hi/lo][warp][16x64], reused by both halves
  const int tid = threadIdx.x, wid = tid >> 6, lane = tid & 63;
  const int qb = (int)(gridDim.x - 1 - blockIdx.x);   // longest-first
  const int bh = blockIdx.y;
  const int b = bh >> 4, h = bh & 15;
  const int srow = tid >> 3;
  const int sxcol = (((lane & 7) ^ ((lane >> 3) & 7)) << 3);
  const int ldsw = wid * 1024;

  // Q fragments for both 64-row halves, straight from global (16B/lane contiguous).
  // Q is pre-scaled by 0.125*log2(e) in gemm_qkv_k -> scores arrive in exp2 domain.
  bf16x8 fqh[2][2], fql[2][2];
#pragma unroll
  for (int hh = 0; hh < 2; hh++) {
    const size_t qbase = ((size_t)(b * TSEQ + qb * 128 + hh * 64 + wid * 16 + (lane & 15))) * TDIM + h * 64;
#pragma unroll
    for (int kq = 0; kq < 2; kq++) {
      fqh[hh][kq] = *(const bf16x8*)(Qh + qbase + (kq * 4 + (lane >> 4)) * 8);
      fql[hh][kq] = *(const bf16x8*)(Ql + qbase + (kq * 4 + (lane >> 4)) * 8);
    }
  }

  f32x4 oacc[2][4];
  float m_run[2][4], l_lane[2][4];
#pragma unroll
  for (int hh = 0; hh < 2; hh++)
#pragma unroll
    for (int i = 0; i < 4; i++) { oacc[hh][i] = fzero(); m_run[hh][i] = -INFINITY; l_lane[hh][i] = 0.f; }

  const size_t kg0 = ((size_t)(b * TSEQ + srow)) * TDIM + h * 64 + sxcol;
  const size_t kg1 = kg0 + (size_t)32 * TDIM;
  const size_t vg0 = ((size_t)((b * THEADS + h) * THDIM + srow)) * TSEQ + sxcol;
  const size_t vg1 = vg0 + (size_t)32 * TSEQ;

  auto stage = [&](int kb, int bi) {
    const size_t ko = (size_t)kb * 64 * TDIM;
    const size_t vo = (size_t)kb * 64;
    gll16(Kh + kg0 + ko, (char*)sK[bi][0] + ldsw);
    gll16(Kh + kg1 + ko, (char*)sK[bi][0] + 4096 + ldsw);
    gll16(Kl + kg0 + ko, (char*)sK[bi][1] + ldsw);
    gll16(Kl + kg1 + ko, (char*)sK[bi][1] + 4096 + ldsw);
    gll16(Vth + vg0 + vo, (char*)sV[bi][0] + ldsw);
    gll16(Vth + vg1 + vo, (char*)sV[bi][0] + 4096 + ldsw);
    gll16(Vtl + vg0 + vo, (char*)sV[bi][1] + ldsw);
    gll16(Vtl + vg1 + vo, (char*)sV[bi][1] + 4096 + ldsw);
  };

  const int nkb = 2 * qb + 2;
  stage(0, 0);
  asm volatile("s_waitcnt vmcnt(0)" ::: "memory");
  __builtin_amdgcn_s_barrier();

  for (int kb = 0; kb < nkb; ++kb) {
    const int cur = kb & 1;
    if (kb + 1 < nkb) stage(kb + 1, cur ^ 1);

    // QK^T for BOTH halves, sharing each K-fragment read (16 -> 8 reads/iter)
    f32x4 sc[2][4];
    __builtin_amdgcn_s_setprio(1);
#pragma unroll
    for (int nf = 0; nf < 4; nf++) {
      f32x4 s0 = fzero(), s1 = fzero();
      const int krow = nf * 16 + (lane & 15);
#pragma unroll
      for (int kq = 0; kq < 2; kq++) {
        const int off = krow * 128 + (((kq * 4 + (lane >> 4)) ^ (lane & 7)) << 4);
        bf16x8 kfh = ldsread((char*)sK[cur][0] + off);
        bf16x8 kfl = ldsread((char*)sK[cur][1] + off);
        s0 = mm16(fqh[0][kq], kfh, s0);
        s0 = mm16(fqh[0][kq], kfl, s0);
        s0 = mm16(fql[0][kq], kfh, s0);
        s1 = mm16(fqh[1][kq], kfh, s1);
        s1 = mm16(fqh[1][kq], kfl, s1);
        s1 = mm16(fql[1][kq], kfh, s1);
      }
      sc[0][nf] = s0; sc[1][nf] = s1;
    }
    __builtin_amdgcn_s_setprio(0);

#pragma unroll
    for (int hh = 0; hh < 2; hh++) {
      // half hh covers q rows [qb*128+hh*64, +64); skip softmax/PV if fully masked
      if (kb * 64 > qb * 128 + hh * 64 + 63) continue;

      const int qg = qb * 128 + hh * 64 + wid * 16 + ((lane >> 4) * 4);
      float pm[4] = {-INFINITY, -INFINITY, -INFINITY, -INFINITY};
      // fully-visible fast path: tile max kv index <= half's min q row -> no causal compare needed
      if (kb * 64 + 63 <= qb * 128 + hh * 64) {
#pragma unroll
        for (int nf = 0; nf < 4; nf++)
#pragma unroll
          for (int r = 0; r < 4; r++) pm[r] = fmaxf(pm[r], sc[hh][nf][r]);
      } else {
#pragma unroll
        for (int nf = 0; nf < 4; nf++) {
          const int kg = kb * 64 + nf * 16 + (lane & 15);
#pragma unroll
          for (int r = 0; r < 4; r++) {
            float v = sc[hh][nf][r];             // already exp2-domain (Q pre-scaled)
            if (kg > qg + r) v = -INFINITY;
            sc[hh][nf][r] = v;
            pm[r] = fmaxf(pm[r], v);
          }
        }
      }
#pragma unroll
      for (int r = 0; r < 4; r++)
#pragma unroll
        for (int d = 1; d < 16; d <<= 1) pm[r] = fmaxf(pm[r], __shfl_xor(pm[r], d, 64));

      // defer-max (T13): skip O/l rescale when tile max within 8 (exp2-domain) of running max.
      // P then bounded by 2^8; f32 accumulators have ample headroom. First tile: m_run=-inf -> taken.
      const float dm = fmaxf(fmaxf(pm[0] - m_run[hh][0], pm[1] - m_run[hh][1]),
                             fmaxf(pm[2] - m_run[hh][2], pm[3] - m_run[hh][3]));
      if (!__all(dm <= 8.0f)) {
#pragma unroll
        for (int r = 0; r < 4; r++) {
          const float mn = fmaxf(m_run[hh][r], pm[r]);
          const float esc = fexp2(m_run[hh][r] - mn);
          m_run[hh][r] = mn;
          l_lane[hh][r] *= esc;
#pragma unroll
          for (int nf = 0; nf < 4; nf++) oacc[hh][nf][r] *= esc;
        }
      }
      float ls[4] = {0.f, 0.f, 0.f, 0.f};
#pragma unroll
      for (int nf = 0; nf < 4; nf++)
#pragma unroll
        for (int r = 0; r < 4; r++) {
          float p = fexp2(sc[hh][nf][r] - m_run[hh][r]);
          sc[hh][nf][r] = p;
          ls[r] += p;
        }
#pragma unroll
      for (int r = 0; r < 4; r++) l_lane[hh][r] += ls[r];

      // P store (truncating hi/lo split; per-warp private, swizzled, no barrier)
#pragma unroll
      for (int nf = 0; nf < 4; nf++)
#pragma unroll
        for (int r = 0; r < 4; r++) {
          float p = sc[hh][nf][r];
          u16 ph = f2bft(p);
          const int prow = (lane >> 4) * 4 + r;
          const int pbyte = (prow * 128 + (nf * 16 + (lane & 15)) * 2) ^ ((prow & 7) << 4);
          *(u16*)((char*)sP[0][wid] + pbyte) = ph;
          *(u16*)((char*)sP[1][wid] + pbyte) = f2bft(p - bf2f(ph));
        }

      // PV: kq-outer so P fragments are read ONCE per kq (16 -> 4 reads/iter total)
      __builtin_amdgcn_s_setprio(1);
#pragma unroll
      for (int kq = 0; kq < 2; kq++) {
        const int prow = lane & 15;
        const int poff = prow * 128 + (((kq * 4 + (lane >> 4)) ^ (prow & 7)) << 4);
        bf16x8 pah = ldsread((char*)sP[0][wid] + poff);
        bf16x8 pal = ldsread((char*)sP[1][wid] + poff);
#pragma unroll
        for (int nf = 0; nf < 4; nf++) {
          const int vrow = nf * 16 + (lane & 15);
          const int voff = vrow * 128 + (((kq * 4 + (lane >> 4)) ^ (lane & 7)) << 4);
          bf16x8 vfh = ldsread((char*)sV[cur][0] + voff);
          bf16x8 vfl = ldsread((char*)sV[cur][1] + voff);
          oacc[hh][nf] = mm16(pah, vfh, oacc[hh][nf]);
          oacc[hh][nf] = mm16(pah, vfl, oacc[hh][nf]);
          oacc[hh][nf] = mm16(pal, vfh, oacc[hh][nf]);
        }
      }
      __builtin_amdgcn_s_setprio(0);
    }
    asm volatile("s_waitcnt vmcnt(0)" ::: "memory");
    __builtin_amdgcn_s_barrier();
  }

#pragma unroll
  for (int hh = 0; hh < 2; hh++)
#pragma unroll
    for (int r = 0; r < 4; r++) {
      float lt = l_lane[hh][r];
#pragma unroll
      for (int d = 1; d < 16; d <<= 1) lt += __shfl_xor(lt, d, 64);
      const float inv = 1.0f / lt;
      const int t = b * TSEQ + qb * 128 + hh * 64 + wid * 16 + ((lane >> 4) * 4) + r;
#pragma unroll
      for (int nf = 0; nf < 4; nf++) {
        const float v = oacc[hh][nf][r] * inv;
        const size_t o = (size_t)t * TDIM + h * 64 + nf * 16 + (lane & 15);
        u16 hv = f2bft(v);
        Oh[o] = hv; Ol[o] = f2bft(v - bf2f(hv));
      }
    }
}

// ---------- router (+ writes ffn-norm bf16): f32 logits from h, top-2, histogram ----------
__launch_bounds__(256)
__global__ void router_k(const float* __restrict__ hres, const float* __restrict__ wn,
                         const float* __restrict__ rw, u16* __restrict__ hn,
                         int* __restrict__ idx01, float* __restrict__ gate01,
                         int* __restrict__ counts) {
  const int t = blockIdx.x, tid = threadIdx.x;
  const float4 xv = ((const float4*)(hres + (size_t)t * TDIM))[tid];
  float ss = xv.x*xv.x + xv.y*xv.y + xv.z*xv.z + xv.w*xv.w;
#pragma unroll
  for (int d = 1; d < 64; d <<= 1) ss += __shfl_xor(ss, d, 64);
  __shared__ float sp[4];
  __shared__ float sacc[4][8];
  if ((tid & 63) == 0) sp[tid >> 6] = ss;
  __syncthreads();
  const float rsc = rsqrtf((sp[0]+sp[1]+sp[2]+sp[3]) * (1.0f / TDIM) + 1e-6f);
  const float4 wv = ((const float4*)wn)[tid];
  const float x0 = xv.x*rsc*wv.x, x1 = xv.y*rsc*wv.y, x2 = xv.z*rsc*wv.z, x3 = xv.w*rsc*wv.w;
  {
    u16 h0 = f2bf(x0), h1 = f2bf(x1), h2 = f2bf(x2), h3 = f2bf(x3);
    uint2 ph; ph.x = (u32)h0 | ((u32)h1 << 16); ph.y = (u32)h2 | ((u32)h3 << 16);
    *(uint2*)(hn + (size_t)t * TDIM + tid * 4) = ph;
  }
  const float* rp = rw + (size_t)(tid * 4) * TEXP;
  float acc[8];
#pragma unroll
  for (int e = 0; e < 8; e++) acc[e] = x0*rp[e] + x1*rp[8+e] + x2*rp[16+e] + x3*rp[24+e];
#pragma unroll
  for (int e = 0; e < 8; e++)
#pragma unroll
    for (int d = 1; d < 64; d <<= 1) acc[e] += __shfl_xor(acc[e], d, 64);
  if ((tid & 63) == 0)
#pragma unroll
    for (int e = 0; e < 8; e++) sacc[tid >> 6][e] = acc[e];
  __syncthreads();
  if (tid == 0) {
    float lg[8];
#pragma unroll
    for (int e = 0; e < 8; e++) lg[e] = sacc[0][e] + sacc[1][e] + sacc[2][e] + sacc[3][e];
    int i1 = 0;
#pragma unroll
    for (int e = 1; e < 8; e++) if (lg[e] > lg[i1]) i1 = e;
    int i2 = (i1 == 0) ? 1 : 0;
#pragma unroll
    for (int e = 0; e < 8; e++) if (e != i1 && lg[e] > lg[i2]) i2 = e;
    const float g1 = 1.0f / (1.0f + __expf(lg[i2] - lg[i1]));
    idx01[t*2] = i1; idx01[t*2+1] = i2;
    gate01[t*2] = g1; gate01[t*2+1] = 1.0f - g1;
    atomicAdd(&counts[i1], 1);
    atomicAdd(&counts[i2], 1);
  }
}

__global__ void offsets_k(const int* __restrict__ counts, int* __restrict__ cursor,
                          int* __restrict__ bm_e, int* __restrict__ bm_s0,
                          int* __restrict__ bm_end, int* __restrict__ n_active) {
  if (threadIdx.x != 0 || blockIdx.x != 0) return;
  int off = 0, nb = 0;
  for (int e = 0; e < TEXP; e++) {
    const int c = counts[e];
    cursor[e] = off;
    const int end = off + c;
    for (int mb = 0; mb * 128 < c; mb++) { bm_e[nb] = e; bm_s0[nb] = off + mb * 128; bm_end[nb] = end; nb++; }
    off = end;
  }
  *n_active = nb;
}

__global__ void scatter_k(const int* __restrict__ idx01, int* __restrict__ cursor,
                          int* __restrict__ slot_of, int* __restrict__ perm) {
  const int t = blockIdx.x * 256 + threadIdx.x;
  if (t >= TTOK) return;
#pragma unroll
  for (int k = 0; k < 2; k++) {
    const int e = idx01[t*2+k];
    const int slot = atomicAdd(&cursor[e], 1);
    slot_of[t*2+k] = slot;
    perm[slot] = t;
  }
}

// ---------- MoE GEMM1: gathered rows, fused w1/w3, silu(z1)*z3 -> hbuf (dbuf + prefetch) ----------
__launch_bounds__(256)
__global__ void moe_gemm1_k(const u16* __restrict__ hn, const u16* __restrict__ w1t,
                            const u16* __restrict__ w3t, const int* __restrict__ perm,
                            const int* __restrict__ bm_e, const int* __restrict__ bm_s0,
                            const int* __restrict__ bm_end, const int* __restrict__ n_active,
                            u16* __restrict__ hbuf) {
  if ((int)blockIdx.x >= *n_active) return;
  __shared__ u16 sA[2][128 * 32], sB1[2][64 * 32], sB3[2][64 * 32];
  const int tid = threadIdx.x, wid = tid >> 6, lane = tid & 63;
  const int e = bm_e[blockIdx.x], slot0 = bm_s0[blockIdx.x], send = bm_end[blockIdx.x];
  const int n0 = blockIdx.y * 64;
  const int wr = wid >> 1, wc = wid & 1;
  const int srow = tid >> 2;
  const int scol = (((tid & 3) ^ ((tid >> 3) & 3)) * 8);
  const int sa0 = slot0 + srow, sa1 = slot0 + srow + 64;
  const int ta = (sa0 < send) ? perm[sa0] : 0;
  const int tb2 = (sa1 < send) ? perm[sa1] : 0;
  const size_t a0 = (size_t)ta * TDIM + scol;
  const size_t a1 = (size_t)tb2 * TDIM + scol;
  const size_t bb = (size_t)e * TDIM * TFF + (size_t)(n0 + srow) * TDIM + scol;
  const int ldsw = wid * 1024;
  f32x4 ac1[4][2], ac3[4][2];
#pragma unroll
  for (int i = 0; i < 4; i++)
#pragma unroll
    for (int j = 0; j < 2; j++) { ac1[i][j] = fzero(); ac3[i][j] = fzero(); }
  const int g = (lane >> 1) & 3;
  int aoffs[4], boffs[2];
#pragma unroll
  for (int mf = 0; mf < 4; mf++)
    aoffs[mf] = (wr*64 + mf*16 + (lane & 15)) * 64 + ((((lane >> 4)) ^ g) << 4);
#pragma unroll
  for (int nf = 0; nf < 2; nf++)
    boffs[nf] = (wc*32 + nf*16 + (lane & 15)) * 64 + ((((lane >> 4)) ^ g) << 4);

  auto stage = [&](int kk, int bi) {
    const int ke = kk * 32;
    gll16(hn + a0 + ke, (char*)sA[bi] + ldsw);
    gll16(hn + a1 + ke, (char*)sA[bi] + 4096 + ldsw);
    gll16(w1t + bb + ke, (char*)sB1[bi] + ldsw);
    gll16(w3t + bb + ke, (char*)sB3[bi] + ldsw);
  };

  stage(0, 0);
  asm volatile("s_waitcnt vmcnt(0)" ::: "memory");
  __builtin_amdgcn_s_barrier();

  for (int kk = 0; kk < 32; ++kk) {
    const int cur = kk & 1;
    if (kk + 1 < 32) stage(kk + 1, cur ^ 1);
    bf16x8 fa[4], f1[2], f3[2];
#pragma unroll
    for (int mf = 0; mf < 4; mf++) fa[mf] = ldsread((char*)sA[cur] + aoffs[mf]);
#pragma unroll
    for (int nf = 0; nf < 2; nf++) { f1[nf] = ldsread((char*)sB1[cur] + boffs[nf]); f3[nf] = ldsread((char*)sB3[cur] + boffs[nf]); }
#pragma unroll
    for (int mf = 0; mf < 4; mf++)
#pragma unroll
      for (int nf = 0; nf < 2; nf++) {
        ac1[mf][nf] = mm16(fa[mf], f1[nf], ac1[mf][nf]);
        ac3[mf][nf] = mm16(fa[mf], f3[nf], ac3[mf][nf]);
      }
    asm volatile("s_waitcnt vmcnt(0)" ::: "memory");
    __builtin_amdgcn_s_barrier();
  }

#pragma unroll
  for (int mf = 0; mf < 4; mf++)
#pragma unroll
    for (int nf = 0; nf < 2; nf++)
#pragma unroll
      for (int r = 0; r < 4; r++) {
        const int slot = slot0 + wr*64 + mf*16 + ((lane >> 4) * 4) + r;
        if (slot < send) {
          const int col = n0 + wc*32 + nf*16 + (lane & 15);
          const float z1 = ac1[mf][nf][r], z3 = ac3[mf][nf][r];
          const float hv = z1 / (1.0f + __expf(-z1)) * z3;
          hbuf[(size_t)slot * TFF + col] = f2bf(hv);
        }
      }
}

// ---------- MoE GEMM2: hbuf @ w2 -> pair outputs (dbuf + prefetch) ----------
__launch_bounds__(256)
__global__ void moe_gemm2_k(const u16* __restrict__ hbuf, const u16* __restrict__ w2t,
                            const int* __restrict__ bm_e, const int* __restrict__ bm_s0,
                            const int* __restrict__ bm_end, const int* __restrict__ n_active,
                            u16* __restrict__ pout) {
  if ((int)blockIdx.x >= *n_active) return;
  __shared__ u16 sA[2][128 * 32], sB[2][64 * 32];
  const int tid = threadIdx.x, wid = tid >> 6, lane = tid & 63;
  const int e = bm_e[blockIdx.x], slot0 = bm_s0[blockIdx.x], send = bm_end[blockIdx.x];
  const int n0 = blockIdx.y * 64;
  const int wr = wid >> 1, wc = wid & 1;
  const int srow = tid >> 2;
  const int scol = (((tid & 3) ^ ((tid >> 3) & 3)) * 8);
  int sa0 = slot0 + srow; if (sa0 > TPAIRS - 1) sa0 = TPAIRS - 1;
  int sa1 = slot0 + srow + 64; if (sa1 > TPAIRS - 1) sa1 = TPAIRS - 1;
  const size_t a0 = (size_t)sa0 * TFF + scol;
  const size_t a1 = (size_t)sa1 * TFF + scol;
  const size_t bb = (size_t)e * TDIM * TFF + (size_t)(n0 + srow) * TFF + scol;
  const int ldsw = wid * 1024;
  f32x4 acc[4][2];
#pragma unroll
  for (int i = 0; i < 4; i++)
#pragma unroll
    for (int j = 0; j < 2; j++) acc[i][j] = fzero();
  const int g = (lane >> 1) & 3;
  int aoffs[4], boffs[2];
#pragma unroll
  for (int mf = 0; mf < 4; mf++)
    aoffs[mf] = (wr*64 + mf*16 + (lane & 15)) * 64 + ((((lane >> 4)) ^ g) << 4);
#pragma unroll
  for (int nf = 0; nf < 2; nf++)
    boffs[nf] = (wc*32 + nf*16 + (lane & 15)) * 64 + ((((lane >> 4)) ^ g) << 4);

  auto stage = [&](int kk, int bi) {
    const int ke = kk * 32;
    gll16(hbuf + a0 + ke, (char*)sA[bi] + ldsw);
    gll16(hbuf + a1 + ke, (char*)sA[bi] + 4096 + ldsw);
    gll16(w2t + bb + ke, (char*)sB[bi] + ldsw);
  };

  stage(0, 0);
  asm volatile("s_waitcnt vmcnt(0)" ::: "memory");
  __builtin_amdgcn_s_barrier();

  for (int kk = 0; kk < 32; ++kk) {
    const int cur = kk & 1;
    if (kk + 1 < 32) stage(kk + 1, cur ^ 1);
    bf16x8 fa[4], fb[2];
#pragma unroll
    for (int mf = 0; mf < 4; mf++) fa[mf] = ldsread((char*)sA[cur] + aoffs[mf]);
#pragma unroll
    for (int nf = 0; nf < 2; nf++) fb[nf] = ldsread((char*)sB[cur] + boffs[nf]);
#pragma unroll
    for (int mf = 0; mf < 4; mf++)
#pragma unroll
      for (int nf = 0; nf < 2; nf++)
        acc[mf][nf] = mm16(fa[mf], fb[nf], acc[mf][nf]);
    asm volatile("s_waitcnt vmcnt(0)" ::: "memory");
    __builtin_amdgcn_s_barrier();
  }

#pragma unroll
  for (int mf = 0; mf < 4; mf++)
#pragma unroll
    for (int nf = 0; nf < 2; nf++)
#pragma unroll
      for (int r = 0; r < 4; r++) {
        const int slot = slot0 + wr*64 + mf*16 + ((lane >> 4) * 4) + r;
        if (slot < send) {
          const int col = n0 + wc*32 + nf*16 + (lane & 15);
          pout[(size_t)slot * TDIM + col] = f2bf(acc[mf][nf][r]);
        }
      }
}

// ---------- final combine: out = h + g0*pout[s0] + g1*pout[s1] ----------
__launch_bounds__(256)
__global__ void combine_k(const float* __restrict__ hres, const u16* __restrict__ pout,
                          const int* __restrict__ slot_of, const float* __restrict__ gate01,
                          float* __restrict__ out) {
  const int t = blockIdx.x, tid = threadIdx.x;
  const int s0 = slot_of[t*2], s1 = slot_of[t*2+1];
  const float g0 = gate01[t*2], g1 = gate01[t*2+1];
  const float4 hv = ((const float4*)(hres + (size_t)t * TDIM))[tid];
  const uint2 u0 = *(const uint2*)(pout + (size_t)s0 * TDIM + tid * 4);
  const uint2 u1 = *(const uint2*)(pout + (size_t)s1 * TDIM + tid * 4);
  float4 o;
  o.x = hv.x + g0 * bf2f((u16)(u0.x & 0xffff)) + g1 * bf2f((u16)(u1.x & 0xffff));
  o.y = hv.y + g0 * bf2f((u16)(u0.x >> 16))    + g1 * bf2f((u16)(u1.x >> 16));
  o.z = hv.z + g0 * bf2f((u16)(u0.y & 0xffff)) + g1 * bf2f((u16)(u1.y & 0xffff));
  o.w = hv.w + g0 * bf2f((u16)(u0.y >> 16))    + g1 * bf2f((u16)(u1.y >> 16));
  ((float4*)(out + (size_t)t * TDIM))[tid] = o;
}

extern "C" void kernel_launch(void* const* d_in, const int* in_sizes, int n_in,
                              void* d_out, int out_size, void* d_ws, size_t ws_size,
                              hipStream_t stream) {
  (void)in_sizes; (void)n_in; (void)out_size; (void)ws_size;
  const float* x   = (const float*)d_in[0];
  const float* anw = (const float*)d_in[1];
  const float* wq  = (const float*)d_in[2];
  const float* wk  = (const float*)d_in[3];
  const float* wv  = (const float*)d_in[4];
  const float* wo  = (const float*)d_in[5];
  const float* fnw = (const float*)d_in[6];
  const float* rw  = (const float*)d_in[7];
  const float* w1  = (const float*)d_in[8];
  const float* w3  = (const float*)d_in[9];
  const float* w2  = (const float*)d_in[10];
  float* out = (float*)d_out;

  char* ws = (char*)d_ws;
  size_t off = 0;
  auto take = [&](size_t bytes) -> char* {
    char* p = ws + off;
    off += (bytes + 255) & ~(size_t)255;
    return p;
  };
  const size_t SZ_W = (size_t)TDIM * TDIM * sizeof(u16);
  const size_t SZ_T = (size_t)TTOK * TDIM * sizeof(u16);
  u16* wqt_h = (u16*)take(SZ_W); u16* wqt_l = (u16*)take(SZ_W);
  u16* wkt_h = (u16*)take(SZ_W); u16* wkt_l = (u16*)take(SZ_W);
  u16* wvt_h = (u16*)take(SZ_W); u16* wvt_l = (u16*)take(SZ_W);
  u16* wot_h = (u16*)take(SZ_W); u16* wot_l = (u16*)take(SZ_W);
  u16* w1t = (u16*)take((size_t)TEXP * TDIM * TFF * sizeof(u16));
  u16* w3t = (u16*)take((size_t)TEXP * TDIM * TFF * sizeof(u16));
  u16* w2t = (u16*)take((size_t)TEXP * TDIM * TFF * sizeof(u16));
  u16* xnh = (u16*)take(SZ_T); u16* xnl = (u16*)take(SZ_T);
  u16* qh  = (u16*)take(SZ_T); u16* ql  = (u16*)take(SZ_T);
  u16* kh  = (u16*)take(SZ_T); u16* kl  = (u16*)take(SZ_T);
  u16* vth = (u16*)take(SZ_T); u16* vtl = (u16*)take(SZ_T);
  float* hres = (float*)take((size_t)TTOK * TDIM * sizeof(float));
  int*   idx01  = (int*)take(TTOK * 2 * 4);
  float* gate01 = (float*)take(TTOK * 2 * 4);
  int*   slot_of = (int*)take(TTOK * 2 * 4);
  int*   perm    = (int*)take(TPAIRS * 4);
  int*   counts  = (int*)take(256);
  int*   cursor  = (int*)take(256);
  int*   bm_e    = (int*)take(96 * 4);
  int*   bm_s0   = (int*)take(96 * 4);
  int*   bm_end  = (int*)take(96 * 4);
  int*   n_act   = (int*)take(256);
  u16* oh = xnh; u16* ol = xnl;
  u16* hn = qh;
  u16* hbuf = kh;
  u16* pout = vth;

  transpose_all_k<<<28672, dim3(32, 8), 0, stream>>>(wq, wk, wv, wo, w1, w3, w2,
                                                     wqt_h, wqt_l, wkt_h, wkt_l, wvt_h, wvt_l,
                                                     wot_h, wot_l, w1t, w3t, w2t);
  rmsnorm_k<<<TTOK, 256, 0, stream>>>(x, anw, xnh, xnl, counts);
  gemm_qkv_k<<<dim3(TTOK/128, 48), 256, 0, stream>>>(xnh, xnl, wqt_h, wqt_l, wkt_h, wkt_l,
                                                     wvt_h, wvt_l, qh, ql, kh, kl, vth, vtl);
  flash_k<<<dim3(TSEQ/128, TBATCH*THEADS), 256, 0, stream>>>(qh, ql, kh, kl, vth, vtl, oh, ol);
  gemm_x3_k<2><<<dim3(TTOK/128, TDIM/64), 256, 0, stream>>>(oh, ol, wot_h, wot_l, nullptr, nullptr, hres, x, TTOK, TDIM, TDIM);
  router_k<<<TTOK, 256, 0, stream>>>(hres, fnw, rw, hn, idx01, gate01, counts);
  offsets_k<<<1, 1, 0, stream>>>(counts, cursor, bm_e, bm_s0, bm_end, n_act);
  scatter_k<<<TTOK/256, 256, 0, stream>>>(idx01, cursor, slot_of, perm);
  moe_gemm1_k<<<dim3(72, TFF/64), 256, 0, stream>>>(hn, w1t, w3t, perm, bm_e, bm_s0, bm_end, n_act, hbuf);
  moe_gemm2_k<<<dim3(72, TDIM/64), 256, 0, stream>>>(hbuf, w2t, bm_e, bm_s0, bm_end, n_act, pout);
  combine_k<<<TTOK, 256, 0, stream>>>(hres, pout, slot_of, gate01, out);
}